// Round 8
// baseline (2220.498 us; speedup 1.0000x reference)
//
#include <hip/hip_runtime.h>
#include <math.h>

typedef short v8s __attribute__((ext_vector_type(8)));   // 8 bf16
typedef float v4f __attribute__((ext_vector_type(4)));

// fast softplus: max(x,0) + ln2*log2(1+exp(-|x|)); HW exp/log, ~3e-5 abs err
__device__ __forceinline__ float sp_f(float x) {
  return fmaxf(x, 0.0f) + 0.69314718056f * __log2f(1.0f + __expf(-fabsf(x)));
}

__device__ __forceinline__ unsigned short f2bf(float f) {
  union { float f; unsigned u; } x; x.f = f;
  unsigned r = (x.u + 0x7FFF + ((x.u >> 16) & 1)) >> 16;
  return (unsigned short)r;
}

__device__ __forceinline__ float bf2f(unsigned short h) {
  union { unsigned u; float f; } x; x.u = ((unsigned)h) << 16;
  return x.f;
}

// ---------------- one-shot weight fragment prep (3 layers x 4 mats) ----------------
__global__ __launch_bounds__(256) void k_prep_wfrag(
    const float* __restrict__ eW1, const float* __restrict__ eW2,
    const float* __restrict__ nW1, const float* __restrict__ nW2,
    unsigned short* __restrict__ wfrag) {
  int i = blockIdx.x >> 2;   // layer
  int m = blockIdx.x & 3;    // matrix
  const float* W;
  if (m == 0)      W = eW1 + (size_t)i * 192 * 64 + 128 * 64;  // W1c
  else if (m == 1) W = eW2 + (size_t)i * 64 * 64;
  else if (m == 2) W = nW1 + (size_t)i * 128 * 64 + 64 * 64;   // nW1b
  else             W = nW2 + (size_t)i * 64 * 64;
  unsigned short* out = wfrag + ((size_t)i * 4 + m) * 4096;
  for (int f = threadIdx.x; f < 4096; f += 256) {
    int j = f & 7, ln = (f >> 3) & 63, kh = (f >> 9) & 1, ct = f >> 10;
    int k = kh * 32 + (ln >> 4) * 8 + j;
    int n = ct * 16 + (ln & 15);
    out[f] = f2bf(W[k * 64 + n]);
  }
}

// ---------------- node embedding, LDS-staged tiles + channel split ----------------
__global__ __launch_bounds__(256) void k_embed_nodes(
    const float* __restrict__ x, const int* __restrict__ batch,
    const float* __restrict__ charge, const float* __restrict__ W_charge,
    const float* __restrict__ b_charge, const float* __restrict__ W_atom,
    const float* __restrict__ b_atom, float* __restrict__ xemb, int N) {
  __shared__ float sW[108 * 64];   // 27.6 KB
  __shared__ float sX[128 * 92];   // 46 KB
  __shared__ float sb[64];
  __shared__ float sWc[16];
  __shared__ float sbc[16];
  for (int i = threadIdx.x; i < 108 * 64; i += blockDim.x) sW[i] = W_atom[i];
  if (threadIdx.x < 64) sb[threadIdx.x] = b_atom[threadIdx.x];
  if (threadIdx.x < 16) {
    sWc[threadIdx.x] = W_charge[threadIdx.x];
    sbc[threadIdx.x] = b_charge[threadIdx.x];
  }
  int ntiles = (N + 127) >> 7;
  for (int tile = blockIdx.x; tile < ntiles; tile += gridDim.x) {
    int base = tile << 7;
    int cnt = N - base; if (cnt > 128) cnt = 128;
    __syncthreads();
    if (cnt == 128) {
      const float4* src = (const float4*)(x + (size_t)base * 92);
      for (int i = threadIdx.x; i < 2944; i += 256) ((float4*)sX)[i] = src[i];
    } else {
      for (int i = threadIdx.x; i < cnt * 92; i += 256)
        sX[i] = x[(size_t)base * 92 + i];
    }
    __syncthreads();
    int t = threadIdx.x;
    int node = t & 127, half = t >> 7;
    if (node < cnt) {
      int n = base + node;
      float acc[32];
#pragma unroll
      for (int j = 0; j < 32; ++j) acc[j] = sb[half * 32 + j];
      const float* xr = sX + node * 92;
      for (int k = 0; k < 92; ++k) {
        float a = xr[k];
        const float* wk = sW + k * 64 + half * 32;
#pragma unroll
        for (int j = 0; j < 32; ++j) acc[j] = fmaf(a, wk[j], acc[j]);
      }
      float ch = charge[batch[n]];
#pragma unroll
      for (int c = 0; c < 16; ++c) {
        float cf = fmaf(ch, sWc[c], sbc[c]);
        const float* wk = sW + (92 + c) * 64 + half * 32;
#pragma unroll
        for (int j = 0; j < 32; ++j) acc[j] = fmaf(cf, wk[j], acc[j]);
      }
      float* o = xemb + (size_t)n * 64 + half * 32;
#pragma unroll
      for (int q8 = 0; q8 < 8; ++q8)
        ((float4*)o)[q8] = make_float4(acc[4*q8], acc[4*q8+1], acc[4*q8+2], acc[4*q8+3]);
    }
  }
}

// ---------------- CSR build ----------------
__global__ __launch_bounds__(256) void k_hist(const int* __restrict__ col,
                                              int* __restrict__ counts, int E) {
  int stride = gridDim.x * blockDim.x;
  for (int e = blockIdx.x * blockDim.x + threadIdx.x; e < E; e += stride)
    atomicAdd(&counts[col[e]], 1);
}

__global__ __launch_bounds__(256) void k_scan1(const int* __restrict__ counts,
                                               int* __restrict__ scan_tmp,
                                               int* __restrict__ bsum, int N) {
  __shared__ int sd[2][256];
  int t = threadIdx.x;
  int i = blockIdx.x * 256 + t;
  int v = (i < N) ? counts[i] : 0;
  sd[0][t] = v;
  __syncthreads();
  int s = 0;
#pragma unroll
  for (int off = 1; off < 256; off <<= 1) {
    int nv = sd[s][t];
    if (t >= off) nv += sd[s][t - off];
    sd[s ^ 1][t] = nv;
    s ^= 1;
    __syncthreads();
  }
  if (i < N) scan_tmp[i] = sd[s][t];
  if (t == 255) bsum[blockIdx.x] = sd[s][255];
}

__global__ __launch_bounds__(256) void k_scan2(int* __restrict__ b, int NB) {
  __shared__ int sd[2][256];
  __shared__ int carry_s;
  int t = threadIdx.x;
  if (t == 0) carry_s = 0;
  __syncthreads();
  for (int base = 0; base < NB; base += 256) {
    int i = base + t;
    int v = (i < NB) ? b[i] : 0;
    sd[0][t] = v;
    __syncthreads();
    int s = 0;
#pragma unroll
    for (int off = 1; off < 256; off <<= 1) {
      int nv = sd[s][t];
      if (t >= off) nv += sd[s][t - off];
      sd[s ^ 1][t] = nv;
      s ^= 1;
      __syncthreads();
    }
    int c = carry_s;
    int tot = sd[s][255];
    if (i < NB) b[i] = sd[s][t] + c;
    __syncthreads();
    if (t == 0) carry_s = c + tot;
    __syncthreads();
  }
}

__global__ __launch_bounds__(256) void k_scan3(const int* __restrict__ counts,
                                               const int* __restrict__ scan_tmp,
                                               const int* __restrict__ bsum,
                                               int* __restrict__ cursor, int N) {
  int i = blockIdx.x * 256 + threadIdx.x;
  if (i < N) {
    int base = (blockIdx.x > 0) ? bsum[blockIdx.x - 1] : 0;
    cursor[i] = scan_tmp[i] - counts[i] + base;
  }
}

__global__ __launch_bounds__(256) void k_scatter(
    const int* __restrict__ row, const int* __restrict__ col,
    int* __restrict__ cursor, int* __restrict__ pos,
    int* __restrict__ row_s, int* __restrict__ col_s, int E) {
  int stride = gridDim.x * blockDim.x;
  for (int e = blockIdx.x * blockDim.x + threadIdx.x; e < E; e += stride) {
    int c = col[e];
    int p = atomicAdd(&cursor[c], 1);
    pos[e] = p;
    row_s[p] = row[e];
    col_s[p] = c;
  }
}

// ---------------- bond embedding: LDS-staged tiles, scatter write ----------------
__global__ __launch_bounds__(256) void k_embed_bonds_pos(
    const float* __restrict__ eattr, const int* __restrict__ pos,
    const float* __restrict__ W_bond, const float* __restrict__ b_bond,
    unsigned short* __restrict__ ea16, int E) {
  __shared__ float sW[41 * 64];    // 10.5 KB
  __shared__ float sE[256 * 41];   // 42 KB
  __shared__ float sb[64];
  for (int i = threadIdx.x; i < 41 * 64; i += blockDim.x) sW[i] = W_bond[i];
  if (threadIdx.x < 64) sb[threadIdx.x] = b_bond[threadIdx.x];
  int ntiles = (E + 255) >> 8;
  for (int tile = blockIdx.x; tile < ntiles; tile += gridDim.x) {
    int base = tile << 8;
    int cnt = E - base; if (cnt > 256) cnt = 256;
    __syncthreads();
    if (cnt == 256) {
      const float4* src = (const float4*)(eattr + (size_t)base * 41);
      for (int i = threadIdx.x; i < 2624; i += 256) ((float4*)sE)[i] = src[i];
    } else {
      for (int i = threadIdx.x; i < cnt * 41; i += 256)
        sE[i] = eattr[(size_t)base * 41 + i];
    }
    __syncthreads();
    int t = threadIdx.x;
    if (t < cnt) {
      float acc[64];
#pragma unroll
      for (int j = 0; j < 64; ++j) acc[j] = sb[j];
      const float* er = sE + t * 41;
      for (int k = 0; k < 41; ++k) {
        float a = er[k];
        const float* wk = sW + k * 64;
#pragma unroll
        for (int j = 0; j < 64; ++j) acc[j] = fmaf(a, wk[j], acc[j]);
      }
      size_t ob = (size_t)pos[base + t] * 64;
#pragma unroll
      for (int q8 = 0; q8 < 8; ++q8) {
        unsigned short tmp[8];
#pragma unroll
        for (int j = 0; j < 8; ++j) tmp[j] = f2bf(acc[q8 * 8 + j]);
        *(uint4*)&ea16[ob + q8 * 8] = *(uint4*)tmp;
      }
    }
  }
}

// ---------------- node-side precompute body ----------------
// storage permute: out[i] = val[((i&3)<<4) | (i>>2)] so lane c16 reads ushort4
__device__ __forceinline__ void node_pre_body(
    const float* __restrict__ xr, const float* sWa, const float* sWb,
    const float* sWp, unsigned short* __restrict__ up16,
    unsigned short* __restrict__ v16, int n) {
  const float4* xr4 = (const float4*)xr;
  float u[64], p[64];
#pragma unroll
  for (int j = 0; j < 64; ++j) { u[j] = 0.f; p[j] = 0.f; }
  for (int k4 = 0; k4 < 16; ++k4) {
    float4 av = xr4[k4];
    const float* wa = sWa + k4 * 256;
    const float* wp = sWp + k4 * 256;
#pragma unroll
    for (int j = 0; j < 64; ++j) u[j] = fmaf(av.x, wa[j], u[j]);
#pragma unroll
    for (int j = 0; j < 64; ++j) p[j] = fmaf(av.x, wp[j], p[j]);
#pragma unroll
    for (int j = 0; j < 64; ++j) u[j] = fmaf(av.y, wa[64 + j], u[j]);
#pragma unroll
    for (int j = 0; j < 64; ++j) p[j] = fmaf(av.y, wp[64 + j], p[j]);
#pragma unroll
    for (int j = 0; j < 64; ++j) u[j] = fmaf(av.z, wa[128 + j], u[j]);
#pragma unroll
    for (int j = 0; j < 64; ++j) p[j] = fmaf(av.z, wp[128 + j], p[j]);
#pragma unroll
    for (int j = 0; j < 64; ++j) u[j] = fmaf(av.w, wa[192 + j], u[j]);
#pragma unroll
    for (int j = 0; j < 64; ++j) p[j] = fmaf(av.w, wp[192 + j], p[j]);
  }
  unsigned short* o = up16 + (size_t)n * 128;
#pragma unroll
  for (int q8 = 0; q8 < 8; ++q8) {
    unsigned short tmp[8];
#pragma unroll
    for (int j = 0; j < 8; ++j) {
      int i = q8 * 8 + j;
      tmp[j] = f2bf(u[((i & 3) << 4) | (i >> 2)]);
    }
    *(uint4*)&o[q8 * 8] = *(uint4*)tmp;
  }
#pragma unroll
  for (int q8 = 0; q8 < 8; ++q8) {
    unsigned short tmp[8];
#pragma unroll
    for (int j = 0; j < 8; ++j) {
      int i = q8 * 8 + j;
      tmp[j] = f2bf(p[((i & 3) << 4) | (i >> 2)]);
    }
    *(uint4*)&o[64 + q8 * 8] = *(uint4*)tmp;
  }
  float vv[64];
#pragma unroll
  for (int j = 0; j < 64; ++j) vv[j] = 0.f;
  for (int k4 = 0; k4 < 16; ++k4) {
    float4 av = xr4[k4];
    const float* wb = sWb + k4 * 256;
#pragma unroll
    for (int j = 0; j < 64; ++j) vv[j] = fmaf(av.x, wb[j], vv[j]);
#pragma unroll
    for (int j = 0; j < 64; ++j) vv[j] = fmaf(av.y, wb[64 + j], vv[j]);
#pragma unroll
    for (int j = 0; j < 64; ++j) vv[j] = fmaf(av.z, wb[128 + j], vv[j]);
#pragma unroll
    for (int j = 0; j < 64; ++j) vv[j] = fmaf(av.w, wb[192 + j], vv[j]);
  }
  unsigned short* ov = v16 + (size_t)n * 64;
#pragma unroll
  for (int q8 = 0; q8 < 8; ++q8) {
    unsigned short tmp[8];
#pragma unroll
    for (int j = 0; j < 8; ++j) {
      int i = q8 * 8 + j;
      tmp[j] = f2bf(vv[((i & 3) << 4) | (i >> 2)]);
    }
    *(uint4*)&ov[q8 * 8] = *(uint4*)tmp;
  }
}

__global__ __launch_bounds__(256) void k_node_pre(
    const float* __restrict__ xemb, const float* __restrict__ eW1,
    const float* __restrict__ nW1, unsigned short* __restrict__ up16,
    unsigned short* __restrict__ v16, int N) {
  __shared__ float sWa[64 * 64];
  __shared__ float sWb[64 * 64];
  __shared__ float sWp[64 * 64];
  for (int i = threadIdx.x; i < 64 * 64; i += blockDim.x) {
    sWa[i] = eW1[i];
    sWb[i] = eW1[64 * 64 + i];
    sWp[i] = nW1[i];
  }
  __syncthreads();
  int stride = gridDim.x * blockDim.x;
  for (int n = blockIdx.x * blockDim.x + threadIdx.x; n < N; n += stride)
    node_pre_body(xemb + (size_t)n * 64, sWa, sWb, sWp, up16, v16, n);
}

// ---------------- fused BN apply + residual + next-layer node_pre ----------------
__global__ __launch_bounds__(256) void k_bn_pre(
    float* __restrict__ xemb, const float* __restrict__ xnew,
    const float* __restrict__ bnacc, const float* __restrict__ gamma,
    const float* __restrict__ beta, const float* __restrict__ eW1n,
    const float* __restrict__ nW1n, unsigned short* __restrict__ up16,
    unsigned short* __restrict__ v16, int N) {
  __shared__ float sWa[64 * 64];
  __shared__ float sWb[64 * 64];
  __shared__ float sWp[64 * 64];
  __shared__ float sscale[64], sshift[64];
  for (int i = threadIdx.x; i < 64 * 64; i += blockDim.x) {
    sWa[i] = eW1n[i];
    sWb[i] = eW1n[64 * 64 + i];
    sWp[i] = nW1n[i];
  }
  if (threadIdx.x < 64) {
    float inv = 1.0f / (float)N;
    float m = bnacc[threadIdx.x] * inv;
    float var = bnacc[64 + threadIdx.x] * inv - m * m;
    float rs = rsqrtf(var + 1e-5f);
    float g = gamma[threadIdx.x];
    sscale[threadIdx.x] = rs * g;
    sshift[threadIdx.x] = beta[threadIdx.x] - m * rs * g;
  }
  __syncthreads();
  int stride = gridDim.x * blockDim.x;
  for (int n = blockIdx.x * blockDim.x + threadIdx.x; n < N; n += stride) {
    float* xr = xemb + (size_t)n * 64;
#pragma unroll
    for (int q = 0; q < 16; ++q) {
      float4 xn4 = ((const float4*)(xnew + (size_t)n * 64))[q];
      float4 xo4 = ((const float4*)xr)[q];
      xo4.x += sp_f(fmaf(xn4.x, sscale[4*q+0], sshift[4*q+0]));
      xo4.y += sp_f(fmaf(xn4.y, sscale[4*q+1], sshift[4*q+1]));
      xo4.z += sp_f(fmaf(xn4.z, sscale[4*q+2], sshift[4*q+2]));
      xo4.w += sp_f(fmaf(xn4.w, sscale[4*q+3], sshift[4*q+3]));
      ((float4*)xr)[q] = xo4;
    }
    node_pre_body(xr, sWa, sWb, sWp, up16, v16, n);
  }
}

// ---------------- fused per-layer edge kernel, MFMA bf16, 8 waves x 16 rows ----------------
#define READ_FRAGS(P)                                                        \
  {                                                                          \
    const v8s* wp_ = (const v8s*)gWf + (P) * 512;                            \
    _Pragma("unroll") for (int ct = 0; ct < 4; ++ct)                         \
        _Pragma("unroll") for (int kh = 0; kh < 2; ++kh)                     \
            bfr[ct][kh] = wp_[(ct * 2 + kh) * 64 + l];                       \
    {                                                                        \
      int row_ = rbase + c16;                                                \
      _Pragma("unroll") for (int kh = 0; kh < 2; ++kh)                       \
        af[kh] = *(const v8s*)&sA[row_ * 64 +                                \
                                  ((kh * 32 + q * 8) ^ ((row_ & 7) << 3))];  \
    }                                                                        \
  }

#define DO_MFMA()                                                            \
  _Pragma("unroll") for (int ct = 0; ct < 4; ++ct) {                         \
    v4f a_ = {0.f, 0.f, 0.f, 0.f};                                           \
    a_ = __builtin_amdgcn_mfma_f32_16x16x32_bf16(af[0], bfr[ct][0], a_,      \
                                                 0, 0, 0);                   \
    a_ = __builtin_amdgcn_mfma_f32_16x16x32_bf16(af[1], bfr[ct][1], a_,      \
                                                 0, 0, 0);                   \
    acc[ct] = a_;                                                            \
  }

__global__ __launch_bounds__(512, 8) void k_edge_mfma(
    const int* __restrict__ row_s, const int* __restrict__ col_s,
    unsigned short* __restrict__ ea16, const unsigned short* __restrict__ up16,
    const unsigned short* __restrict__ v16,
    const unsigned short* __restrict__ gWf, const float* __restrict__ eb1,
    const float* __restrict__ eb2, const float* __restrict__ nb1,
    const float* __restrict__ nb2, float* __restrict__ xnew, int E,
    int store_ea) {
  __shared__ __align__(16) unsigned char smem[34304];
  unsigned short* sA = (unsigned short*)smem;             // 16 KB (aliased)
  float* msgb        = (float*)smem;                      // 32 KB
  float* sBb         = (float*)(smem + 32768);            // 1 KB
  int* scol          = (int*)(smem + 33792);              // 512 B

  int tid = threadIdx.x;
  // bijective XCD-chunked swizzle (m204): consecutive logical tiles -> same XCD.
  // HW round-robins blockIdx across 8 XCDs; xcd = bid&7 gets chunk of tiles.
  int nwg = gridDim.x;
  int q8c = nwg >> 3, r8c = nwg & 7;
  int xcd = blockIdx.x & 7, idx = blockIdx.x >> 3;
  int tile = (xcd < r8c ? xcd * (q8c + 1) : r8c * (q8c + 1) + (xcd - r8c) * q8c) + idx;
  int te = tile * 128;
  int w = tid >> 6, l = tid & 63, q = l >> 4, c16 = l & 15;
  int rbase = w * 16;

  int rid[4], cid[4], eid[4];
#pragma unroll
  for (int r = 0; r < 4; ++r) {
    int e = te + rbase + q * 4 + r;
    eid[r] = e;
    int ec = e < E ? e : E - 1;
    rid[r] = row_s[ec];
    cid[r] = col_s[ec];
  }

  if (tid < 64) {
    sBb[0 * 64 + tid] = eb1[tid];
    sBb[1 * 64 + tid] = eb2[tid];
    sBb[2 * 64 + tid] = nb1[tid];
    sBb[3 * 64 + tid] = nb2[tid];
  }
  if (tid < 128) {
    int e = te + tid;
    scol[tid] = col_s[e < E ? e : E - 1];
  }
  for (int i = tid; i < 1024; i += 512) {
    int r = i >> 3, cc = i & 7;
    int e = te + r;
    if (e >= E) e = E - 1;
    uint4 d = *(const uint4*)&ea16[(size_t)e * 64 + cc * 8];
    *(uint4*)&sA[r * 64 + ((cc * 8) ^ ((r & 7) << 3))] = d;
  }

  v8s af[2];
  v8s bfr[4][2];
  v4f acc[4];

  __syncthreads();   // staging done

  // ---- phase 0: T = sp(ea@W1c + b1 + u[row] + v[col]) ----
  READ_FRAGS(0);
  DO_MFMA();
#pragma unroll
  for (int r = 0; r < 4; ++r) {
    ushort4 uu = *(const ushort4*)&up16[(size_t)rid[r] * 128 + c16 * 4];
    ushort4 vv = *(const ushort4*)&v16[(size_t)cid[r] * 64 + c16 * 4];
    int row = rbase + q * 4 + r;
    const unsigned short* up_ = (const unsigned short*)&uu;
    const unsigned short* vp_ = (const unsigned short*)&vv;
#pragma unroll
    for (int ct = 0; ct < 4; ++ct) {
      int n = ct * 16 + c16;
      float t = acc[ct][r] + sBb[n] + bf2f(up_[ct]) + bf2f(vp_[ct]);
      t = sp_f(t);
      sA[row * 64 + (n ^ ((row & 7) << 3))] = f2bf(t);
    }
  }

  // ---- phase 1: ea' = T@eW2 + b2 -> sA (own band) ----
  READ_FRAGS(1);
  DO_MFMA();
#pragma unroll
  for (int ct = 0; ct < 4; ++ct) {
    int n = ct * 16 + c16;
#pragma unroll
    for (int r = 0; r < 4; ++r) {
      float en = acc[ct][r] + sBb[64 + n];
      int row = rbase + q * 4 + r;
      sA[row * 64 + (n ^ ((row & 7) << 3))] = f2bf(en);
    }
  }
  __syncthreads();   // writeback reads all rows
  if (store_ea) {
    for (int i = tid; i < 1024; i += 512) {
      int r = i >> 3, cc = i & 7;
      if (te + r < E) {
        uint4 d = *(const uint4*)&sA[r * 64 + ((cc * 8) ^ ((r & 7) << 3))];
        *(uint4*)&ea16[(size_t)(te + r) * 64 + cc * 8] = d;
      }
    }
  }
  __syncthreads();   // phase-2 epi writes must not race writeback reads

  // ---- phase 2: T2 = sp(ea'@nW1b + b3 + p[row]) ----
  READ_FRAGS(2);
  DO_MFMA();
#pragma unroll
  for (int r = 0; r < 4; ++r) {
    ushort4 pp = *(const ushort4*)&up16[(size_t)rid[r] * 128 + 64 + c16 * 4];
    int row = rbase + q * 4 + r;
    const unsigned short* pp_ = (const unsigned short*)&pp;
#pragma unroll
    for (int ct = 0; ct < 4; ++ct) {
      int n = ct * 16 + c16;
      float t2 = acc[ct][r] + sBb[128 + n] + bf2f(pp_[ct]);
      t2 = sp_f(t2);
      sA[row * 64 + (n ^ ((row & 7) << 3))] = f2bf(t2);
    }
  }

  // ---- phase 3: msg = T2@nW2 + b4 -> msgb (sA dead after frag loads) ----
  READ_FRAGS(3);
  __syncthreads();   // all waves done reading sA; msgb alias safe
  DO_MFMA();
#pragma unroll
  for (int ct = 0; ct < 4; ++ct) {
    int n = ct * 16 + c16;
#pragma unroll
    for (int r = 0; r < 4; ++r) {
      float msg = acc[ct][r] + sBb[192 + n];
      int row = rbase + q * 4 + r;
      msgb[row * 64 + n] = (eid[r] < E) ? msg : 0.0f;
    }
  }
  __syncthreads();

  // ---- segmented reduction; plain store for interior (exclusive) segments ----
  int nrows = E - te;
  if (nrows > 128) nrows = 128;
  for (int r0 = w; r0 < nrows; r0 += 8) {
    int c0 = scol[r0];
    if (r0 > 0 && scol[r0 - 1] == c0) continue;
    float s = 0.0f;
    int r = r0;
    do {
      s += msgb[r * 64 + l];
      ++r;
    } while (r < nrows && scol[r] == c0);
    if (r0 > 0 && r < nrows)
      xnew[(size_t)c0 * 64 + l] = s;     // run fully interior: exclusive writer
    else
      atomicAdd(&xnew[(size_t)c0 * 64 + l], s);
  }
}

// ---------------- BN stats ----------------
__global__ __launch_bounds__(256) void k_bn_stats(
    const float* __restrict__ xnew, float* __restrict__ bnacc, int N) {
  int t = threadIdx.x;
  int ch = t & 63;
  int sl = t >> 6;
  float s = 0.f, s2 = 0.f;
  for (int n = blockIdx.x * 4 + sl; n < N; n += gridDim.x * 4) {
    float v = xnew[(size_t)n * 64 + ch];
    s += v;
    s2 = fmaf(v, v, s2);
  }
  __shared__ float red[256], red2[256];
  red[t] = s;
  red2[t] = s2;
  __syncthreads();
  if (sl == 0) {
    s = red[ch] + red[64 + ch] + red[128 + ch] + red[192 + ch];
    s2 = red2[ch] + red2[64 + ch] + red2[128 + ch] + red2[192 + ch];
    atomicAdd(&bnacc[ch], s);
    atomicAdd(&bnacc[64 + ch], s2);
  }
}

// ---------------- BN apply + softplus + residual (last layer) ----------------
__global__ __launch_bounds__(256) void k_bn_apply(
    float* __restrict__ x, const float* __restrict__ xnew,
    const float* __restrict__ bnacc, const float* __restrict__ gamma,
    const float* __restrict__ beta, int N) {
  __shared__ float sscale[64], sshift[64];
  if (threadIdx.x < 64) {
    float inv = 1.0f / (float)N;
    float m = bnacc[threadIdx.x] * inv;
    float var = bnacc[64 + threadIdx.x] * inv - m * m;
    float rs = rsqrtf(var + 1e-5f);
    float g = gamma[threadIdx.x];
    sscale[threadIdx.x] = rs * g;
    sshift[threadIdx.x] = beta[threadIdx.x] - m * rs * g;
  }
  __syncthreads();
  size_t total = (size_t)N * 64;
  size_t stride = (size_t)gridDim.x * blockDim.x;
  for (size_t i = (size_t)blockIdx.x * blockDim.x + threadIdx.x; i < total; i += stride) {
    int ch = (int)(i & 63);
    float v = fmaf(xnew[i], sscale[ch], sshift[ch]);
    x[i] += sp_f(v);
  }
}

// ---------------- fused pool + predictor ----------------
__device__ __forceinline__ int lbound(const int* a, int n, int key) {
  int lo = 0, hi = n;
  while (lo < hi) {
    int mid = (lo + hi) >> 1;
    if (a[mid] < key) lo = mid + 1; else hi = mid;
  }
  return lo;
}

__global__ __launch_bounds__(256) void k_pool_pred(
    const float* __restrict__ x, const int* __restrict__ batch, int N,
    const float* __restrict__ pW1, const float* __restrict__ pb1,
    const float* __restrict__ pW2, const float* __restrict__ pb2,
    const float* __restrict__ pW3, const float* __restrict__ pb3,
    float* __restrict__ out) {
  int b = blockIdx.x;
  int lo = lbound(batch, N, b);
  int hi = lbound(batch, N, b + 1);
  int t = threadIdx.x;
  int ch = t & 63;
  int sl = t >> 6;
  float s = 0.f;
  for (int n = lo + sl; n < hi; n += 4) s += x[(size_t)n * 64 + ch];
  __shared__ float red4[4][64];
  __shared__ float sg[64];
  __shared__ float sh1[128];
  __shared__ float red[128];
  red4[sl][ch] = s;
  __syncthreads();
  if (t < 64) {
    float tot = red4[0][t] + red4[1][t] + red4[2][t] + red4[3][t];
    float cnt = (float)(hi - lo);
    sg[t] = tot / fmaxf(cnt, 1.0f);
  }
  __syncthreads();
  if (t < 128) {
    float h = pb1[t];
    for (int k = 0; k < 64; ++k) h = fmaf(sg[k], pW1[k * 128 + t], h);
    sh1[t] = sp_f(h);
  }
  __syncthreads();
  if (t < 128) {
    float h = pb2[t];
    for (int k = 0; k < 128; ++k) h = fmaf(sh1[k], pW2[k * 128 + t], h);
    red[t] = sp_f(h) * pW3[t];
  }
  __syncthreads();
  for (int off = 64; off > 0; off >>= 1) {
    if (t < off) red[t] += red[t + off];
    __syncthreads();
  }
  if (t == 0) out[b] = red[0] + pb3[0];
}

extern "C" void kernel_launch(void* const* d_in, const int* in_sizes, int n_in,
                              void* d_out, int out_size, void* d_ws, size_t ws_size,
                              hipStream_t stream) {
  const float* x         = (const float*)d_in[0];
  const float* edge_attr = (const float*)d_in[1];
  const float* charge    = (const float*)d_in[2];
  const int*   eidx      = (const int*)d_in[3];
  const int*   batch     = (const int*)d_in[4];
  const float* W_charge  = (const float*)d_in[5];
  const float* b_charge  = (const float*)d_in[6];
  const float* W_atom    = (const float*)d_in[7];
  const float* b_atom    = (const float*)d_in[8];
  const float* W_bond    = (const float*)d_in[9];
  const float* b_bond    = (const float*)d_in[10];
  const float* eW1 = (const float*)d_in[11];
  const float* eb1 = (const float*)d_in[12];
  const float* eW2 = (const float*)d_in[13];
  const float* eb2 = (const float*)d_in[14];
  const float* nW1 = (const float*)d_in[15];
  const float* nb1 = (const float*)d_in[16];
  const float* nW2 = (const float*)d_in[17];
  const float* nb2 = (const float*)d_in[18];
  const float* gam = (const float*)d_in[19];
  const float* bet = (const float*)d_in[20];
  const float* pW1 = (const float*)d_in[21];
  const float* pb1 = (const float*)d_in[22];
  const float* pW2 = (const float*)d_in[23];
  const float* pb2 = (const float*)d_in[24];
  const float* pW3 = (const float*)d_in[25];
  const float* pb3 = (const float*)d_in[26];

  int N = in_sizes[4];
  int E = in_sizes[3] / 2;
  int B = in_sizes[2];
  const int* row = eidx;
  const int* col = eidx + E;

  char* wptr = (char*)d_ws;
  unsigned short* ea16 = (unsigned short*)wptr; wptr += (((size_t)E * 64 * 2 + 255) & ~255ull);
  unsigned short* up16 = (unsigned short*)wptr; wptr += (((size_t)N * 128 * 2 + 255) & ~255ull);
  unsigned short* v16  = (unsigned short*)wptr; wptr += (((size_t)N * 64 * 2 + 255) & ~255ull);
  unsigned short* wfrag = (unsigned short*)wptr; wptr += 12 * 4096 * 2;
  float* xemb = (float*)wptr; wptr += (size_t)N * 64 * 4;
  float* xnew = (float*)wptr; wptr += (size_t)N * 64 * 4;
  float* bnacc = (float*)wptr; wptr += 256 * 4;
  int* counts = (int*)wptr;   wptr += (size_t)N * 4;
  int* scan_tmp = (int*)wptr; wptr += (size_t)N * 4;
  int* cursor = (int*)wptr;   wptr += (size_t)N * 4;
  int* bsum = (int*)wptr;     wptr += 4096;
  int* pos = (int*)wptr;      wptr += (size_t)E * 4;
  int* row_s = (int*)wptr;    wptr += (size_t)E * 4;
  int* col_s = (int*)wptr;    wptr += (size_t)E * 4;

  int NB = (N + 255) / 256;

  k_prep_wfrag<<<12, 256, 0, stream>>>(eW1, eW2, nW1, nW2, wfrag);
  hipMemsetAsync(counts, 0, (size_t)N * 4, stream);
  k_hist<<<2048, 256, 0, stream>>>(col, counts, E);
  k_scan1<<<NB, 256, 0, stream>>>(counts, scan_tmp, bsum, N);
  k_scan2<<<1, 256, 0, stream>>>(bsum, NB);
  k_scan3<<<NB, 256, 0, stream>>>(counts, scan_tmp, bsum, cursor, N);
  k_scatter<<<2048, 256, 0, stream>>>(row, col, cursor, pos, row_s, col_s, E);

  int ntilesN = (N + 127) / 128;
  k_embed_nodes<<<ntilesN, 256, 0, stream>>>(x, batch, charge, W_charge,
                                             b_charge, W_atom, b_atom, xemb, N);
  k_embed_bonds_pos<<<2048, 256, 0, stream>>>(edge_attr, pos, W_bond, b_bond,
                                              ea16, E);
  k_node_pre<<<NB, 256, 0, stream>>>(xemb, eW1, nW1, up16, v16, N);

  int gridE = (E + 127) / 128;
  for (int i = 0; i < 3; ++i) {
    hipMemsetAsync(xnew, 0, (size_t)N * 64 * 4, stream);
    hipMemsetAsync(bnacc, 0, 256 * 4, stream);
    k_edge_mfma<<<gridE, 512, 0, stream>>>(
        row_s, col_s, ea16, up16, v16, wfrag + (size_t)i * 16384,
        eb1 + (size_t)i * 64, eb2 + (size_t)i * 64, nb1 + (size_t)i * 64,
        nb2 + (size_t)i * 64, xnew, E, (i < 2) ? 1 : 0);
    k_bn_stats<<<1024, 256, 0, stream>>>(xnew, bnacc, N);
    if (i < 2) {
      k_bn_pre<<<NB, 256, 0, stream>>>(
          xemb, xnew, bnacc, gam + (size_t)i * 64, bet + (size_t)i * 64,
          eW1 + (size_t)(i + 1) * 192 * 64, nW1 + (size_t)(i + 1) * 128 * 64,
          up16, v16, N);
    } else {
      k_bn_apply<<<4096, 256, 0, stream>>>(xemb, xnew, bnacc,
                                           gam + (size_t)i * 64,
                                           bet + (size_t)i * 64, N);
    }
  }

  k_pool_pred<<<B, 256, 0, stream>>>(xemb, batch, N, pW1, pb1, pW2, pb2,
                                     pW3, pb3, (float*)d_out);
}

// Round 9
// 2173.903 us; speedup vs baseline: 1.0214x; 1.0214x over previous
//
#include <hip/hip_runtime.h>
#include <math.h>

typedef short v8s __attribute__((ext_vector_type(8)));   // 8 bf16
typedef float v4f __attribute__((ext_vector_type(4)));

// fast softplus: max(x,0) + ln2*log2(1+exp(-|x|)); HW exp/log, ~3e-5 abs err
__device__ __forceinline__ float sp_f(float x) {
  return fmaxf(x, 0.0f) + 0.69314718056f * __log2f(1.0f + __expf(-fabsf(x)));
}

__device__ __forceinline__ unsigned short f2bf(float f) {
  union { float f; unsigned u; } x; x.f = f;
  unsigned r = (x.u + 0x7FFF + ((x.u >> 16) & 1)) >> 16;
  return (unsigned short)r;
}

__device__ __forceinline__ float bf2f(unsigned short h) {
  union { unsigned u; float f; } x; x.u = ((unsigned)h) << 16;
  return x.f;
}

// ---------------- one-shot weight fragment prep (3 layers x 4 mats + W_bond) ----------------
__global__ __launch_bounds__(256) void k_prep_wfrag(
    const float* __restrict__ eW1, const float* __restrict__ eW2,
    const float* __restrict__ nW1, const float* __restrict__ nW2,
    const float* __restrict__ W_bond, unsigned short* __restrict__ wfrag) {
  if (blockIdx.x == 12) {
    // W_bond [41][64], zero-padded to K=64
    unsigned short* out = wfrag + 12 * 4096;
    for (int f = threadIdx.x; f < 4096; f += 256) {
      int j = f & 7, ln = (f >> 3) & 63, kh = (f >> 9) & 1, ct = f >> 10;
      int k = kh * 32 + (ln >> 4) * 8 + j;
      int n = ct * 16 + (ln & 15);
      out[f] = (k < 41) ? f2bf(W_bond[k * 64 + n]) : 0;
    }
    return;
  }
  int i = blockIdx.x >> 2;   // layer
  int m = blockIdx.x & 3;    // matrix
  const float* W;
  if (m == 0)      W = eW1 + (size_t)i * 192 * 64 + 128 * 64;  // W1c
  else if (m == 1) W = eW2 + (size_t)i * 64 * 64;
  else if (m == 2) W = nW1 + (size_t)i * 128 * 64 + 64 * 64;   // nW1b
  else             W = nW2 + (size_t)i * 64 * 64;
  unsigned short* out = wfrag + ((size_t)i * 4 + m) * 4096;
  for (int f = threadIdx.x; f < 4096; f += 256) {
    int j = f & 7, ln = (f >> 3) & 63, kh = (f >> 9) & 1, ct = f >> 10;
    int k = kh * 32 + (ln >> 4) * 8 + j;
    int n = ct * 16 + (ln & 15);
    out[f] = f2bf(W[k * 64 + n]);
  }
}

// ---------------- node embedding, LDS-staged tiles + channel split ----------------
__global__ __launch_bounds__(256) void k_embed_nodes(
    const float* __restrict__ x, const int* __restrict__ batch,
    const float* __restrict__ charge, const float* __restrict__ W_charge,
    const float* __restrict__ b_charge, const float* __restrict__ W_atom,
    const float* __restrict__ b_atom, float* __restrict__ xemb, int N) {
  __shared__ float sW[108 * 64];   // 27.6 KB
  __shared__ float sX[128 * 92];   // 46 KB
  __shared__ float sb[64];
  __shared__ float sWc[16];
  __shared__ float sbc[16];
  for (int i = threadIdx.x; i < 108 * 64; i += blockDim.x) sW[i] = W_atom[i];
  if (threadIdx.x < 64) sb[threadIdx.x] = b_atom[threadIdx.x];
  if (threadIdx.x < 16) {
    sWc[threadIdx.x] = W_charge[threadIdx.x];
    sbc[threadIdx.x] = b_charge[threadIdx.x];
  }
  int ntiles = (N + 127) >> 7;
  for (int tile = blockIdx.x; tile < ntiles; tile += gridDim.x) {
    int base = tile << 7;
    int cnt = N - base; if (cnt > 128) cnt = 128;
    __syncthreads();
    if (cnt == 128) {
      const float4* src = (const float4*)(x + (size_t)base * 92);
      for (int i = threadIdx.x; i < 2944; i += 256) ((float4*)sX)[i] = src[i];
    } else {
      for (int i = threadIdx.x; i < cnt * 92; i += 256)
        sX[i] = x[(size_t)base * 92 + i];
    }
    __syncthreads();
    int t = threadIdx.x;
    int node = t & 127, half = t >> 7;
    if (node < cnt) {
      int n = base + node;
      float acc[32];
#pragma unroll
      for (int j = 0; j < 32; ++j) acc[j] = sb[half * 32 + j];
      const float* xr = sX + node * 92;
      for (int k = 0; k < 92; ++k) {
        float a = xr[k];
        const float* wk = sW + k * 64 + half * 32;
#pragma unroll
        for (int j = 0; j < 32; ++j) acc[j] = fmaf(a, wk[j], acc[j]);
      }
      float ch = charge[batch[n]];
#pragma unroll
      for (int c = 0; c < 16; ++c) {
        float cf = fmaf(ch, sWc[c], sbc[c]);
        const float* wk = sW + (92 + c) * 64 + half * 32;
#pragma unroll
        for (int j = 0; j < 32; ++j) acc[j] = fmaf(cf, wk[j], acc[j]);
      }
      float* o = xemb + (size_t)n * 64 + half * 32;
#pragma unroll
      for (int q8 = 0; q8 < 8; ++q8)
        ((float4*)o)[q8] = make_float4(acc[4*q8], acc[4*q8+1], acc[4*q8+2], acc[4*q8+3]);
    }
  }
}

// ---------------- CSR build ----------------
__global__ __launch_bounds__(256) void k_hist(const int* __restrict__ col,
                                              int* __restrict__ counts, int E) {
  int stride = gridDim.x * blockDim.x;
  for (int e = blockIdx.x * blockDim.x + threadIdx.x; e < E; e += stride)
    atomicAdd(&counts[col[e]], 1);
}

__global__ __launch_bounds__(256) void k_scan1(const int* __restrict__ counts,
                                               int* __restrict__ scan_tmp,
                                               int* __restrict__ bsum, int N) {
  __shared__ int sd[2][256];
  int t = threadIdx.x;
  int i = blockIdx.x * 256 + t;
  int v = (i < N) ? counts[i] : 0;
  sd[0][t] = v;
  __syncthreads();
  int s = 0;
#pragma unroll
  for (int off = 1; off < 256; off <<= 1) {
    int nv = sd[s][t];
    if (t >= off) nv += sd[s][t - off];
    sd[s ^ 1][t] = nv;
    s ^= 1;
    __syncthreads();
  }
  if (i < N) scan_tmp[i] = sd[s][t];
  if (t == 255) bsum[blockIdx.x] = sd[s][255];
}

__global__ __launch_bounds__(256) void k_scan2(int* __restrict__ b, int NB) {
  __shared__ int sd[2][256];
  __shared__ int carry_s;
  int t = threadIdx.x;
  if (t == 0) carry_s = 0;
  __syncthreads();
  for (int base = 0; base < NB; base += 256) {
    int i = base + t;
    int v = (i < NB) ? b[i] : 0;
    sd[0][t] = v;
    __syncthreads();
    int s = 0;
#pragma unroll
    for (int off = 1; off < 256; off <<= 1) {
      int nv = sd[s][t];
      if (t >= off) nv += sd[s][t - off];
      sd[s ^ 1][t] = nv;
      s ^= 1;
      __syncthreads();
    }
    int c = carry_s;
    int tot = sd[s][255];
    if (i < NB) b[i] = sd[s][t] + c;
    __syncthreads();
    if (t == 0) carry_s = c + tot;
    __syncthreads();
  }
}

__global__ __launch_bounds__(256) void k_scan3(const int* __restrict__ counts,
                                               const int* __restrict__ scan_tmp,
                                               const int* __restrict__ bsum,
                                               int* __restrict__ cursor, int N) {
  int i = blockIdx.x * 256 + threadIdx.x;
  if (i < N) {
    int base = (blockIdx.x > 0) ? bsum[blockIdx.x - 1] : 0;
    cursor[i] = scan_tmp[i] - counts[i] + base;
  }
}

__global__ __launch_bounds__(256) void k_scatter(
    const int* __restrict__ row, const int* __restrict__ col,
    int* __restrict__ cursor, int* __restrict__ pos,
    int* __restrict__ row_s, int* __restrict__ col_s, int E) {
  int stride = gridDim.x * blockDim.x;
  for (int e = blockIdx.x * blockDim.x + threadIdx.x; e < E; e += stride) {
    int c = col[e];
    int p = atomicAdd(&cursor[c], 1);
    pos[e] = p;
    row_s[p] = row[e];
    col_s[p] = c;
  }
}

// ---------------- bond embedding via MFMA: [128 edges x 41] @ [41 x 64] ----------------
__global__ __launch_bounds__(256) void k_embed_bonds_mfma(
    const float* __restrict__ eattr, const int* __restrict__ pos,
    const unsigned short* __restrict__ gWb, const float* __restrict__ b_bond,
    unsigned short* __restrict__ ea16, int E) {
  __shared__ unsigned short sA[128 * 64];  // 16 KB, swizzled
  __shared__ float sb[64];
  __shared__ int spos[128];
  int tid = threadIdx.x;
  int w = tid >> 6, l = tid & 63, q = l >> 4, c16 = l & 15;
  int rbase = w * 32;
  if (tid < 64) sb[tid] = b_bond[tid];
  int ntiles = (E + 127) >> 7;
  for (int tile = blockIdx.x; tile < ntiles; tile += gridDim.x) {
    int te = tile << 7;
    int cnt = E - te; if (cnt > 128) cnt = 128;
    __syncthreads();   // protect sA reuse across loop iterations
    uint4 z = make_uint4(0, 0, 0, 0);
    for (int i = tid; i < 1024; i += 256) ((uint4*)sA)[i] = z;
    __syncthreads();
    // stage + convert coalesced fp32 -> swizzled bf16
    int nflt = cnt * 41;
    for (int i = tid; i < nflt; i += 256) {
      int r = i / 41, k = i - r * 41;
      float v = eattr[(size_t)te * 41 + i];
      sA[r * 64 + (k ^ ((r & 7) << 3))] = f2bf(v);
    }
    if (tid < 128) spos[tid] = (te + tid < E) ? pos[te + tid] : -1;
    __syncthreads();
    // fragments + MFMA (K=64, zero padded)
    v8s bfr[4][2], af[2][2];
    v4f acc[2][4];
    const v8s* wp_ = (const v8s*)gWb;
#pragma unroll
    for (int ct = 0; ct < 4; ++ct)
#pragma unroll
      for (int kh = 0; kh < 2; ++kh)
        bfr[ct][kh] = wp_[(ct * 2 + kh) * 64 + l];
#pragma unroll
    for (int rb = 0; rb < 2; ++rb)
#pragma unroll
      for (int kh = 0; kh < 2; ++kh) {
        int row_ = rbase + rb * 16 + c16;
        af[rb][kh] = *(const v8s*)&sA[row_ * 64 +
                                      ((kh * 32 + q * 8) ^ ((row_ & 7) << 3))];
      }
#pragma unroll
    for (int rb = 0; rb < 2; ++rb)
#pragma unroll
      for (int ct = 0; ct < 4; ++ct) {
        v4f a_ = {0.f, 0.f, 0.f, 0.f};
        a_ = __builtin_amdgcn_mfma_f32_16x16x32_bf16(af[rb][0], bfr[ct][0], a_, 0, 0, 0);
        a_ = __builtin_amdgcn_mfma_f32_16x16x32_bf16(af[rb][1], bfr[ct][1], a_, 0, 0, 0);
        acc[rb][ct] = a_;
      }
    // epilogue: + bias -> bf16 back into own band of sA
#pragma unroll
    for (int rb = 0; rb < 2; ++rb)
#pragma unroll
      for (int ct = 0; ct < 4; ++ct) {
        int n = ct * 16 + c16;
#pragma unroll
        for (int r = 0; r < 4; ++r) {
          float v = acc[rb][ct][r] + sb[n];
          int row = rbase + rb * 16 + q * 4 + r;
          sA[row * 64 + (n ^ ((row & 7) << 3))] = f2bf(v);
        }
      }
    __syncthreads();
    // scatter rows to ea16[pos[e]]
    for (int i = tid; i < 1024; i += 256) {
      int r = i >> 3, cc = i & 7;
      int p = spos[r];
      if (p >= 0) {
        uint4 d = *(const uint4*)&sA[r * 64 + ((cc * 8) ^ ((r & 7) << 3))];
        *(uint4*)&ea16[(size_t)p * 64 + cc * 8] = d;
      }
    }
  }
}

// ---------------- node-side precompute body ----------------
// up16 row layout (interleaved): idx c16*8 + j, j<4 -> u[j*16+c16], j>=4 -> p[(j-4)*16+c16]
// v16 row layout: idx c16*4 + ct -> v[ct*16+c16]
__device__ __forceinline__ void node_pre_body(
    const float* __restrict__ xr, const float* sWa, const float* sWb,
    const float* sWp, unsigned short* __restrict__ up16,
    unsigned short* __restrict__ v16, int n) {
  const float4* xr4 = (const float4*)xr;
  float u[64], p[64];
#pragma unroll
  for (int j = 0; j < 64; ++j) { u[j] = 0.f; p[j] = 0.f; }
  for (int k4 = 0; k4 < 16; ++k4) {
    float4 av = xr4[k4];
    const float* wa = sWa + k4 * 256;
    const float* wp = sWp + k4 * 256;
#pragma unroll
    for (int j = 0; j < 64; ++j) u[j] = fmaf(av.x, wa[j], u[j]);
#pragma unroll
    for (int j = 0; j < 64; ++j) p[j] = fmaf(av.x, wp[j], p[j]);
#pragma unroll
    for (int j = 0; j < 64; ++j) u[j] = fmaf(av.y, wa[64 + j], u[j]);
#pragma unroll
    for (int j = 0; j < 64; ++j) p[j] = fmaf(av.y, wp[64 + j], p[j]);
#pragma unroll
    for (int j = 0; j < 64; ++j) u[j] = fmaf(av.z, wa[128 + j], u[j]);
#pragma unroll
    for (int j = 0; j < 64; ++j) p[j] = fmaf(av.z, wp[128 + j], p[j]);
#pragma unroll
    for (int j = 0; j < 64; ++j) u[j] = fmaf(av.w, wa[192 + j], u[j]);
#pragma unroll
    for (int j = 0; j < 64; ++j) p[j] = fmaf(av.w, wp[192 + j], p[j]);
  }
  unsigned short* o = up16 + (size_t)n * 128;
#pragma unroll
  for (int q8 = 0; q8 < 16; ++q8) {   // q8 == c16
    unsigned short tmp[8];
#pragma unroll
    for (int j = 0; j < 8; ++j)
      tmp[j] = f2bf(j < 4 ? u[j * 16 + q8] : p[(j - 4) * 16 + q8]);
    *(uint4*)&o[q8 * 8] = *(uint4*)tmp;
  }
  float vv[64];
#pragma unroll
  for (int j = 0; j < 64; ++j) vv[j] = 0.f;
  for (int k4 = 0; k4 < 16; ++k4) {
    float4 av = xr4[k4];
    const float* wb = sWb + k4 * 256;
#pragma unroll
    for (int j = 0; j < 64; ++j) vv[j] = fmaf(av.x, wb[j], vv[j]);
#pragma unroll
    for (int j = 0; j < 64; ++j) vv[j] = fmaf(av.y, wb[64 + j], vv[j]);
#pragma unroll
    for (int j = 0; j < 64; ++j) vv[j] = fmaf(av.z, wb[128 + j], vv[j]);
#pragma unroll
    for (int j = 0; j < 64; ++j) vv[j] = fmaf(av.w, wb[192 + j], vv[j]);
  }
  unsigned short* ov = v16 + (size_t)n * 64;
#pragma unroll
  for (int q8 = 0; q8 < 8; ++q8) {
    unsigned short tmp[8];
#pragma unroll
    for (int j = 0; j < 8; ++j) {
      int i = q8 * 8 + j;
      tmp[j] = f2bf(vv[((i & 3) << 4) | (i >> 2)]);
    }
    *(uint4*)&ov[q8 * 8] = *(uint4*)tmp;
  }
}

__global__ __launch_bounds__(256) void k_node_pre(
    const float* __restrict__ xemb, const float* __restrict__ eW1,
    const float* __restrict__ nW1, unsigned short* __restrict__ up16,
    unsigned short* __restrict__ v16, int N) {
  __shared__ float sWa[64 * 64];
  __shared__ float sWb[64 * 64];
  __shared__ float sWp[64 * 64];
  for (int i = threadIdx.x; i < 64 * 64; i += blockDim.x) {
    sWa[i] = eW1[i];
    sWb[i] = eW1[64 * 64 + i];
    sWp[i] = nW1[i];
  }
  __syncthreads();
  int stride = gridDim.x * blockDim.x;
  for (int n = blockIdx.x * blockDim.x + threadIdx.x; n < N; n += stride)
    node_pre_body(xemb + (size_t)n * 64, sWa, sWb, sWp, up16, v16, n);
}

// ---------------- fused BN apply + residual + next-layer node_pre ----------------
__global__ __launch_bounds__(256) void k_bn_pre(
    float* __restrict__ xemb, const float* __restrict__ xnew,
    const float* __restrict__ bnacc, const float* __restrict__ gamma,
    const float* __restrict__ beta, const float* __restrict__ eW1n,
    const float* __restrict__ nW1n, unsigned short* __restrict__ up16,
    unsigned short* __restrict__ v16, int N) {
  __shared__ float sWa[64 * 64];
  __shared__ float sWb[64 * 64];
  __shared__ float sWp[64 * 64];
  __shared__ float sscale[64], sshift[64];
  for (int i = threadIdx.x; i < 64 * 64; i += blockDim.x) {
    sWa[i] = eW1n[i];
    sWb[i] = eW1n[64 * 64 + i];
    sWp[i] = nW1n[i];
  }
  if (threadIdx.x < 64) {
    float inv = 1.0f / (float)N;
    float m = bnacc[threadIdx.x] * inv;
    float var = bnacc[64 + threadIdx.x] * inv - m * m;
    float rs = rsqrtf(var + 1e-5f);
    float g = gamma[threadIdx.x];
    sscale[threadIdx.x] = rs * g;
    sshift[threadIdx.x] = beta[threadIdx.x] - m * rs * g;
  }
  __syncthreads();
  int stride = gridDim.x * blockDim.x;
  for (int n = blockIdx.x * blockDim.x + threadIdx.x; n < N; n += stride) {
    float* xr = xemb + (size_t)n * 64;
#pragma unroll
    for (int q = 0; q < 16; ++q) {
      float4 xn4 = ((const float4*)(xnew + (size_t)n * 64))[q];
      float4 xo4 = ((const float4*)xr)[q];
      xo4.x += sp_f(fmaf(xn4.x, sscale[4*q+0], sshift[4*q+0]));
      xo4.y += sp_f(fmaf(xn4.y, sscale[4*q+1], sshift[4*q+1]));
      xo4.z += sp_f(fmaf(xn4.z, sscale[4*q+2], sshift[4*q+2]));
      xo4.w += sp_f(fmaf(xn4.w, sscale[4*q+3], sshift[4*q+3]));
      ((float4*)xr)[q] = xo4;
    }
    node_pre_body(xr, sWa, sWb, sWp, up16, v16, n);
  }
}

// ---------------- fused per-layer edge kernel, MFMA bf16, 4 waves x 32 rows ----------------
#define READ_FRAGS(P)                                                        \
  {                                                                          \
    const v8s* wp_ = (const v8s*)gWf + (P) * 512;                            \
    _Pragma("unroll") for (int ct = 0; ct < 4; ++ct)                         \
        _Pragma("unroll") for (int kh = 0; kh < 2; ++kh)                     \
            bfr[ct][kh] = wp_[(ct * 2 + kh) * 64 + l];                       \
    _Pragma("unroll") for (int rb = 0; rb < 2; ++rb)                         \
        _Pragma("unroll") for (int kh = 0; kh < 2; ++kh) {                   \
      int row_ = rbase + rb * 16 + c16;                                      \
      af[rb][kh] = *(const v8s*)&sA[row_ * 64 +                              \
                                    ((kh * 32 + q * 8) ^ ((row_ & 7) << 3))];\
    }                                                                        \
  }

#define DO_MFMA()                                                            \
  _Pragma("unroll") for (int rb = 0; rb < 2; ++rb)                           \
      _Pragma("unroll") for (int ct = 0; ct < 4; ++ct) {                     \
    v4f a_ = {0.f, 0.f, 0.f, 0.f};                                           \
    a_ = __builtin_amdgcn_mfma_f32_16x16x32_bf16(af[rb][0], bfr[ct][0], a_,  \
                                                 0, 0, 0);                   \
    a_ = __builtin_amdgcn_mfma_f32_16x16x32_bf16(af[rb][1], bfr[ct][1], a_,  \
                                                 0, 0, 0);                   \
    acc[rb][ct] = a_;                                                        \
  }

__global__ __launch_bounds__(256, 4) void k_edge_mfma(
    const int* __restrict__ row_s, const int* __restrict__ col_s,
    unsigned short* __restrict__ ea16, const unsigned short* __restrict__ up16,
    const unsigned short* __restrict__ v16,
    const unsigned short* __restrict__ gWf, const float* __restrict__ eb1,
    const float* __restrict__ eb2, const float* __restrict__ nb1,
    const float* __restrict__ nb2, float* __restrict__ xnew, int E,
    int store_ea) {
  __shared__ __align__(16) unsigned char smem[34304];
  unsigned short* sA = (unsigned short*)smem;             // 16 KB (aliased)
  float* msgb        = (float*)smem;                      // 32 KB
  float* sBb         = (float*)(smem + 32768);            // 1 KB
  int* scol          = (int*)(smem + 33792);              // 512 B

  int tid = threadIdx.x;
  int te = blockIdx.x * 128;
  int w = tid >> 6, l = tid & 63, q = l >> 4, c16 = l & 15;
  int rbase = w * 32;

  int rid[2][4], cid[2][4], eid[2][4];
#pragma unroll
  for (int rb = 0; rb < 2; ++rb)
#pragma unroll
    for (int r = 0; r < 4; ++r) {
      int e = te + rbase + rb * 16 + q * 4 + r;
      eid[rb][r] = e;
      int ec = e < E ? e : E - 1;
      rid[rb][r] = row_s[ec];
      cid[rb][r] = col_s[ec];
    }
  // single combined u|p gather (16B/lane) + v gather, issued early
  uint4 upv_pf[2][4];
  ushort4 vv_pf[2][4];
#pragma unroll
  for (int rb = 0; rb < 2; ++rb)
#pragma unroll
    for (int r = 0; r < 4; ++r) {
      upv_pf[rb][r] = *(const uint4*)&up16[(size_t)rid[rb][r] * 128 + c16 * 8];
      vv_pf[rb][r] = *(const ushort4*)&v16[(size_t)cid[rb][r] * 64 + c16 * 4];
    }

  if (tid < 64) {
    sBb[0 * 64 + tid] = eb1[tid];
    sBb[1 * 64 + tid] = eb2[tid];
    sBb[2 * 64 + tid] = nb1[tid];
    sBb[3 * 64 + tid] = nb2[tid];
  }
  if (tid < 128) {
    int e = te + tid;
    scol[tid] = col_s[e < E ? e : E - 1];
  }
  for (int i = tid; i < 1024; i += 256) {
    int r = i >> 3, cc = i & 7;
    int e = te + r;
    if (e >= E) e = E - 1;
    uint4 d = *(const uint4*)&ea16[(size_t)e * 64 + cc * 8];
    *(uint4*)&sA[r * 64 + ((cc * 8) ^ ((r & 7) << 3))] = d;
  }

  v8s af[2][2];
  v8s bfr[4][2];
  v4f acc[2][4];

  __syncthreads();   // staging done

  // ---- phase 0: T = sp(ea@W1c + b1 + u[row] + v[col]) ----
  READ_FRAGS(0);
  DO_MFMA();
#pragma unroll
  for (int rb = 0; rb < 2; ++rb)
#pragma unroll
    for (int r = 0; r < 4; ++r) {
      const unsigned short* uv = (const unsigned short*)&upv_pf[rb][r];
      const unsigned short* vp_ = (const unsigned short*)&vv_pf[rb][r];
      int row = rbase + rb * 16 + q * 4 + r;
#pragma unroll
      for (int ct = 0; ct < 4; ++ct) {
        int n = ct * 16 + c16;
        float t = acc[rb][ct][r] + sBb[n] + bf2f(uv[ct]) + bf2f(vp_[ct]);
        t = sp_f(t);
        sA[row * 64 + (n ^ ((row & 7) << 3))] = f2bf(t);
      }
    }

  // ---- phase 1: ea' = T@eW2 + b2 -> sA (own band) ----
  READ_FRAGS(1);
  DO_MFMA();
#pragma unroll
  for (int rb = 0; rb < 2; ++rb)
#pragma unroll
    for (int ct = 0; ct < 4; ++ct) {
      int n = ct * 16 + c16;
#pragma unroll
      for (int r = 0; r < 4; ++r) {
        float en = acc[rb][ct][r] + sBb[64 + n];
        int row = rbase + rb * 16 + q * 4 + r;
        sA[row * 64 + (n ^ ((row & 7) << 3))] = f2bf(en);
      }
    }
  __syncthreads();   // writeback reads all rows
  if (store_ea) {
    for (int i = tid; i < 1024; i += 256) {
      int r = i >> 3, cc = i & 7;
      if (te + r < E) {
        uint4 d = *(const uint4*)&sA[r * 64 + ((cc * 8) ^ ((r & 7) << 3))];
        *(uint4*)&ea16[(size_t)(te + r) * 64 + cc * 8] = d;
      }
    }
  }
  __syncthreads();   // phase-2 epi writes must not race writeback reads

  // ---- phase 2: T2 = sp(ea'@nW1b + b3 + p[row]) ----
  READ_FRAGS(2);
  DO_MFMA();
#pragma unroll
  for (int rb = 0; rb < 2; ++rb)
#pragma unroll
    for (int r = 0; r < 4; ++r) {
      const unsigned short* uv = (const unsigned short*)&upv_pf[rb][r];
      int row = rbase + rb * 16 + q * 4 + r;
#pragma unroll
      for (int ct = 0; ct < 4; ++ct) {
        int n = ct * 16 + c16;
        float t2 = acc[rb][ct][r] + sBb[128 + n] + bf2f(uv[4 + ct]);
        t2 = sp_f(t2);
        sA[row * 64 + (n ^ ((row & 7) << 3))] = f2bf(t2);
      }
    }

  // ---- phase 3: msg = T2@nW2 + b4 -> msgb (sA dead after frag loads) ----
  READ_FRAGS(3);
  __syncthreads();   // all waves done reading sA; msgb alias safe
  DO_MFMA();
#pragma unroll
  for (int rb = 0; rb < 2; ++rb)
#pragma unroll
    for (int ct = 0; ct < 4; ++ct) {
      int n = ct * 16 + c16;
#pragma unroll
      for (int r = 0; r < 4; ++r) {
        float msg = acc[rb][ct][r] + sBb[192 + n];
        int row = rbase + rb * 16 + q * 4 + r;
        msgb[row * 64 + n] = (eid[rb][r] < E) ? msg : 0.0f;
      }
    }
  __syncthreads();

  // ---- segmented reduction; plain store for interior (exclusive) segments ----
  int nrows = E - te;
  if (nrows > 128) nrows = 128;
  for (int r0 = w; r0 < nrows; r0 += 4) {
    int c0 = scol[r0];
    if (r0 > 0 && scol[r0 - 1] == c0) continue;
    float s = 0.0f;
    int r = r0;
    do {
      s += msgb[r * 64 + l];
      ++r;
    } while (r < nrows && scol[r] == c0);
    if (r0 > 0 && r < nrows)
      xnew[(size_t)c0 * 64 + l] = s;     // run fully interior: exclusive writer
    else
      atomicAdd(&xnew[(size_t)c0 * 64 + l], s);
  }
}

// ---------------- BN stats ----------------
__global__ __launch_bounds__(256) void k_bn_stats(
    const float* __restrict__ xnew, float* __restrict__ bnacc, int N) {
  int t = threadIdx.x;
  int ch = t & 63;
  int sl = t >> 6;
  float s = 0.f, s2 = 0.f;
  for (int n = blockIdx.x * 4 + sl; n < N; n += gridDim.x * 4) {
    float v = xnew[(size_t)n * 64 + ch];
    s += v;
    s2 = fmaf(v, v, s2);
  }
  __shared__ float red[256], red2[256];
  red[t] = s;
  red2[t] = s2;
  __syncthreads();
  if (sl == 0) {
    s = red[ch] + red[64 + ch] + red[128 + ch] + red[192 + ch];
    s2 = red2[ch] + red2[64 + ch] + red2[128 + ch] + red2[192 + ch];
    atomicAdd(&bnacc[ch], s);
    atomicAdd(&bnacc[64 + ch], s2);
  }
}

// ---------------- BN apply + softplus + residual (last layer) ----------------
__global__ __launch_bounds__(256) void k_bn_apply(
    float* __restrict__ x, const float* __restrict__ xnew,
    const float* __restrict__ bnacc, const float* __restrict__ gamma,
    const float* __restrict__ beta, int N) {
  __shared__ float sscale[64], sshift[64];
  if (threadIdx.x < 64) {
    float inv = 1.0f / (float)N;
    float m = bnacc[threadIdx.x] * inv;
    float var = bnacc[64 + threadIdx.x] * inv - m * m;
    float rs = rsqrtf(var + 1e-5f);
    float g = gamma[threadIdx.x];
    sscale[threadIdx.x] = rs * g;
    sshift[threadIdx.x] = beta[threadIdx.x] - m * rs * g;
  }
  __syncthreads();
  size_t total = (size_t)N * 64;
  size_t stride = (size_t)gridDim.x * blockDim.x;
  for (size_t i = (size_t)blockIdx.x * blockDim.x + threadIdx.x; i < total; i += stride) {
    int ch = (int)(i & 63);
    float v = fmaf(xnew[i], sscale[ch], sshift[ch]);
    x[i] += sp_f(v);
  }
}

// ---------------- fused pool + predictor ----------------
__device__ __forceinline__ int lbound(const int* a, int n, int key) {
  int lo = 0, hi = n;
  while (lo < hi) {
    int mid = (lo + hi) >> 1;
    if (a[mid] < key) lo = mid + 1; else hi = mid;
  }
  return lo;
}

__global__ __launch_bounds__(256) void k_pool_pred(
    const float* __restrict__ x, const int* __restrict__ batch, int N,
    const float* __restrict__ pW1, const float* __restrict__ pb1,
    const float* __restrict__ pW2, const float* __restrict__ pb2,
    const float* __restrict__ pW3, const float* __restrict__ pb3,
    float* __restrict__ out) {
  int b = blockIdx.x;
  int lo = lbound(batch, N, b);
  int hi = lbound(batch, N, b + 1);
  int t = threadIdx.x;
  int ch = t & 63;
  int sl = t >> 6;
  float s = 0.f;
  for (int n = lo + sl; n < hi; n += 4) s += x[(size_t)n * 64 + ch];
  __shared__ float red4[4][64];
  __shared__ float sg[64];
  __shared__ float sh1[128];
  __shared__ float red[128];
  red4[sl][ch] = s;
  __syncthreads();
  if (t < 64) {
    float tot = red4[0][t] + red4[1][t] + red4[2][t] + red4[3][t];
    float cnt = (float)(hi - lo);
    sg[t] = tot / fmaxf(cnt, 1.0f);
  }
  __syncthreads();
  if (t < 128) {
    float h = pb1[t];
    for (int k = 0; k < 64; ++k) h = fmaf(sg[k], pW1[k * 128 + t], h);
    sh1[t] = sp_f(h);
  }
  __syncthreads();
  if (t < 128) {
    float h = pb2[t];
    for (int k = 0; k < 128; ++k) h = fmaf(sh1[k], pW2[k * 128 + t], h);
    red[t] = sp_f(h) * pW3[t];
  }
  __syncthreads();
  for (int off = 64; off > 0; off >>= 1) {
    if (t < off) red[t] += red[t + off];
    __syncthreads();
  }
  if (t == 0) out[b] = red[0] + pb3[0];
}

extern "C" void kernel_launch(void* const* d_in, const int* in_sizes, int n_in,
                              void* d_out, int out_size, void* d_ws, size_t ws_size,
                              hipStream_t stream) {
  const float* x         = (const float*)d_in[0];
  const float* edge_attr = (const float*)d_in[1];
  const float* charge    = (const float*)d_in[2];
  const int*   eidx      = (const int*)d_in[3];
  const int*   batch     = (const int*)d_in[4];
  const float* W_charge  = (const float*)d_in[5];
  const float* b_charge  = (const float*)d_in[6];
  const float* W_atom    = (const float*)d_in[7];
  const float* b_atom    = (const float*)d_in[8];
  const float* W_bond    = (const float*)d_in[9];
  const float* b_bond    = (const float*)d_in[10];
  const float* eW1 = (const float*)d_in[11];
  const float* eb1 = (const float*)d_in[12];
  const float* eW2 = (const float*)d_in[13];
  const float* eb2 = (const float*)d_in[14];
  const float* nW1 = (const float*)d_in[15];
  const float* nb1 = (const float*)d_in[16];
  const float* nW2 = (const float*)d_in[17];
  const float* nb2 = (const float*)d_in[18];
  const float* gam = (const float*)d_in[19];
  const float* bet = (const float*)d_in[20];
  const float* pW1 = (const float*)d_in[21];
  const float* pb1 = (const float*)d_in[22];
  const float* pW2 = (const float*)d_in[23];
  const float* pb2 = (const float*)d_in[24];
  const float* pW3 = (const float*)d_in[25];
  const float* pb3 = (const float*)d_in[26];

  int N = in_sizes[4];
  int E = in_sizes[3] / 2;
  int B = in_sizes[2];
  const int* row = eidx;
  const int* col = eidx + E;

  char* wptr = (char*)d_ws;
  unsigned short* ea16 = (unsigned short*)wptr; wptr += (((size_t)E * 64 * 2 + 255) & ~255ull);
  unsigned short* up16 = (unsigned short*)wptr; wptr += (((size_t)N * 128 * 2 + 255) & ~255ull);
  unsigned short* v16  = (unsigned short*)wptr; wptr += (((size_t)N * 64 * 2 + 255) & ~255ull);
  unsigned short* wfrag = (unsigned short*)wptr; wptr += 13 * 4096 * 2;
  float* xemb = (float*)wptr; wptr += (size_t)N * 64 * 4;
  float* xnew = (float*)wptr; wptr += (size_t)N * 64 * 4;
  float* bnacc = (float*)wptr; wptr += 256 * 4;
  int* counts = (int*)wptr;   wptr += (size_t)N * 4;
  int* scan_tmp = (int*)wptr; wptr += (size_t)N * 4;
  int* cursor = (int*)wptr;   wptr += (size_t)N * 4;
  int* bsum = (int*)wptr;     wptr += 4096;
  int* pos = (int*)wptr;      wptr += (size_t)E * 4;
  int* row_s = (int*)wptr;    wptr += (size_t)E * 4;
  int* col_s = (int*)wptr;    wptr += (size_t)E * 4;

  int NB = (N + 255) / 256;

  k_prep_wfrag<<<13, 256, 0, stream>>>(eW1, eW2, nW1, nW2, W_bond, wfrag);
  hipMemsetAsync(counts, 0, (size_t)N * 4, stream);
  k_hist<<<2048, 256, 0, stream>>>(col, counts, E);
  k_scan1<<<NB, 256, 0, stream>>>(counts, scan_tmp, bsum, N);
  k_scan2<<<1, 256, 0, stream>>>(bsum, NB);
  k_scan3<<<NB, 256, 0, stream>>>(counts, scan_tmp, bsum, cursor, N);
  k_scatter<<<2048, 256, 0, stream>>>(row, col, cursor, pos, row_s, col_s, E);

  int ntilesN = (N + 127) / 128;
  k_embed_nodes<<<ntilesN, 256, 0, stream>>>(x, batch, charge, W_charge,
                                             b_charge, W_atom, b_atom, xemb, N);
  k_embed_bonds_mfma<<<2048, 256, 0, stream>>>(edge_attr, pos,
                                               wfrag + 12 * 4096, b_bond,
                                               ea16, E);
  k_node_pre<<<NB, 256, 0, stream>>>(xemb, eW1, nW1, up16, v16, N);

  int gridE = (E + 127) / 128;
  for (int i = 0; i < 3; ++i) {
    hipMemsetAsync(xnew, 0, (size_t)N * 64 * 4, stream);
    hipMemsetAsync(bnacc, 0, 256 * 4, stream);
    k_edge_mfma<<<gridE, 256, 0, stream>>>(
        row_s, col_s, ea16, up16, v16, wfrag + (size_t)i * 16384,
        eb1 + (size_t)i * 64, eb2 + (size_t)i * 64, nb1 + (size_t)i * 64,
        nb2 + (size_t)i * 64, xnew, E, (i < 2) ? 1 : 0);
    k_bn_stats<<<1024, 256, 0, stream>>>(xnew, bnacc, N);
    if (i < 2) {
      k_bn_pre<<<NB, 256, 0, stream>>>(
          xemb, xnew, bnacc, gam + (size_t)i * 64, bet + (size_t)i * 64,
          eW1 + (size_t)(i + 1) * 192 * 64, nW1 + (size_t)(i + 1) * 128 * 64,
          up16, v16, N);
    } else {
      k_bn_apply<<<4096, 256, 0, stream>>>(xemb, xnew, bnacc,
                                           gam + (size_t)i * 64,
                                           bet + (size_t)i * 64, N);
    }
  }

  k_pool_pred<<<B, 256, 0, stream>>>(xemb, batch, N, pW1, pb1, pW2, pb2,
                                     pW3, pb3, (float*)d_out);
}

// Round 10
// 2168.491 us; speedup vs baseline: 1.0240x; 1.0025x over previous
//
#include <hip/hip_runtime.h>
#include <math.h>

typedef short v8s __attribute__((ext_vector_type(8)));   // 8 bf16
typedef float v4f __attribute__((ext_vector_type(4)));
typedef unsigned int u32x4 __attribute__((ext_vector_type(4)));

__device__ __forceinline__ u32x4 nt_load4(const void* p) {
  return __builtin_nontemporal_load((const u32x4*)p);
}
__device__ __forceinline__ void nt_store4(void* p, u32x4 v) {
  __builtin_nontemporal_store(v, (u32x4*)p);
}

// fast softplus: max(x,0) + ln2*log2(1+exp(-|x|)); HW exp/log, ~3e-5 abs err
__device__ __forceinline__ float sp_f(float x) {
  return fmaxf(x, 0.0f) + 0.69314718056f * __log2f(1.0f + __expf(-fabsf(x)));
}

__device__ __forceinline__ unsigned short f2bf(float f) {
  union { float f; unsigned u; } x; x.f = f;
  unsigned r = (x.u + 0x7FFF + ((x.u >> 16) & 1)) >> 16;
  return (unsigned short)r;
}

__device__ __forceinline__ float bf2f(unsigned short h) {
  union { unsigned u; float f; } x; x.u = ((unsigned)h) << 16;
  return x.f;
}

// ---------------- one-shot weight fragment prep (3 layers x 4 mats + W_bond) ----------------
__global__ __launch_bounds__(256) void k_prep_wfrag(
    const float* __restrict__ eW1, const float* __restrict__ eW2,
    const float* __restrict__ nW1, const float* __restrict__ nW2,
    const float* __restrict__ W_bond, unsigned short* __restrict__ wfrag) {
  if (blockIdx.x == 12) {
    unsigned short* out = wfrag + 12 * 4096;
    for (int f = threadIdx.x; f < 4096; f += 256) {
      int j = f & 7, ln = (f >> 3) & 63, kh = (f >> 9) & 1, ct = f >> 10;
      int k = kh * 32 + (ln >> 4) * 8 + j;
      int n = ct * 16 + (ln & 15);
      out[f] = (k < 41) ? f2bf(W_bond[k * 64 + n]) : 0;
    }
    return;
  }
  int i = blockIdx.x >> 2;   // layer
  int m = blockIdx.x & 3;    // matrix
  const float* W;
  if (m == 0)      W = eW1 + (size_t)i * 192 * 64 + 128 * 64;  // W1c
  else if (m == 1) W = eW2 + (size_t)i * 64 * 64;
  else if (m == 2) W = nW1 + (size_t)i * 128 * 64 + 64 * 64;   // nW1b
  else             W = nW2 + (size_t)i * 64 * 64;
  unsigned short* out = wfrag + ((size_t)i * 4 + m) * 4096;
  for (int f = threadIdx.x; f < 4096; f += 256) {
    int j = f & 7, ln = (f >> 3) & 63, kh = (f >> 9) & 1, ct = f >> 10;
    int k = kh * 32 + (ln >> 4) * 8 + j;
    int n = ct * 16 + (ln & 15);
    out[f] = f2bf(W[k * 64 + n]);
  }
}

// ---------------- node embedding, LDS-staged tiles + channel split ----------------
__global__ __launch_bounds__(256) void k_embed_nodes(
    const float* __restrict__ x, const int* __restrict__ batch,
    const float* __restrict__ charge, const float* __restrict__ W_charge,
    const float* __restrict__ b_charge, const float* __restrict__ W_atom,
    const float* __restrict__ b_atom, float* __restrict__ xemb, int N) {
  __shared__ float sW[108 * 64];   // 27.6 KB
  __shared__ float sX[128 * 92];   // 46 KB
  __shared__ float sb[64];
  __shared__ float sWc[16];
  __shared__ float sbc[16];
  for (int i = threadIdx.x; i < 108 * 64; i += blockDim.x) sW[i] = W_atom[i];
  if (threadIdx.x < 64) sb[threadIdx.x] = b_atom[threadIdx.x];
  if (threadIdx.x < 16) {
    sWc[threadIdx.x] = W_charge[threadIdx.x];
    sbc[threadIdx.x] = b_charge[threadIdx.x];
  }
  int ntiles = (N + 127) >> 7;
  for (int tile = blockIdx.x; tile < ntiles; tile += gridDim.x) {
    int base = tile << 7;
    int cnt = N - base; if (cnt > 128) cnt = 128;
    __syncthreads();
    if (cnt == 128) {
      const u32x4* src = (const u32x4*)(x + (size_t)base * 92);
      for (int i = threadIdx.x; i < 2944; i += 256)
        ((u32x4*)sX)[i] = nt_load4(&src[i]);
    } else {
      for (int i = threadIdx.x; i < cnt * 92; i += 256)
        sX[i] = x[(size_t)base * 92 + i];
    }
    __syncthreads();
    int t = threadIdx.x;
    int node = t & 127, half = t >> 7;
    if (node < cnt) {
      int n = base + node;
      float acc[32];
#pragma unroll
      for (int j = 0; j < 32; ++j) acc[j] = sb[half * 32 + j];
      const float* xr = sX + node * 92;
      for (int k = 0; k < 92; ++k) {
        float a = xr[k];
        const float* wk = sW + k * 64 + half * 32;
#pragma unroll
        for (int j = 0; j < 32; ++j) acc[j] = fmaf(a, wk[j], acc[j]);
      }
      float ch = charge[batch[n]];
#pragma unroll
      for (int c = 0; c < 16; ++c) {
        float cf = fmaf(ch, sWc[c], sbc[c]);
        const float* wk = sW + (92 + c) * 64 + half * 32;
#pragma unroll
        for (int j = 0; j < 32; ++j) acc[j] = fmaf(cf, wk[j], acc[j]);
      }
      float* o = xemb + (size_t)n * 64 + half * 32;
#pragma unroll
      for (int q8 = 0; q8 < 8; ++q8)
        ((float4*)o)[q8] = make_float4(acc[4*q8], acc[4*q8+1], acc[4*q8+2], acc[4*q8+3]);
    }
  }
}

// ---------------- CSR build ----------------
__global__ __launch_bounds__(256) void k_hist(const int* __restrict__ col,
                                              int* __restrict__ counts, int E) {
  int stride = gridDim.x * blockDim.x;
  for (int e = blockIdx.x * blockDim.x + threadIdx.x; e < E; e += stride)
    atomicAdd(&counts[col[e]], 1);
}

__global__ __launch_bounds__(256) void k_scan1(const int* __restrict__ counts,
                                               int* __restrict__ scan_tmp,
                                               int* __restrict__ bsum, int N) {
  __shared__ int sd[2][256];
  int t = threadIdx.x;
  int i = blockIdx.x * 256 + t;
  int v = (i < N) ? counts[i] : 0;
  sd[0][t] = v;
  __syncthreads();
  int s = 0;
#pragma unroll
  for (int off = 1; off < 256; off <<= 1) {
    int nv = sd[s][t];
    if (t >= off) nv += sd[s][t - off];
    sd[s ^ 1][t] = nv;
    s ^= 1;
    __syncthreads();
  }
  if (i < N) scan_tmp[i] = sd[s][t];
  if (t == 255) bsum[blockIdx.x] = sd[s][255];
}

__global__ __launch_bounds__(256) void k_scan2(int* __restrict__ b, int NB) {
  __shared__ int sd[2][256];
  __shared__ int carry_s;
  int t = threadIdx.x;
  if (t == 0) carry_s = 0;
  __syncthreads();
  for (int base = 0; base < NB; base += 256) {
    int i = base + t;
    int v = (i < NB) ? b[i] : 0;
    sd[0][t] = v;
    __syncthreads();
    int s = 0;
#pragma unroll
    for (int off = 1; off < 256; off <<= 1) {
      int nv = sd[s][t];
      if (t >= off) nv += sd[s][t - off];
      sd[s ^ 1][t] = nv;
      s ^= 1;
      __syncthreads();
    }
    int c = carry_s;
    int tot = sd[s][255];
    if (i < NB) b[i] = sd[s][t] + c;
    __syncthreads();
    if (t == 0) carry_s = c + tot;
    __syncthreads();
  }
}

__global__ __launch_bounds__(256) void k_scan3(const int* __restrict__ counts,
                                               const int* __restrict__ scan_tmp,
                                               const int* __restrict__ bsum,
                                               int* __restrict__ cursor, int N) {
  int i = blockIdx.x * 256 + threadIdx.x;
  if (i < N) {
    int base = (blockIdx.x > 0) ? bsum[blockIdx.x - 1] : 0;
    cursor[i] = scan_tmp[i] - counts[i] + base;
  }
}

__global__ __launch_bounds__(256) void k_scatter(
    const int* __restrict__ row, const int* __restrict__ col,
    int* __restrict__ cursor, int* __restrict__ pos,
    int* __restrict__ row_s, int* __restrict__ col_s, int E) {
  int stride = gridDim.x * blockDim.x;
  for (int e = blockIdx.x * blockDim.x + threadIdx.x; e < E; e += stride) {
    int c = col[e];
    int p = atomicAdd(&cursor[c], 1);
    pos[e] = p;
    row_s[p] = row[e];
    col_s[p] = c;
  }
}

// ---------------- bond embedding via MFMA: [128 edges x 41] @ [41 x 64] ----------------
__global__ __launch_bounds__(256) void k_embed_bonds_mfma(
    const float* __restrict__ eattr, const int* __restrict__ pos,
    const unsigned short* __restrict__ gWb, const float* __restrict__ b_bond,
    unsigned short* __restrict__ ea16, int E) {
  __shared__ unsigned short sA[128 * 64];  // 16 KB, swizzled
  __shared__ float sb[64];
  __shared__ int spos[128];
  int tid = threadIdx.x;
  int w = tid >> 6, l = tid & 63, q = l >> 4, c16 = l & 15;
  int rbase = w * 32;
  if (tid < 64) sb[tid] = b_bond[tid];
  int ntiles = (E + 127) >> 7;
  for (int tile = blockIdx.x; tile < ntiles; tile += gridDim.x) {
    int te = tile << 7;
    int cnt = E - te; if (cnt > 128) cnt = 128;
    __syncthreads();   // protect sA reuse across loop iterations
    uint4 z = make_uint4(0, 0, 0, 0);
    for (int i = tid; i < 1024; i += 256) ((uint4*)sA)[i] = z;
    __syncthreads();
    // stage + convert coalesced fp32 -> swizzled bf16 (nontemporal stream read)
    int nflt = cnt * 41;
    for (int i = tid; i < nflt; i += 256) {
      int r = i / 41, k = i - r * 41;
      float v = __builtin_nontemporal_load(&eattr[(size_t)te * 41 + i]);
      sA[r * 64 + (k ^ ((r & 7) << 3))] = f2bf(v);
    }
    if (tid < 128) spos[tid] = (te + tid < E) ? pos[te + tid] : -1;
    __syncthreads();
    v8s bfr[4][2], af[2][2];
    v4f acc[2][4];
    const v8s* wp_ = (const v8s*)gWb;
#pragma unroll
    for (int ct = 0; ct < 4; ++ct)
#pragma unroll
      for (int kh = 0; kh < 2; ++kh)
        bfr[ct][kh] = wp_[(ct * 2 + kh) * 64 + l];
#pragma unroll
    for (int rb = 0; rb < 2; ++rb)
#pragma unroll
      for (int kh = 0; kh < 2; ++kh) {
        int row_ = rbase + rb * 16 + c16;
        af[rb][kh] = *(const v8s*)&sA[row_ * 64 +
                                      ((kh * 32 + q * 8) ^ ((row_ & 7) << 3))];
      }
#pragma unroll
    for (int rb = 0; rb < 2; ++rb)
#pragma unroll
      for (int ct = 0; ct < 4; ++ct) {
        v4f a_ = {0.f, 0.f, 0.f, 0.f};
        a_ = __builtin_amdgcn_mfma_f32_16x16x32_bf16(af[rb][0], bfr[ct][0], a_, 0, 0, 0);
        a_ = __builtin_amdgcn_mfma_f32_16x16x32_bf16(af[rb][1], bfr[ct][1], a_, 0, 0, 0);
        acc[rb][ct] = a_;
      }
#pragma unroll
    for (int rb = 0; rb < 2; ++rb)
#pragma unroll
      for (int ct = 0; ct < 4; ++ct) {
        int n = ct * 16 + c16;
#pragma unroll
        for (int r = 0; r < 4; ++r) {
          float v = acc[rb][ct][r] + sb[n];
          int row = rbase + rb * 16 + q * 4 + r;
          sA[row * 64 + (n ^ ((row & 7) << 3))] = f2bf(v);
        }
      }
    __syncthreads();
    // scatter rows to ea16[pos[e]] (nontemporal stream write)
    for (int i = tid; i < 1024; i += 256) {
      int r = i >> 3, cc = i & 7;
      int p = spos[r];
      if (p >= 0) {
        u32x4 d = *(const u32x4*)&sA[r * 64 + ((cc * 8) ^ ((r & 7) << 3))];
        nt_store4(&ea16[(size_t)p * 64 + cc * 8], d);
      }
    }
  }
}

// ---------------- node-side precompute body ----------------
// up16 row layout (interleaved): idx c16*8 + j, j<4 -> u[j*16+c16], j>=4 -> p[(j-4)*16+c16]
// v16 row layout: idx c16*4 + ct -> v[ct*16+c16]
__device__ __forceinline__ void node_pre_body(
    const float* __restrict__ xr, const float* sWa, const float* sWb,
    const float* sWp, unsigned short* __restrict__ up16,
    unsigned short* __restrict__ v16, int n) {
  const float4* xr4 = (const float4*)xr;
  float u[64], p[64];
#pragma unroll
  for (int j = 0; j < 64; ++j) { u[j] = 0.f; p[j] = 0.f; }
  for (int k4 = 0; k4 < 16; ++k4) {
    float4 av = xr4[k4];
    const float* wa = sWa + k4 * 256;
    const float* wp = sWp + k4 * 256;
#pragma unroll
    for (int j = 0; j < 64; ++j) u[j] = fmaf(av.x, wa[j], u[j]);
#pragma unroll
    for (int j = 0; j < 64; ++j) p[j] = fmaf(av.x, wp[j], p[j]);
#pragma unroll
    for (int j = 0; j < 64; ++j) u[j] = fmaf(av.y, wa[64 + j], u[j]);
#pragma unroll
    for (int j = 0; j < 64; ++j) p[j] = fmaf(av.y, wp[64 + j], p[j]);
#pragma unroll
    for (int j = 0; j < 64; ++j) u[j] = fmaf(av.z, wa[128 + j], u[j]);
#pragma unroll
    for (int j = 0; j < 64; ++j) p[j] = fmaf(av.z, wp[128 + j], p[j]);
#pragma unroll
    for (int j = 0; j < 64; ++j) u[j] = fmaf(av.w, wa[192 + j], u[j]);
#pragma unroll
    for (int j = 0; j < 64; ++j) p[j] = fmaf(av.w, wp[192 + j], p[j]);
  }
  unsigned short* o = up16 + (size_t)n * 128;
#pragma unroll
  for (int q8 = 0; q8 < 16; ++q8) {   // q8 == c16
    unsigned short tmp[8];
#pragma unroll
    for (int j = 0; j < 8; ++j)
      tmp[j] = f2bf(j < 4 ? u[j * 16 + q8] : p[(j - 4) * 16 + q8]);
    *(uint4*)&o[q8 * 8] = *(uint4*)tmp;
  }
  float vv[64];
#pragma unroll
  for (int j = 0; j < 64; ++j) vv[j] = 0.f;
  for (int k4 = 0; k4 < 16; ++k4) {
    float4 av = xr4[k4];
    const float* wb = sWb + k4 * 256;
#pragma unroll
    for (int j = 0; j < 64; ++j) vv[j] = fmaf(av.x, wb[j], vv[j]);
#pragma unroll
    for (int j = 0; j < 64; ++j) vv[j] = fmaf(av.y, wb[64 + j], vv[j]);
#pragma unroll
    for (int j = 0; j < 64; ++j) vv[j] = fmaf(av.z, wb[128 + j], vv[j]);
#pragma unroll
    for (int j = 0; j < 64; ++j) vv[j] = fmaf(av.w, wb[192 + j], vv[j]);
  }
  unsigned short* ov = v16 + (size_t)n * 64;
#pragma unroll
  for (int q8 = 0; q8 < 8; ++q8) {
    unsigned short tmp[8];
#pragma unroll
    for (int j = 0; j < 8; ++j) {
      int i = q8 * 8 + j;
      tmp[j] = f2bf(vv[((i & 3) << 4) | (i >> 2)]);
    }
    *(uint4*)&ov[q8 * 8] = *(uint4*)tmp;
  }
}

__global__ __launch_bounds__(256) void k_node_pre(
    const float* __restrict__ xemb, const float* __restrict__ eW1,
    const float* __restrict__ nW1, unsigned short* __restrict__ up16,
    unsigned short* __restrict__ v16, int N) {
  __shared__ float sWa[64 * 64];
  __shared__ float sWb[64 * 64];
  __shared__ float sWp[64 * 64];
  for (int i = threadIdx.x; i < 64 * 64; i += blockDim.x) {
    sWa[i] = eW1[i];
    sWb[i] = eW1[64 * 64 + i];
    sWp[i] = nW1[i];
  }
  __syncthreads();
  int stride = gridDim.x * blockDim.x;
  for (int n = blockIdx.x * blockDim.x + threadIdx.x; n < N; n += stride)
    node_pre_body(xemb + (size_t)n * 64, sWa, sWb, sWp, up16, v16, n);
}

// ---------------- fused BN apply + residual + next-layer node_pre ----------------
__global__ __launch_bounds__(256) void k_bn_pre(
    float* __restrict__ xemb, const float* __restrict__ xnew,
    const float* __restrict__ bnacc, const float* __restrict__ gamma,
    const float* __restrict__ beta, const float* __restrict__ eW1n,
    const float* __restrict__ nW1n, unsigned short* __restrict__ up16,
    unsigned short* __restrict__ v16, int N) {
  __shared__ float sWa[64 * 64];
  __shared__ float sWb[64 * 64];
  __shared__ float sWp[64 * 64];
  __shared__ float sscale[64], sshift[64];
  for (int i = threadIdx.x; i < 64 * 64; i += blockDim.x) {
    sWa[i] = eW1n[i];
    sWb[i] = eW1n[64 * 64 + i];
    sWp[i] = nW1n[i];
  }
  if (threadIdx.x < 64) {
    float inv = 1.0f / (float)N;
    float m = bnacc[threadIdx.x] * inv;
    float var = bnacc[64 + threadIdx.x] * inv - m * m;
    float rs = rsqrtf(var + 1e-5f);
    float g = gamma[threadIdx.x];
    sscale[threadIdx.x] = rs * g;
    sshift[threadIdx.x] = beta[threadIdx.x] - m * rs * g;
  }
  __syncthreads();
  int stride = gridDim.x * blockDim.x;
  for (int n = blockIdx.x * blockDim.x + threadIdx.x; n < N; n += stride) {
    float* xr = xemb + (size_t)n * 64;
#pragma unroll
    for (int q = 0; q < 16; ++q) {
      float4 xn4 = ((const float4*)(xnew + (size_t)n * 64))[q];
      float4 xo4 = ((const float4*)xr)[q];
      xo4.x += sp_f(fmaf(xn4.x, sscale[4*q+0], sshift[4*q+0]));
      xo4.y += sp_f(fmaf(xn4.y, sscale[4*q+1], sshift[4*q+1]));
      xo4.z += sp_f(fmaf(xn4.z, sscale[4*q+2], sshift[4*q+2]));
      xo4.w += sp_f(fmaf(xn4.w, sscale[4*q+3], sshift[4*q+3]));
      ((float4*)xr)[q] = xo4;
    }
    node_pre_body(xr, sWa, sWb, sWp, up16, v16, n);
  }
}

// ---------------- fused per-layer edge kernel, MFMA bf16, 4 waves x 32 rows ----------------
#define READ_FRAGS(P)                                                        \
  {                                                                          \
    const v8s* wp_ = (const v8s*)gWf + (P) * 512;                            \
    _Pragma("unroll") for (int ct = 0; ct < 4; ++ct)                         \
        _Pragma("unroll") for (int kh = 0; kh < 2; ++kh)                     \
            bfr[ct][kh] = wp_[(ct * 2 + kh) * 64 + l];                       \
    _Pragma("unroll") for (int rb = 0; rb < 2; ++rb)                         \
        _Pragma("unroll") for (int kh = 0; kh < 2; ++kh) {                   \
      int row_ = rbase + rb * 16 + c16;                                      \
      af[rb][kh] = *(const v8s*)&sA[row_ * 64 +                              \
                                    ((kh * 32 + q * 8) ^ ((row_ & 7) << 3))];\
    }                                                                        \
  }

#define DO_MFMA()                                                            \
  _Pragma("unroll") for (int rb = 0; rb < 2; ++rb)                           \
      _Pragma("unroll") for (int ct = 0; ct < 4; ++ct) {                     \
    v4f a_ = {0.f, 0.f, 0.f, 0.f};                                           \
    a_ = __builtin_amdgcn_mfma_f32_16x16x32_bf16(af[rb][0], bfr[ct][0], a_,  \
                                                 0, 0, 0);                   \
    a_ = __builtin_amdgcn_mfma_f32_16x16x32_bf16(af[rb][1], bfr[ct][1], a_,  \
                                                 0, 0, 0);                   \
    acc[rb][ct] = a_;                                                        \
  }

__global__ __launch_bounds__(256, 4) void k_edge_mfma(
    const int* __restrict__ row_s, const int* __restrict__ col_s,
    unsigned short* __restrict__ ea16, const unsigned short* __restrict__ up16,
    const unsigned short* __restrict__ v16,
    const unsigned short* __restrict__ gWf, const float* __restrict__ eb1,
    const float* __restrict__ eb2, const float* __restrict__ nb1,
    const float* __restrict__ nb2, float* __restrict__ xnew, int E,
    int store_ea) {
  __shared__ __align__(16) unsigned char smem[34304];
  unsigned short* sA = (unsigned short*)smem;             // 16 KB (aliased)
  float* msgb        = (float*)smem;                      // 32 KB
  float* sBb         = (float*)(smem + 32768);            // 1 KB
  int* scol          = (int*)(smem + 33792);              // 512 B

  int tid = threadIdx.x;
  int te = blockIdx.x * 128;
  int w = tid >> 6, l = tid & 63, q = l >> 4, c16 = l & 15;
  int rbase = w * 32;

  int rid[2][4], cid[2][4], eid[2][4];
#pragma unroll
  for (int rb = 0; rb < 2; ++rb)
#pragma unroll
    for (int r = 0; r < 4; ++r) {
      int e = te + rbase + rb * 16 + q * 4 + r;
      eid[rb][r] = e;
      int ec = e < E ? e : E - 1;
      rid[rb][r] = row_s[ec];
      cid[rb][r] = col_s[ec];
    }
  // single combined u|p gather (16B/lane) + v gather, issued early
  uint4 upv_pf[2][4];
  ushort4 vv_pf[2][4];
#pragma unroll
  for (int rb = 0; rb < 2; ++rb)
#pragma unroll
    for (int r = 0; r < 4; ++r) {
      upv_pf[rb][r] = *(const uint4*)&up16[(size_t)rid[rb][r] * 128 + c16 * 8];
      vv_pf[rb][r] = *(const ushort4*)&v16[(size_t)cid[rb][r] * 64 + c16 * 4];
    }

  if (tid < 64) {
    sBb[0 * 64 + tid] = eb1[tid];
    sBb[1 * 64 + tid] = eb2[tid];
    sBb[2 * 64 + tid] = nb1[tid];
    sBb[3 * 64 + tid] = nb2[tid];
  }
  if (tid < 128) {
    int e = te + tid;
    scol[tid] = col_s[e < E ? e : E - 1];
  }
  // ea stream stage-in (nontemporal: read-once per layer)
  for (int i = tid; i < 1024; i += 256) {
    int r = i >> 3, cc = i & 7;
    int e = te + r;
    if (e >= E) e = E - 1;
    u32x4 d = nt_load4(&ea16[(size_t)e * 64 + cc * 8]);
    *(u32x4*)&sA[r * 64 + ((cc * 8) ^ ((r & 7) << 3))] = d;
  }

  v8s af[2][2];
  v8s bfr[4][2];
  v4f acc[2][4];

  __syncthreads();   // staging done

  // ---- phase 0: T = sp(ea@W1c + b1 + u[row] + v[col]) ----
  READ_FRAGS(0);
  DO_MFMA();
#pragma unroll
  for (int rb = 0; rb < 2; ++rb)
#pragma unroll
    for (int r = 0; r < 4; ++r) {
      const unsigned short* uv = (const unsigned short*)&upv_pf[rb][r];
      const unsigned short* vp_ = (const unsigned short*)&vv_pf[rb][r];
      int row = rbase + rb * 16 + q * 4 + r;
#pragma unroll
      for (int ct = 0; ct < 4; ++ct) {
        int n = ct * 16 + c16;
        float t = acc[rb][ct][r] + sBb[n] + bf2f(uv[ct]) + bf2f(vp_[ct]);
        t = sp_f(t);
        sA[row * 64 + (n ^ ((row & 7) << 3))] = f2bf(t);
      }
    }

  // ---- phase 1: ea' = T@eW2 + b2 -> sA (own band) ----
  READ_FRAGS(1);
  DO_MFMA();
#pragma unroll
  for (int rb = 0; rb < 2; ++rb)
#pragma unroll
    for (int ct = 0; ct < 4; ++ct) {
      int n = ct * 16 + c16;
#pragma unroll
      for (int r = 0; r < 4; ++r) {
        float en = acc[rb][ct][r] + sBb[64 + n];
        int row = rbase + rb * 16 + q * 4 + r;
        sA[row * 64 + (n ^ ((row & 7) << 3))] = f2bf(en);
      }
    }
  __syncthreads();   // writeback reads all rows
  if (store_ea) {
    for (int i = tid; i < 1024; i += 256) {
      int r = i >> 3, cc = i & 7;
      if (te + r < E) {
        u32x4 d = *(const u32x4*)&sA[r * 64 + ((cc * 8) ^ ((r & 7) << 3))];
        nt_store4(&ea16[(size_t)(te + r) * 64 + cc * 8], d);
      }
    }
  }
  __syncthreads();   // phase-2 epi writes must not race writeback reads

  // ---- phase 2: T2 = sp(ea'@nW1b + b3 + p[row]) ----
  READ_FRAGS(2);
  DO_MFMA();
#pragma unroll
  for (int rb = 0; rb < 2; ++rb)
#pragma unroll
    for (int r = 0; r < 4; ++r) {
      const unsigned short* uv = (const unsigned short*)&upv_pf[rb][r];
      int row = rbase + rb * 16 + q * 4 + r;
#pragma unroll
      for (int ct = 0; ct < 4; ++ct) {
        int n = ct * 16 + c16;
        float t2 = acc[rb][ct][r] + sBb[128 + n] + bf2f(uv[4 + ct]);
        t2 = sp_f(t2);
        sA[row * 64 + (n ^ ((row & 7) << 3))] = f2bf(t2);
      }
    }

  // ---- phase 3: msg = T2@nW2 + b4 -> msgb (sA dead after frag loads) ----
  READ_FRAGS(3);
  __syncthreads();   // all waves done reading sA; msgb alias safe
  DO_MFMA();
#pragma unroll
  for (int rb = 0; rb < 2; ++rb)
#pragma unroll
    for (int ct = 0; ct < 4; ++ct) {
      int n = ct * 16 + c16;
#pragma unroll
      for (int r = 0; r < 4; ++r) {
        float msg = acc[rb][ct][r] + sBb[192 + n];
        int row = rbase + rb * 16 + q * 4 + r;
        msgb[row * 64 + n] = (eid[rb][r] < E) ? msg : 0.0f;
      }
    }
  __syncthreads();

  // ---- segmented reduction; plain store for interior (exclusive) segments ----
  int nrows = E - te;
  if (nrows > 128) nrows = 128;
  for (int r0 = w; r0 < nrows; r0 += 4) {
    int c0 = scol[r0];
    if (r0 > 0 && scol[r0 - 1] == c0) continue;
    float s = 0.0f;
    int r = r0;
    do {
      s += msgb[r * 64 + l];
      ++r;
    } while (r < nrows && scol[r] == c0);
    if (r0 > 0 && r < nrows)
      xnew[(size_t)c0 * 64 + l] = s;     // run fully interior: exclusive writer
    else
      atomicAdd(&xnew[(size_t)c0 * 64 + l], s);
  }
}

// ---------------- BN stats ----------------
__global__ __launch_bounds__(256) void k_bn_stats(
    const float* __restrict__ xnew, float* __restrict__ bnacc, int N) {
  int t = threadIdx.x;
  int ch = t & 63;
  int sl = t >> 6;
  float s = 0.f, s2 = 0.f;
  for (int n = blockIdx.x * 4 + sl; n < N; n += gridDim.x * 4) {
    float v = xnew[(size_t)n * 64 + ch];
    s += v;
    s2 = fmaf(v, v, s2);
  }
  __shared__ float red[256], red2[256];
  red[t] = s;
  red2[t] = s2;
  __syncthreads();
  if (sl == 0) {
    s = red[ch] + red[64 + ch] + red[128 + ch] + red[192 + ch];
    s2 = red2[ch] + red2[64 + ch] + red2[128 + ch] + red2[192 + ch];
    atomicAdd(&bnacc[ch], s);
    atomicAdd(&bnacc[64 + ch], s2);
  }
}

// ---------------- BN apply + softplus + residual (last layer) ----------------
__global__ __launch_bounds__(256) void k_bn_apply(
    float* __restrict__ x, const float* __restrict__ xnew,
    const float* __restrict__ bnacc, const float* __restrict__ gamma,
    const float* __restrict__ beta, int N) {
  __shared__ float sscale[64], sshift[64];
  if (threadIdx.x < 64) {
    float inv = 1.0f / (float)N;
    float m = bnacc[threadIdx.x] * inv;
    float var = bnacc[64 + threadIdx.x] * inv - m * m;
    float rs = rsqrtf(var + 1e-5f);
    float g = gamma[threadIdx.x];
    sscale[threadIdx.x] = rs * g;
    sshift[threadIdx.x] = beta[threadIdx.x] - m * rs * g;
  }
  __syncthreads();
  size_t total = (size_t)N * 64;
  size_t stride = (size_t)gridDim.x * blockDim.x;
  for (size_t i = (size_t)blockIdx.x * blockDim.x + threadIdx.x; i < total; i += stride) {
    int ch = (int)(i & 63);
    float v = fmaf(xnew[i], sscale[ch], sshift[ch]);
    x[i] += sp_f(v);
  }
}

// ---------------- fused pool + predictor ----------------
__device__ __forceinline__ int lbound(const int* a, int n, int key) {
  int lo = 0, hi = n;
  while (lo < hi) {
    int mid = (lo + hi) >> 1;
    if (a[mid] < key) lo = mid + 1; else hi = mid;
  }
  return lo;
}

__global__ __launch_bounds__(256) void k_pool_pred(
    const float* __restrict__ x, const int* __restrict__ batch, int N,
    const float* __restrict__ pW1, const float* __restrict__ pb1,
    const float* __restrict__ pW2, const float* __restrict__ pb2,
    const float* __restrict__ pW3, const float* __restrict__ pb3,
    float* __restrict__ out) {
  int b = blockIdx.x;
  int lo = lbound(batch, N, b);
  int hi = lbound(batch, N, b + 1);
  int t = threadIdx.x;
  int ch = t & 63;
  int sl = t >> 6;
  float s = 0.f;
  for (int n = lo + sl; n < hi; n += 4) s += x[(size_t)n * 64 + ch];
  __shared__ float red4[4][64];
  __shared__ float sg[64];
  __shared__ float sh1[128];
  __shared__ float red[128];
  red4[sl][ch] = s;
  __syncthreads();
  if (t < 64) {
    float tot = red4[0][t] + red4[1][t] + red4[2][t] + red4[3][t];
    float cnt = (float)(hi - lo);
    sg[t] = tot / fmaxf(cnt, 1.0f);
  }
  __syncthreads();
  if (t < 128) {
    float h = pb1[t];
    for (int k = 0; k < 64; ++k) h = fmaf(sg[k], pW1[k * 128 + t], h);
    sh1[t] = sp_f(h);
  }
  __syncthreads();
  if (t < 128) {
    float h = pb2[t];
    for (int k = 0; k < 128; ++k) h = fmaf(sh1[k], pW2[k * 128 + t], h);
    red[t] = sp_f(h) * pW3[t];
  }
  __syncthreads();
  for (int off = 64; off > 0; off >>= 1) {
    if (t < off) red[t] += red[t + off];
    __syncthreads();
  }
  if (t == 0) out[b] = red[0] + pb3[0];
}

extern "C" void kernel_launch(void* const* d_in, const int* in_sizes, int n_in,
                              void* d_out, int out_size, void* d_ws, size_t ws_size,
                              hipStream_t stream) {
  const float* x         = (const float*)d_in[0];
  const float* edge_attr = (const float*)d_in[1];
  const float* charge    = (const float*)d_in[2];
  const int*   eidx      = (const int*)d_in[3];
  const int*   batch     = (const int*)d_in[4];
  const float* W_charge  = (const float*)d_in[5];
  const float* b_charge  = (const float*)d_in[6];
  const float* W_atom    = (const float*)d_in[7];
  const float* b_atom    = (const float*)d_in[8];
  const float* W_bond    = (const float*)d_in[9];
  const float* b_bond    = (const float*)d_in[10];
  const float* eW1 = (const float*)d_in[11];
  const float* eb1 = (const float*)d_in[12];
  const float* eW2 = (const float*)d_in[13];
  const float* eb2 = (const float*)d_in[14];
  const float* nW1 = (const float*)d_in[15];
  const float* nb1 = (const float*)d_in[16];
  const float* nW2 = (const float*)d_in[17];
  const float* nb2 = (const float*)d_in[18];
  const float* gam = (const float*)d_in[19];
  const float* bet = (const float*)d_in[20];
  const float* pW1 = (const float*)d_in[21];
  const float* pb1 = (const float*)d_in[22];
  const float* pW2 = (const float*)d_in[23];
  const float* pb2 = (const float*)d_in[24];
  const float* pW3 = (const float*)d_in[25];
  const float* pb3 = (const float*)d_in[26];

  int N = in_sizes[4];
  int E = in_sizes[3] / 2;
  int B = in_sizes[2];
  const int* row = eidx;
  const int* col = eidx + E;

  char* wptr = (char*)d_ws;
  unsigned short* ea16 = (unsigned short*)wptr; wptr += (((size_t)E * 64 * 2 + 255) & ~255ull);
  unsigned short* up16 = (unsigned short*)wptr; wptr += (((size_t)N * 128 * 2 + 255) & ~255ull);
  unsigned short* v16  = (unsigned short*)wptr; wptr += (((size_t)N * 64 * 2 + 255) & ~255ull);
  unsigned short* wfrag = (unsigned short*)wptr; wptr += 13 * 4096 * 2;
  float* xemb = (float*)wptr; wptr += (size_t)N * 64 * 4;
  float* xnew = (float*)wptr; wptr += (size_t)N * 64 * 4;
  float* bnacc = (float*)wptr; wptr += 256 * 4;
  int* counts = (int*)wptr;   wptr += (size_t)N * 4;
  int* scan_tmp = (int*)wptr; wptr += (size_t)N * 4;
  int* cursor = (int*)wptr;   wptr += (size_t)N * 4;
  int* bsum = (int*)wptr;     wptr += 4096;
  int* pos = (int*)wptr;      wptr += (size_t)E * 4;
  int* row_s = (int*)wptr;    wptr += (size_t)E * 4;
  int* col_s = (int*)wptr;    wptr += (size_t)E * 4;

  int NB = (N + 255) / 256;

  k_prep_wfrag<<<13, 256, 0, stream>>>(eW1, eW2, nW1, nW2, W_bond, wfrag);
  hipMemsetAsync(counts, 0, (size_t)N * 4, stream);
  k_hist<<<2048, 256, 0, stream>>>(col, counts, E);
  k_scan1<<<NB, 256, 0, stream>>>(counts, scan_tmp, bsum, N);
  k_scan2<<<1, 256, 0, stream>>>(bsum, NB);
  k_scan3<<<NB, 256, 0, stream>>>(counts, scan_tmp, bsum, cursor, N);
  k_scatter<<<2048, 256, 0, stream>>>(row, col, cursor, pos, row_s, col_s, E);

  int ntilesN = (N + 127) / 128;
  k_embed_nodes<<<ntilesN, 256, 0, stream>>>(x, batch, charge, W_charge,
                                             b_charge, W_atom, b_atom, xemb, N);
  k_embed_bonds_mfma<<<2048, 256, 0, stream>>>(edge_attr, pos,
                                               wfrag + 12 * 4096, b_bond,
                                               ea16, E);
  k_node_pre<<<NB, 256, 0, stream>>>(xemb, eW1, nW1, up16, v16, N);

  int gridE = (E + 127) / 128;
  for (int i = 0; i < 3; ++i) {
    hipMemsetAsync(xnew, 0, (size_t)N * 64 * 4, stream);
    hipMemsetAsync(bnacc, 0, 256 * 4, stream);
    k_edge_mfma<<<gridE, 256, 0, stream>>>(
        row_s, col_s, ea16, up16, v16, wfrag + (size_t)i * 16384,
        eb1 + (size_t)i * 64, eb2 + (size_t)i * 64, nb1 + (size_t)i * 64,
        nb2 + (size_t)i * 64, xnew, E, (i < 2) ? 1 : 0);
    k_bn_stats<<<1024, 256, 0, stream>>>(xnew, bnacc, N);
    if (i < 2) {
      k_bn_pre<<<NB, 256, 0, stream>>>(
          xemb, xnew, bnacc, gam + (size_t)i * 64, bet + (size_t)i * 64,
          eW1 + (size_t)(i + 1) * 192 * 64, nW1 + (size_t)(i + 1) * 128 * 64,
          up16, v16, N);
    } else {
      k_bn_apply<<<4096, 256, 0, stream>>>(xemb, xnew, bnacc,
                                           gam + (size_t)i * 64,
                                           bet + (size_t)i * 64, N);
    }
  }

  k_pool_pred<<<B, 256, 0, stream>>>(xemb, batch, N, pW1, pb1, pW2, pb2,
                                     pW3, pb3, (float*)d_out);
}

// Round 11
// 2024.937 us; speedup vs baseline: 1.0966x; 1.0709x over previous
//
#include <hip/hip_runtime.h>
#include <math.h>

typedef short v8s __attribute__((ext_vector_type(8)));   // 8 bf16
typedef float v4f __attribute__((ext_vector_type(4)));
typedef unsigned int u32x4 __attribute__((ext_vector_type(4)));

__device__ __forceinline__ u32x4 nt_load4(const void* p) {
  return __builtin_nontemporal_load((const u32x4*)p);
}
__device__ __forceinline__ void nt_store4(void* p, u32x4 v) {
  __builtin_nontemporal_store(v, (u32x4*)p);
}

// fast softplus: max(x,0) + ln2*log2(1+exp(-|x|)); HW exp/log, ~3e-5 abs err
__device__ __forceinline__ float sp_f(float x) {
  return fmaxf(x, 0.0f) + 0.69314718056f * __log2f(1.0f + __expf(-fabsf(x)));
}

__device__ __forceinline__ unsigned short f2bf(float f) {
  union { float f; unsigned u; } x; x.f = f;
  unsigned r = (x.u + 0x7FFF + ((x.u >> 16) & 1)) >> 16;
  return (unsigned short)r;
}

__device__ __forceinline__ float bf2f(unsigned short h) {
  union { unsigned u; float f; } x; x.u = ((unsigned)h) << 16;
  return x.f;
}

// ---------------- one-shot weight fragment prep (3 layers x 4 mats + W_bond) ----------------
__global__ __launch_bounds__(256) void k_prep_wfrag(
    const float* __restrict__ eW1, const float* __restrict__ eW2,
    const float* __restrict__ nW1, const float* __restrict__ nW2,
    const float* __restrict__ W_bond, unsigned short* __restrict__ wfrag) {
  if (blockIdx.x == 12) {
    unsigned short* out = wfrag + 12 * 4096;
    for (int f = threadIdx.x; f < 4096; f += 256) {
      int j = f & 7, ln = (f >> 3) & 63, kh = (f >> 9) & 1, ct = f >> 10;
      int k = kh * 32 + (ln >> 4) * 8 + j;
      int n = ct * 16 + (ln & 15);
      out[f] = (k < 41) ? f2bf(W_bond[k * 64 + n]) : 0;
    }
    return;
  }
  int i = blockIdx.x >> 2;   // layer
  int m = blockIdx.x & 3;    // matrix
  const float* W;
  if (m == 0)      W = eW1 + (size_t)i * 192 * 64 + 128 * 64;  // W1c
  else if (m == 1) W = eW2 + (size_t)i * 64 * 64;
  else if (m == 2) W = nW1 + (size_t)i * 128 * 64 + 64 * 64;   // nW1b
  else             W = nW2 + (size_t)i * 64 * 64;
  unsigned short* out = wfrag + ((size_t)i * 4 + m) * 4096;
  for (int f = threadIdx.x; f < 4096; f += 256) {
    int j = f & 7, ln = (f >> 3) & 63, kh = (f >> 9) & 1, ct = f >> 10;
    int k = kh * 32 + (ln >> 4) * 8 + j;
    int n = ct * 16 + (ln & 15);
    out[f] = f2bf(W[k * 64 + n]);
  }
}

// ---------------- node embedding, LDS-staged tiles + channel split ----------------
__global__ __launch_bounds__(256) void k_embed_nodes(
    const float* __restrict__ x, const int* __restrict__ batch,
    const float* __restrict__ charge, const float* __restrict__ W_charge,
    const float* __restrict__ b_charge, const float* __restrict__ W_atom,
    const float* __restrict__ b_atom, float* __restrict__ xemb, int N) {
  __shared__ float sW[108 * 64];   // 27.6 KB
  __shared__ float sX[128 * 92];   // 46 KB
  __shared__ float sb[64];
  __shared__ float sWc[16];
  __shared__ float sbc[16];
  for (int i = threadIdx.x; i < 108 * 64; i += blockDim.x) sW[i] = W_atom[i];
  if (threadIdx.x < 64) sb[threadIdx.x] = b_atom[threadIdx.x];
  if (threadIdx.x < 16) {
    sWc[threadIdx.x] = W_charge[threadIdx.x];
    sbc[threadIdx.x] = b_charge[threadIdx.x];
  }
  int ntiles = (N + 127) >> 7;
  for (int tile = blockIdx.x; tile < ntiles; tile += gridDim.x) {
    int base = tile << 7;
    int cnt = N - base; if (cnt > 128) cnt = 128;
    __syncthreads();
    if (cnt == 128) {
      const u32x4* src = (const u32x4*)(x + (size_t)base * 92);
      for (int i = threadIdx.x; i < 2944; i += 256)
        ((u32x4*)sX)[i] = nt_load4(&src[i]);
    } else {
      for (int i = threadIdx.x; i < cnt * 92; i += 256)
        sX[i] = x[(size_t)base * 92 + i];
    }
    __syncthreads();
    int t = threadIdx.x;
    int node = t & 127, half = t >> 7;
    if (node < cnt) {
      int n = base + node;
      float acc[32];
#pragma unroll
      for (int j = 0; j < 32; ++j) acc[j] = sb[half * 32 + j];
      const float* xr = sX + node * 92;
      for (int k = 0; k < 92; ++k) {
        float a = xr[k];
        const float* wk = sW + k * 64 + half * 32;
#pragma unroll
        for (int j = 0; j < 32; ++j) acc[j] = fmaf(a, wk[j], acc[j]);
      }
      float ch = charge[batch[n]];
#pragma unroll
      for (int c = 0; c < 16; ++c) {
        float cf = fmaf(ch, sWc[c], sbc[c]);
        const float* wk = sW + (92 + c) * 64 + half * 32;
#pragma unroll
        for (int j = 0; j < 32; ++j) acc[j] = fmaf(cf, wk[j], acc[j]);
      }
      float* o = xemb + (size_t)n * 64 + half * 32;
#pragma unroll
      for (int q8 = 0; q8 < 8; ++q8)
        ((float4*)o)[q8] = make_float4(acc[4*q8], acc[4*q8+1], acc[4*q8+2], acc[4*q8+3]);
    }
  }
}

// ---------------- CSR build ----------------
__global__ __launch_bounds__(256) void k_hist(const int* __restrict__ col,
                                              int* __restrict__ counts, int E) {
  int stride = gridDim.x * blockDim.x;
  for (int e = blockIdx.x * blockDim.x + threadIdx.x; e < E; e += stride)
    atomicAdd(&counts[col[e]], 1);
}

__global__ __launch_bounds__(256) void k_scan1(const int* __restrict__ counts,
                                               int* __restrict__ scan_tmp,
                                               int* __restrict__ bsum, int N) {
  __shared__ int sd[2][256];
  int t = threadIdx.x;
  int i = blockIdx.x * 256 + t;
  int v = (i < N) ? counts[i] : 0;
  sd[0][t] = v;
  __syncthreads();
  int s = 0;
#pragma unroll
  for (int off = 1; off < 256; off <<= 1) {
    int nv = sd[s][t];
    if (t >= off) nv += sd[s][t - off];
    sd[s ^ 1][t] = nv;
    s ^= 1;
    __syncthreads();
  }
  if (i < N) scan_tmp[i] = sd[s][t];
  if (t == 255) bsum[blockIdx.x] = sd[s][255];
}

__global__ __launch_bounds__(256) void k_scan2(int* __restrict__ b, int NB) {
  __shared__ int sd[2][256];
  __shared__ int carry_s;
  int t = threadIdx.x;
  if (t == 0) carry_s = 0;
  __syncthreads();
  for (int base = 0; base < NB; base += 256) {
    int i = base + t;
    int v = (i < NB) ? b[i] : 0;
    sd[0][t] = v;
    __syncthreads();
    int s = 0;
#pragma unroll
    for (int off = 1; off < 256; off <<= 1) {
      int nv = sd[s][t];
      if (t >= off) nv += sd[s][t - off];
      sd[s ^ 1][t] = nv;
      s ^= 1;
      __syncthreads();
    }
    int c = carry_s;
    int tot = sd[s][255];
    if (i < NB) b[i] = sd[s][t] + c;
    __syncthreads();
    if (t == 0) carry_s = c + tot;
    __syncthreads();
  }
}

__global__ __launch_bounds__(256) void k_scan3(const int* __restrict__ counts,
                                               const int* __restrict__ scan_tmp,
                                               const int* __restrict__ bsum,
                                               int* __restrict__ cursor, int N) {
  int i = blockIdx.x * 256 + threadIdx.x;
  if (i < N) {
    int base = (blockIdx.x > 0) ? bsum[blockIdx.x - 1] : 0;
    cursor[i] = scan_tmp[i] - counts[i] + base;
  }
}

__global__ __launch_bounds__(256) void k_scatter(
    const int* __restrict__ row, const int* __restrict__ col,
    int* __restrict__ cursor, int* __restrict__ pos,
    int* __restrict__ row_s, int* __restrict__ col_s, int E) {
  int stride = gridDim.x * blockDim.x;
  for (int e = blockIdx.x * blockDim.x + threadIdx.x; e < E; e += stride) {
    int c = col[e];
    int p = atomicAdd(&cursor[c], 1);
    pos[e] = p;
    row_s[p] = row[e];
    col_s[p] = c;
  }
}

// ---------------- bond embedding via MFMA: [128 edges x 41] @ [41 x 64] ----------------
__global__ __launch_bounds__(256) void k_embed_bonds_mfma(
    const float* __restrict__ eattr, const int* __restrict__ pos,
    const unsigned short* __restrict__ gWb, const float* __restrict__ b_bond,
    unsigned short* __restrict__ ea16, int E) {
  __shared__ unsigned short sA[128 * 64];  // 16 KB, swizzled
  __shared__ float sb[64];
  __shared__ int spos[128];
  int tid = threadIdx.x;
  int w = tid >> 6, l = tid & 63, q = l >> 4, c16 = l & 15;
  int rbase = w * 32;
  if (tid < 64) sb[tid] = b_bond[tid];
  int ntiles = (E + 127) >> 7;
  for (int tile = blockIdx.x; tile < ntiles; tile += gridDim.x) {
    int te = tile << 7;
    int cnt = E - te; if (cnt > 128) cnt = 128;
    __syncthreads();   // protect sA reuse across loop iterations
    uint4 z = make_uint4(0, 0, 0, 0);
    for (int i = tid; i < 1024; i += 256) ((uint4*)sA)[i] = z;
    __syncthreads();
    int nflt = cnt * 41;
    for (int i = tid; i < nflt; i += 256) {
      int r = i / 41, k = i - r * 41;
      float v = __builtin_nontemporal_load(&eattr[(size_t)te * 41 + i]);
      sA[r * 64 + (k ^ ((r & 7) << 3))] = f2bf(v);
    }
    if (tid < 128) spos[tid] = (te + tid < E) ? pos[te + tid] : -1;
    __syncthreads();
    v8s bfr[4][2], af[2][2];
    v4f acc[2][4];
    const v8s* wp_ = (const v8s*)gWb;
#pragma unroll
    for (int ct = 0; ct < 4; ++ct)
#pragma unroll
      for (int kh = 0; kh < 2; ++kh)
        bfr[ct][kh] = wp_[(ct * 2 + kh) * 64 + l];
#pragma unroll
    for (int rb = 0; rb < 2; ++rb)
#pragma unroll
      for (int kh = 0; kh < 2; ++kh) {
        int row_ = rbase + rb * 16 + c16;
        af[rb][kh] = *(const v8s*)&sA[row_ * 64 +
                                      ((kh * 32 + q * 8) ^ ((row_ & 7) << 3))];
      }
#pragma unroll
    for (int rb = 0; rb < 2; ++rb)
#pragma unroll
      for (int ct = 0; ct < 4; ++ct) {
        v4f a_ = {0.f, 0.f, 0.f, 0.f};
        a_ = __builtin_amdgcn_mfma_f32_16x16x32_bf16(af[rb][0], bfr[ct][0], a_, 0, 0, 0);
        a_ = __builtin_amdgcn_mfma_f32_16x16x32_bf16(af[rb][1], bfr[ct][1], a_, 0, 0, 0);
        acc[rb][ct] = a_;
      }
#pragma unroll
    for (int rb = 0; rb < 2; ++rb)
#pragma unroll
      for (int ct = 0; ct < 4; ++ct) {
        int n = ct * 16 + c16;
#pragma unroll
        for (int r = 0; r < 4; ++r) {
          float v = acc[rb][ct][r] + sb[n];
          int row = rbase + rb * 16 + q * 4 + r;
          sA[row * 64 + (n ^ ((row & 7) << 3))] = f2bf(v);
        }
      }
    __syncthreads();
    for (int i = tid; i < 1024; i += 256) {
      int r = i >> 3, cc = i & 7;
      int p = spos[r];
      if (p >= 0) {
        u32x4 d = *(const u32x4*)&sA[r * 64 + ((cc * 8) ^ ((r & 7) << 3))];
        nt_store4(&ea16[(size_t)p * 64 + cc * 8], d);
      }
    }
  }
}

// ---------------- node-side precompute body (R5 layout) ----------------
// storage permute: out[i] = val[((i&3)<<4) | (i>>2)] so lane c16 reads ushort4 at c16*4;
// up16[n] = [u_perm(64) | p_perm(64)], v16[n] = v_perm(64)
__device__ __forceinline__ void node_pre_body(
    const float* __restrict__ xr, const float* sWa, const float* sWb,
    const float* sWp, unsigned short* __restrict__ up16,
    unsigned short* __restrict__ v16, int n) {
  const float4* xr4 = (const float4*)xr;
  float u[64], p[64];
#pragma unroll
  for (int j = 0; j < 64; ++j) { u[j] = 0.f; p[j] = 0.f; }
  for (int k4 = 0; k4 < 16; ++k4) {
    float4 av = xr4[k4];
    const float* wa = sWa + k4 * 256;
    const float* wp = sWp + k4 * 256;
#pragma unroll
    for (int j = 0; j < 64; ++j) u[j] = fmaf(av.x, wa[j], u[j]);
#pragma unroll
    for (int j = 0; j < 64; ++j) p[j] = fmaf(av.x, wp[j], p[j]);
#pragma unroll
    for (int j = 0; j < 64; ++j) u[j] = fmaf(av.y, wa[64 + j], u[j]);
#pragma unroll
    for (int j = 0; j < 64; ++j) p[j] = fmaf(av.y, wp[64 + j], p[j]);
#pragma unroll
    for (int j = 0; j < 64; ++j) u[j] = fmaf(av.z, wa[128 + j], u[j]);
#pragma unroll
    for (int j = 0; j < 64; ++j) p[j] = fmaf(av.z, wp[128 + j], p[j]);
#pragma unroll
    for (int j = 0; j < 64; ++j) u[j] = fmaf(av.w, wa[192 + j], u[j]);
#pragma unroll
    for (int j = 0; j < 64; ++j) p[j] = fmaf(av.w, wp[192 + j], p[j]);
  }
  unsigned short* o = up16 + (size_t)n * 128;
#pragma unroll
  for (int q8 = 0; q8 < 8; ++q8) {
    unsigned short tmp[8];
#pragma unroll
    for (int j = 0; j < 8; ++j) {
      int i = q8 * 8 + j;
      tmp[j] = f2bf(u[((i & 3) << 4) | (i >> 2)]);
    }
    *(uint4*)&o[q8 * 8] = *(uint4*)tmp;
  }
#pragma unroll
  for (int q8 = 0; q8 < 8; ++q8) {
    unsigned short tmp[8];
#pragma unroll
    for (int j = 0; j < 8; ++j) {
      int i = q8 * 8 + j;
      tmp[j] = f2bf(p[((i & 3) << 4) | (i >> 2)]);
    }
    *(uint4*)&o[64 + q8 * 8] = *(uint4*)tmp;
  }
  float vv[64];
#pragma unroll
  for (int j = 0; j < 64; ++j) vv[j] = 0.f;
  for (int k4 = 0; k4 < 16; ++k4) {
    float4 av = xr4[k4];
    const float* wb = sWb + k4 * 256;
#pragma unroll
    for (int j = 0; j < 64; ++j) vv[j] = fmaf(av.x, wb[j], vv[j]);
#pragma unroll
    for (int j = 0; j < 64; ++j) vv[j] = fmaf(av.y, wb[64 + j], vv[j]);
#pragma unroll
    for (int j = 0; j < 64; ++j) vv[j] = fmaf(av.z, wb[128 + j], vv[j]);
#pragma unroll
    for (int j = 0; j < 64; ++j) vv[j] = fmaf(av.w, wb[192 + j], vv[j]);
  }
  unsigned short* ov = v16 + (size_t)n * 64;
#pragma unroll
  for (int q8 = 0; q8 < 8; ++q8) {
    unsigned short tmp[8];
#pragma unroll
    for (int j = 0; j < 8; ++j) {
      int i = q8 * 8 + j;
      tmp[j] = f2bf(vv[((i & 3) << 4) | (i >> 2)]);
    }
    *(uint4*)&ov[q8 * 8] = *(uint4*)tmp;
  }
}

__global__ __launch_bounds__(256) void k_node_pre(
    const float* __restrict__ xemb, const float* __restrict__ eW1,
    const float* __restrict__ nW1, unsigned short* __restrict__ up16,
    unsigned short* __restrict__ v16, int N) {
  __shared__ float sWa[64 * 64];
  __shared__ float sWb[64 * 64];
  __shared__ float sWp[64 * 64];
  for (int i = threadIdx.x; i < 64 * 64; i += blockDim.x) {
    sWa[i] = eW1[i];
    sWb[i] = eW1[64 * 64 + i];
    sWp[i] = nW1[i];
  }
  __syncthreads();
  int stride = gridDim.x * blockDim.x;
  for (int n = blockIdx.x * blockDim.x + threadIdx.x; n < N; n += stride)
    node_pre_body(xemb + (size_t)n * 64, sWa, sWb, sWp, up16, v16, n);
}

// ---------------- fused BN apply + residual + next-layer node_pre ----------------
__global__ __launch_bounds__(256) void k_bn_pre(
    float* __restrict__ xemb, const float* __restrict__ xnew,
    const float* __restrict__ bnacc, const float* __restrict__ gamma,
    const float* __restrict__ beta, const float* __restrict__ eW1n,
    const float* __restrict__ nW1n, unsigned short* __restrict__ up16,
    unsigned short* __restrict__ v16, int N) {
  __shared__ float sWa[64 * 64];
  __shared__ float sWb[64 * 64];
  __shared__ float sWp[64 * 64];
  __shared__ float sscale[64], sshift[64];
  for (int i = threadIdx.x; i < 64 * 64; i += blockDim.x) {
    sWa[i] = eW1n[i];
    sWb[i] = eW1n[64 * 64 + i];
    sWp[i] = nW1n[i];
  }
  if (threadIdx.x < 64) {
    float inv = 1.0f / (float)N;
    float m = bnacc[threadIdx.x] * inv;
    float var = bnacc[64 + threadIdx.x] * inv - m * m;
    float rs = rsqrtf(var + 1e-5f);
    float g = gamma[threadIdx.x];
    sscale[threadIdx.x] = rs * g;
    sshift[threadIdx.x] = beta[threadIdx.x] - m * rs * g;
  }
  __syncthreads();
  int stride = gridDim.x * blockDim.x;
  for (int n = blockIdx.x * blockDim.x + threadIdx.x; n < N; n += stride) {
    float* xr = xemb + (size_t)n * 64;
#pragma unroll
    for (int q = 0; q < 16; ++q) {
      float4 xn4 = ((const float4*)(xnew + (size_t)n * 64))[q];
      float4 xo4 = ((const float4*)xr)[q];
      xo4.x += sp_f(fmaf(xn4.x, sscale[4*q+0], sshift[4*q+0]));
      xo4.y += sp_f(fmaf(xn4.y, sscale[4*q+1], sshift[4*q+1]));
      xo4.z += sp_f(fmaf(xn4.z, sscale[4*q+2], sshift[4*q+2]));
      xo4.w += sp_f(fmaf(xn4.w, sscale[4*q+3], sshift[4*q+3]));
      ((float4*)xr)[q] = xo4;
    }
    node_pre_body(xr, sWa, sWb, sWp, up16, v16, n);
  }
}

// ---------------- fused per-layer edge kernel, MFMA bf16, 4 waves x 32 rows ----------------
#define READ_FRAGS(P)                                                        \
  {                                                                          \
    const v8s* wp_ = (const v8s*)gWf + (P) * 512;                            \
    _Pragma("unroll") for (int ct = 0; ct < 4; ++ct)                         \
        _Pragma("unroll") for (int kh = 0; kh < 2; ++kh)                     \
            bfr[ct][kh] = wp_[(ct * 2 + kh) * 64 + l];                       \
    _Pragma("unroll") for (int rb = 0; rb < 2; ++rb)                         \
        _Pragma("unroll") for (int kh = 0; kh < 2; ++kh) {                   \
      int row_ = rbase + rb * 16 + c16;                                      \
      af[rb][kh] = *(const v8s*)&sA[row_ * 64 +                              \
                                    ((kh * 32 + q * 8) ^ ((row_ & 7) << 3))];\
    }                                                                        \
  }

#define DO_MFMA()                                                            \
  _Pragma("unroll") for (int rb = 0; rb < 2; ++rb)                           \
      _Pragma("unroll") for (int ct = 0; ct < 4; ++ct) {                     \
    v4f a_ = {0.f, 0.f, 0.f, 0.f};                                           \
    a_ = __builtin_amdgcn_mfma_f32_16x16x32_bf16(af[rb][0], bfr[ct][0], a_,  \
                                                 0, 0, 0);                   \
    a_ = __builtin_amdgcn_mfma_f32_16x16x32_bf16(af[rb][1], bfr[ct][1], a_,  \
                                                 0, 0, 0);                   \
    acc[rb][ct] = a_;                                                        \
  }

__global__ __launch_bounds__(256, 4) void k_edge_mfma(
    const int* __restrict__ row_s, const int* __restrict__ col_s,
    unsigned short* __restrict__ ea16, const unsigned short* __restrict__ up16,
    const unsigned short* __restrict__ v16,
    const unsigned short* __restrict__ gWf, const float* __restrict__ eb1,
    const float* __restrict__ eb2, const float* __restrict__ nb1,
    const float* __restrict__ nb2, float* __restrict__ xnew, int E,
    int store_ea) {
  __shared__ __align__(16) unsigned char smem[34304];
  unsigned short* sA = (unsigned short*)smem;             // 16 KB (aliased)
  float* msgb        = (float*)smem;                      // 32 KB
  float* sBb         = (float*)(smem + 32768);            // 1 KB
  int* scol          = (int*)(smem + 33792);              // 512 B

  int tid = threadIdx.x;
  int te = blockIdx.x * 128;
  int w = tid >> 6, l = tid & 63, q = l >> 4, c16 = l & 15;
  int rbase = w * 32;

  int rid[2][4], cid[2][4], eid[2][4];
#pragma unroll
  for (int rb = 0; rb < 2; ++rb)
#pragma unroll
    for (int r = 0; r < 4; ++r) {
      int e = te + rbase + rb * 16 + q * 4 + r;
      eid[rb][r] = e;
      int ec = e < E ? e : E - 1;
      rid[rb][r] = row_s[ec];
      cid[rb][r] = col_s[ec];
    }
  // split gathers: u + v issued early (R5 schedule)
  ushort4 uu_pf[2][4], vv_pf[2][4];
#pragma unroll
  for (int rb = 0; rb < 2; ++rb)
#pragma unroll
    for (int r = 0; r < 4; ++r) {
      uu_pf[rb][r] = *(const ushort4*)&up16[(size_t)rid[rb][r] * 128 + c16 * 4];
      vv_pf[rb][r] = *(const ushort4*)&v16[(size_t)cid[rb][r] * 64 + c16 * 4];
    }

  if (tid < 64) {
    sBb[0 * 64 + tid] = eb1[tid];
    sBb[1 * 64 + tid] = eb2[tid];
    sBb[2 * 64 + tid] = nb1[tid];
    sBb[3 * 64 + tid] = nb2[tid];
  }
  if (tid < 128) {
    int e = te + tid;
    scol[tid] = col_s[e < E ? e : E - 1];
  }
  // ea stream stage-in (nontemporal: read-once per layer)
  for (int i = tid; i < 1024; i += 256) {
    int r = i >> 3, cc = i & 7;
    int e = te + r;
    if (e >= E) e = E - 1;
    u32x4 d = nt_load4(&ea16[(size_t)e * 64 + cc * 8]);
    *(u32x4*)&sA[r * 64 + ((cc * 8) ^ ((r & 7) << 3))] = d;
  }

  v8s af[2][2];
  v8s bfr[4][2];
  v4f acc[2][4];

  __syncthreads();   // staging done

  // ---- phase 0: T = sp(ea@W1c + b1 + u[row] + v[col]) ----
  READ_FRAGS(0);
  DO_MFMA();
  // prefetch p for phase 2 (lands during phase 1 + writeback)
  ushort4 pp_pf[2][4];
#pragma unroll
  for (int rb = 0; rb < 2; ++rb)
#pragma unroll
    for (int r = 0; r < 4; ++r)
      pp_pf[rb][r] =
          *(const ushort4*)&up16[(size_t)rid[rb][r] * 128 + 64 + c16 * 4];
#pragma unroll
  for (int rb = 0; rb < 2; ++rb)
#pragma unroll
    for (int r = 0; r < 4; ++r) {
      const unsigned short* up_ = (const unsigned short*)&uu_pf[rb][r];
      const unsigned short* vp_ = (const unsigned short*)&vv_pf[rb][r];
      int row = rbase + rb * 16 + q * 4 + r;
#pragma unroll
      for (int ct = 0; ct < 4; ++ct) {
        int n = ct * 16 + c16;
        float t = acc[rb][ct][r] + sBb[n] + bf2f(up_[ct]) + bf2f(vp_[ct]);
        t = sp_f(t);
        sA[row * 64 + (n ^ ((row & 7) << 3))] = f2bf(t);
      }
    }

  // ---- phase 1: ea' = T@eW2 + b2 -> sA (own band) ----
  READ_FRAGS(1);
  DO_MFMA();
#pragma unroll
  for (int rb = 0; rb < 2; ++rb)
#pragma unroll
    for (int ct = 0; ct < 4; ++ct) {
      int n = ct * 16 + c16;
#pragma unroll
      for (int r = 0; r < 4; ++r) {
        float en = acc[rb][ct][r] + sBb[64 + n];
        int row = rbase + rb * 16 + q * 4 + r;
        sA[row * 64 + (n ^ ((row & 7) << 3))] = f2bf(en);
      }
    }
  if (store_ea) {
    __syncthreads();   // writeback reads all rows
    for (int i = tid; i < 1024; i += 256) {
      int r = i >> 3, cc = i & 7;
      if (te + r < E) {
        u32x4 d = *(const u32x4*)&sA[r * 64 + ((cc * 8) ^ ((r & 7) << 3))];
        nt_store4(&ea16[(size_t)(te + r) * 64 + cc * 8], d);
      }
    }
    __syncthreads();   // phase-2 epi writes must not race writeback reads
  }

  // ---- phase 2: T2 = sp(ea'@nW1b + b3 + p[row]) ----
  READ_FRAGS(2);
  DO_MFMA();
#pragma unroll
  for (int rb = 0; rb < 2; ++rb)
#pragma unroll
    for (int r = 0; r < 4; ++r) {
      const unsigned short* pp_ = (const unsigned short*)&pp_pf[rb][r];
      int row = rbase + rb * 16 + q * 4 + r;
#pragma unroll
      for (int ct = 0; ct < 4; ++ct) {
        int n = ct * 16 + c16;
        float t2 = acc[rb][ct][r] + sBb[128 + n] + bf2f(pp_[ct]);
        t2 = sp_f(t2);
        sA[row * 64 + (n ^ ((row & 7) << 3))] = f2bf(t2);
      }
    }

  // ---- phase 3: msg = T2@nW2 + b4 -> msgb (sA dead after frag loads) ----
  READ_FRAGS(3);
  __syncthreads();   // all waves done reading sA; msgb alias safe
  DO_MFMA();
#pragma unroll
  for (int rb = 0; rb < 2; ++rb)
#pragma unroll
    for (int ct = 0; ct < 4; ++ct) {
      int n = ct * 16 + c16;
#pragma unroll
      for (int r = 0; r < 4; ++r) {
        float msg = acc[rb][ct][r] + sBb[192 + n];
        int row = rbase + rb * 16 + q * 4 + r;
        msgb[row * 64 + n] = (eid[rb][r] < E) ? msg : 0.0f;
      }
    }
  __syncthreads();

  // ---- segmented reduction; plain store for interior (exclusive) segments ----
  int nrows = E - te;
  if (nrows > 128) nrows = 128;
  for (int r0 = w; r0 < nrows; r0 += 4) {
    int c0 = scol[r0];
    if (r0 > 0 && scol[r0 - 1] == c0) continue;
    float s = 0.0f;
    int r = r0;
    do {
      s += msgb[r * 64 + l];
      ++r;
    } while (r < nrows && scol[r] == c0);
    if (r0 > 0 && r < nrows)
      xnew[(size_t)c0 * 64 + l] = s;     // run fully interior: exclusive writer
    else
      atomicAdd(&xnew[(size_t)c0 * 64 + l], s);
  }
}

// ---------------- BN stats ----------------
__global__ __launch_bounds__(256) void k_bn_stats(
    const float* __restrict__ xnew, float* __restrict__ bnacc, int N) {
  int t = threadIdx.x;
  int ch = t & 63;
  int sl = t >> 6;
  float s = 0.f, s2 = 0.f;
  for (int n = blockIdx.x * 4 + sl; n < N; n += gridDim.x * 4) {
    float v = xnew[(size_t)n * 64 + ch];
    s += v;
    s2 = fmaf(v, v, s2);
  }
  __shared__ float red[256], red2[256];
  red[t] = s;
  red2[t] = s2;
  __syncthreads();
  if (sl == 0) {
    s = red[ch] + red[64 + ch] + red[128 + ch] + red[192 + ch];
    s2 = red2[ch] + red2[64 + ch] + red2[128 + ch] + red2[192 + ch];
    atomicAdd(&bnacc[ch], s);
    atomicAdd(&bnacc[64 + ch], s2);
  }
}

// ---------------- BN apply + softplus + residual (last layer) ----------------
__global__ __launch_bounds__(256) void k_bn_apply(
    float* __restrict__ x, const float* __restrict__ xnew,
    const float* __restrict__ bnacc, const float* __restrict__ gamma,
    const float* __restrict__ beta, int N) {
  __shared__ float sscale[64], sshift[64];
  if (threadIdx.x < 64) {
    float inv = 1.0f / (float)N;
    float m = bnacc[threadIdx.x] * inv;
    float var = bnacc[64 + threadIdx.x] * inv - m * m;
    float rs = rsqrtf(var + 1e-5f);
    float g = gamma[threadIdx.x];
    sscale[threadIdx.x] = rs * g;
    sshift[threadIdx.x] = beta[threadIdx.x] - m * rs * g;
  }
  __syncthreads();
  size_t total = (size_t)N * 64;
  size_t stride = (size_t)gridDim.x * blockDim.x;
  for (size_t i = (size_t)blockIdx.x * blockDim.x + threadIdx.x; i < total; i += stride) {
    int ch = (int)(i & 63);
    float v = fmaf(xnew[i], sscale[ch], sshift[ch]);
    x[i] += sp_f(v);
  }
}

// ---------------- fused pool + predictor ----------------
__device__ __forceinline__ int lbound(const int* a, int n, int key) {
  int lo = 0, hi = n;
  while (lo < hi) {
    int mid = (lo + hi) >> 1;
    if (a[mid] < key) lo = mid + 1; else hi = mid;
  }
  return lo;
}

__global__ __launch_bounds__(256) void k_pool_pred(
    const float* __restrict__ x, const int* __restrict__ batch, int N,
    const float* __restrict__ pW1, const float* __restrict__ pb1,
    const float* __restrict__ pW2, const float* __restrict__ pb2,
    const float* __restrict__ pW3, const float* __restrict__ pb3,
    float* __restrict__ out) {
  int b = blockIdx.x;
  int lo = lbound(batch, N, b);
  int hi = lbound(batch, N, b + 1);
  int t = threadIdx.x;
  int ch = t & 63;
  int sl = t >> 6;
  float s = 0.f;
  for (int n = lo + sl; n < hi; n += 4) s += x[(size_t)n * 64 + ch];
  __shared__ float red4[4][64];
  __shared__ float sg[64];
  __shared__ float sh1[128];
  __shared__ float red[128];
  red4[sl][ch] = s;
  __syncthreads();
  if (t < 64) {
    float tot = red4[0][t] + red4[1][t] + red4[2][t] + red4[3][t];
    float cnt = (float)(hi - lo);
    sg[t] = tot / fmaxf(cnt, 1.0f);
  }
  __syncthreads();
  if (t < 128) {
    float h = pb1[t];
    for (int k = 0; k < 64; ++k) h = fmaf(sg[k], pW1[k * 128 + t], h);
    sh1[t] = sp_f(h);
  }
  __syncthreads();
  if (t < 128) {
    float h = pb2[t];
    for (int k = 0; k < 128; ++k) h = fmaf(sh1[k], pW2[k * 128 + t], h);
    red[t] = sp_f(h) * pW3[t];
  }
  __syncthreads();
  for (int off = 64; off > 0; off >>= 1) {
    if (t < off) red[t] += red[t + off];
    __syncthreads();
  }
  if (t == 0) out[b] = red[0] + pb3[0];
}

extern "C" void kernel_launch(void* const* d_in, const int* in_sizes, int n_in,
                              void* d_out, int out_size, void* d_ws, size_t ws_size,
                              hipStream_t stream) {
  const float* x         = (const float*)d_in[0];
  const float* edge_attr = (const float*)d_in[1];
  const float* charge    = (const float*)d_in[2];
  const int*   eidx      = (const int*)d_in[3];
  const int*   batch     = (const int*)d_in[4];
  const float* W_charge  = (const float*)d_in[5];
  const float* b_charge  = (const float*)d_in[6];
  const float* W_atom    = (const float*)d_in[7];
  const float* b_atom    = (const float*)d_in[8];
  const float* W_bond    = (const float*)d_in[9];
  const float* b_bond    = (const float*)d_in[10];
  const float* eW1 = (const float*)d_in[11];
  const float* eb1 = (const float*)d_in[12];
  const float* eW2 = (const float*)d_in[13];
  const float* eb2 = (const float*)d_in[14];
  const float* nW1 = (const float*)d_in[15];
  const float* nb1 = (const float*)d_in[16];
  const float* nW2 = (const float*)d_in[17];
  const float* nb2 = (const float*)d_in[18];
  const float* gam = (const float*)d_in[19];
  const float* bet = (const float*)d_in[20];
  const float* pW1 = (const float*)d_in[21];
  const float* pb1 = (const float*)d_in[22];
  const float* pW2 = (const float*)d_in[23];
  const float* pb2 = (const float*)d_in[24];
  const float* pW3 = (const float*)d_in[25];
  const float* pb3 = (const float*)d_in[26];

  int N = in_sizes[4];
  int E = in_sizes[3] / 2;
  int B = in_sizes[2];
  const int* row = eidx;
  const int* col = eidx + E;

  char* wptr = (char*)d_ws;
  unsigned short* ea16 = (unsigned short*)wptr; wptr += (((size_t)E * 64 * 2 + 255) & ~255ull);
  unsigned short* up16 = (unsigned short*)wptr; wptr += (((size_t)N * 128 * 2 + 255) & ~255ull);
  unsigned short* v16  = (unsigned short*)wptr; wptr += (((size_t)N * 64 * 2 + 255) & ~255ull);
  unsigned short* wfrag = (unsigned short*)wptr; wptr += 13 * 4096 * 2;
  float* xemb = (float*)wptr; wptr += (size_t)N * 64 * 4;
  float* xnew = (float*)wptr; wptr += (size_t)N * 64 * 4;
  float* bnacc = (float*)wptr; wptr += 256 * 4;
  int* counts = (int*)wptr;   wptr += (size_t)N * 4;
  int* scan_tmp = (int*)wptr; wptr += (size_t)N * 4;
  int* cursor = (int*)wptr;   wptr += (size_t)N * 4;
  int* bsum = (int*)wptr;     wptr += 4096;
  int* pos = (int*)wptr;      wptr += (size_t)E * 4;
  int* row_s = (int*)wptr;    wptr += (size_t)E * 4;
  int* col_s = (int*)wptr;    wptr += (size_t)E * 4;

  int NB = (N + 255) / 256;

  k_prep_wfrag<<<13, 256, 0, stream>>>(eW1, eW2, nW1, nW2, W_bond, wfrag);
  hipMemsetAsync(counts, 0, (size_t)N * 4, stream);
  k_hist<<<2048, 256, 0, stream>>>(col, counts, E);
  k_scan1<<<NB, 256, 0, stream>>>(counts, scan_tmp, bsum, N);
  k_scan2<<<1, 256, 0, stream>>>(bsum, NB);
  k_scan3<<<NB, 256, 0, stream>>>(counts, scan_tmp, bsum, cursor, N);
  k_scatter<<<2048, 256, 0, stream>>>(row, col, cursor, pos, row_s, col_s, E);

  int ntilesN = (N + 127) / 128;
  k_embed_nodes<<<ntilesN, 256, 0, stream>>>(x, batch, charge, W_charge,
                                             b_charge, W_atom, b_atom, xemb, N);
  k_embed_bonds_mfma<<<2048, 256, 0, stream>>>(edge_attr, pos,
                                               wfrag + 12 * 4096, b_bond,
                                               ea16, E);
  k_node_pre<<<NB, 256, 0, stream>>>(xemb, eW1, nW1, up16, v16, N);

  int gridE = (E + 127) / 128;
  for (int i = 0; i < 3; ++i) {
    hipMemsetAsync(xnew, 0, (size_t)N * 64 * 4, stream);
    hipMemsetAsync(bnacc, 0, 256 * 4, stream);
    k_edge_mfma<<<gridE, 256, 0, stream>>>(
        row_s, col_s, ea16, up16, v16, wfrag + (size_t)i * 16384,
        eb1 + (size_t)i * 64, eb2 + (size_t)i * 64, nb1 + (size_t)i * 64,
        nb2 + (size_t)i * 64, xnew, E, (i < 2) ? 1 : 0);
    k_bn_stats<<<1024, 256, 0, stream>>>(xnew, bnacc, N);
    if (i < 2) {
      k_bn_pre<<<NB, 256, 0, stream>>>(
          xemb, xnew, bnacc, gam + (size_t)i * 64, bet + (size_t)i * 64,
          eW1 + (size_t)(i + 1) * 192 * 64, nW1 + (size_t)(i + 1) * 128 * 64,
          up16, v16, N);
    } else {
      k_bn_apply<<<4096, 256, 0, stream>>>(xemb, xnew, bnacc,
                                           gam + (size_t)i * 64,
                                           bet + (size_t)i * 64, N);
    }
  }

  k_pool_pred<<<B, 256, 0, stream>>>(xemb, batch, N, pW1, pb1, pW2, pb2,
                                     pW3, pb3, (float*)d_out);
}

// Round 12
// 2002.036 us; speedup vs baseline: 1.1091x; 1.0114x over previous
//
#include <hip/hip_runtime.h>
#include <math.h>

typedef short v8s __attribute__((ext_vector_type(8)));   // 8 bf16
typedef float v4f __attribute__((ext_vector_type(4)));
typedef unsigned int u32x4 __attribute__((ext_vector_type(4)));

__device__ __forceinline__ u32x4 nt_load4(const void* p) {
  return __builtin_nontemporal_load((const u32x4*)p);
}
__device__ __forceinline__ void nt_store4(void* p, u32x4 v) {
  __builtin_nontemporal_store(v, (u32x4*)p);
}

// fast softplus: max(x,0) + ln2*log2(1+exp(-|x|)); HW exp/log, ~3e-5 abs err
__device__ __forceinline__ float sp_f(float x) {
  return fmaxf(x, 0.0f) + 0.69314718056f * __log2f(1.0f + __expf(-fabsf(x)));
}

__device__ __forceinline__ unsigned short f2bf(float f) {
  union { float f; unsigned u; } x; x.f = f;
  unsigned r = (x.u + 0x7FFF + ((x.u >> 16) & 1)) >> 16;
  return (unsigned short)r;
}

__device__ __forceinline__ float bf2f(unsigned short h) {
  union { unsigned u; float f; } x; x.u = ((unsigned)h) << 16;
  return x.f;
}

// ---------------- one-shot weight fragment prep (3 layers x 4 mats + W_bond) ----------------
__global__ __launch_bounds__(256) void k_prep_wfrag(
    const float* __restrict__ eW1, const float* __restrict__ eW2,
    const float* __restrict__ nW1, const float* __restrict__ nW2,
    const float* __restrict__ W_bond, unsigned short* __restrict__ wfrag) {
  if (blockIdx.x == 12) {
    unsigned short* out = wfrag + 12 * 4096;
    for (int f = threadIdx.x; f < 4096; f += 256) {
      int j = f & 7, ln = (f >> 3) & 63, kh = (f >> 9) & 1, ct = f >> 10;
      int k = kh * 32 + (ln >> 4) * 8 + j;
      int n = ct * 16 + (ln & 15);
      out[f] = (k < 41) ? f2bf(W_bond[k * 64 + n]) : 0;
    }
    return;
  }
  int i = blockIdx.x >> 2;   // layer
  int m = blockIdx.x & 3;    // matrix
  const float* W;
  if (m == 0)      W = eW1 + (size_t)i * 192 * 64 + 128 * 64;  // W1c
  else if (m == 1) W = eW2 + (size_t)i * 64 * 64;
  else if (m == 2) W = nW1 + (size_t)i * 128 * 64 + 64 * 64;   // nW1b
  else             W = nW2 + (size_t)i * 64 * 64;
  unsigned short* out = wfrag + ((size_t)i * 4 + m) * 4096;
  for (int f = threadIdx.x; f < 4096; f += 256) {
    int j = f & 7, ln = (f >> 3) & 63, kh = (f >> 9) & 1, ct = f >> 10;
    int k = kh * 32 + (ln >> 4) * 8 + j;
    int n = ct * 16 + (ln & 15);
    out[f] = f2bf(W[k * 64 + n]);
  }
}

// ---------------- node embedding, LDS-staged tiles + channel split ----------------
__global__ __launch_bounds__(256) void k_embed_nodes(
    const float* __restrict__ x, const int* __restrict__ batch,
    const float* __restrict__ charge, const float* __restrict__ W_charge,
    const float* __restrict__ b_charge, const float* __restrict__ W_atom,
    const float* __restrict__ b_atom, float* __restrict__ xemb, int N) {
  __shared__ float sW[108 * 64];   // 27.6 KB
  __shared__ float sX[128 * 92];   // 46 KB
  __shared__ float sb[64];
  __shared__ float sWc[16];
  __shared__ float sbc[16];
  for (int i = threadIdx.x; i < 108 * 64; i += blockDim.x) sW[i] = W_atom[i];
  if (threadIdx.x < 64) sb[threadIdx.x] = b_atom[threadIdx.x];
  if (threadIdx.x < 16) {
    sWc[threadIdx.x] = W_charge[threadIdx.x];
    sbc[threadIdx.x] = b_charge[threadIdx.x];
  }
  int ntiles = (N + 127) >> 7;
  for (int tile = blockIdx.x; tile < ntiles; tile += gridDim.x) {
    int base = tile << 7;
    int cnt = N - base; if (cnt > 128) cnt = 128;
    __syncthreads();
    if (cnt == 128) {
      const u32x4* src = (const u32x4*)(x + (size_t)base * 92);
      for (int i = threadIdx.x; i < 2944; i += 256)
        ((u32x4*)sX)[i] = nt_load4(&src[i]);
    } else {
      for (int i = threadIdx.x; i < cnt * 92; i += 256)
        sX[i] = x[(size_t)base * 92 + i];
    }
    __syncthreads();
    int t = threadIdx.x;
    int node = t & 127, half = t >> 7;
    if (node < cnt) {
      int n = base + node;
      float acc[32];
#pragma unroll
      for (int j = 0; j < 32; ++j) acc[j] = sb[half * 32 + j];
      const float* xr = sX + node * 92;
      for (int k = 0; k < 92; ++k) {
        float a = xr[k];
        const float* wk = sW + k * 64 + half * 32;
#pragma unroll
        for (int j = 0; j < 32; ++j) acc[j] = fmaf(a, wk[j], acc[j]);
      }
      float ch = charge[batch[n]];
#pragma unroll
      for (int c = 0; c < 16; ++c) {
        float cf = fmaf(ch, sWc[c], sbc[c]);
        const float* wk = sW + (92 + c) * 64 + half * 32;
#pragma unroll
        for (int j = 0; j < 32; ++j) acc[j] = fmaf(cf, wk[j], acc[j]);
      }
      float* o = xemb + (size_t)n * 64 + half * 32;
#pragma unroll
      for (int q8 = 0; q8 < 8; ++q8)
        ((float4*)o)[q8] = make_float4(acc[4*q8], acc[4*q8+1], acc[4*q8+2], acc[4*q8+3]);
    }
  }
}

// ---------------- CSR build ----------------
__global__ __launch_bounds__(256) void k_hist(const int* __restrict__ col,
                                              int* __restrict__ counts, int E) {
  int stride = gridDim.x * blockDim.x;
  for (int e = blockIdx.x * blockDim.x + threadIdx.x; e < E; e += stride)
    atomicAdd(&counts[col[e]], 1);
}

__global__ __launch_bounds__(256) void k_scan1(const int* __restrict__ counts,
                                               int* __restrict__ scan_tmp,
                                               int* __restrict__ bsum, int N) {
  __shared__ int sd[2][256];
  int t = threadIdx.x;
  int i = blockIdx.x * 256 + t;
  int v = (i < N) ? counts[i] : 0;
  sd[0][t] = v;
  __syncthreads();
  int s = 0;
#pragma unroll
  for (int off = 1; off < 256; off <<= 1) {
    int nv = sd[s][t];
    if (t >= off) nv += sd[s][t - off];
    sd[s ^ 1][t] = nv;
    s ^= 1;
    __syncthreads();
  }
  if (i < N) scan_tmp[i] = sd[s][t];
  if (t == 255) bsum[blockIdx.x] = sd[s][255];
}

__global__ __launch_bounds__(256) void k_scan2(int* __restrict__ b, int NB) {
  __shared__ int sd[2][256];
  __shared__ int carry_s;
  int t = threadIdx.x;
  if (t == 0) carry_s = 0;
  __syncthreads();
  for (int base = 0; base < NB; base += 256) {
    int i = base + t;
    int v = (i < NB) ? b[i] : 0;
    sd[0][t] = v;
    __syncthreads();
    int s = 0;
#pragma unroll
    for (int off = 1; off < 256; off <<= 1) {
      int nv = sd[s][t];
      if (t >= off) nv += sd[s][t - off];
      sd[s ^ 1][t] = nv;
      s ^= 1;
      __syncthreads();
    }
    int c = carry_s;
    int tot = sd[s][255];
    if (i < NB) b[i] = sd[s][t] + c;
    __syncthreads();
    if (t == 0) carry_s = c + tot;
    __syncthreads();
  }
}

__global__ __launch_bounds__(256) void k_scan3(const int* __restrict__ counts,
                                               const int* __restrict__ scan_tmp,
                                               const int* __restrict__ bsum,
                                               int* __restrict__ cursor, int N) {
  int i = blockIdx.x * 256 + threadIdx.x;
  if (i < N) {
    int base = (blockIdx.x > 0) ? bsum[blockIdx.x - 1] : 0;
    cursor[i] = scan_tmp[i] - counts[i] + base;
  }
}

__global__ __launch_bounds__(256) void k_scatter(
    const int* __restrict__ row, const int* __restrict__ col,
    int* __restrict__ cursor, int* __restrict__ pos,
    int* __restrict__ row_s, int* __restrict__ col_s, int E) {
  int stride = gridDim.x * blockDim.x;
  for (int e = blockIdx.x * blockDim.x + threadIdx.x; e < E; e += stride) {
    int c = col[e];
    int p = atomicAdd(&cursor[c], 1);
    pos[e] = p;
    row_s[p] = row[e];
    col_s[p] = c;
  }
}

// ---------------- bond embedding via MFMA: [128 edges x 41] @ [41 x 64] ----------------
__global__ __launch_bounds__(256) void k_embed_bonds_mfma(
    const float* __restrict__ eattr, const int* __restrict__ pos,
    const unsigned short* __restrict__ gWb, const float* __restrict__ b_bond,
    unsigned short* __restrict__ ea16, int E) {
  __shared__ unsigned short sA[128 * 64];  // 16 KB, swizzled
  __shared__ float sb[64];
  __shared__ int spos[128];
  int tid = threadIdx.x;
  int w = tid >> 6, l = tid & 63, q = l >> 4, c16 = l & 15;
  int rbase = w * 32;
  if (tid < 64) sb[tid] = b_bond[tid];
  int ntiles = (E + 127) >> 7;
  for (int tile = blockIdx.x; tile < ntiles; tile += gridDim.x) {
    int te = tile << 7;
    int cnt = E - te; if (cnt > 128) cnt = 128;
    __syncthreads();   // protect sA reuse across loop iterations
    uint4 z = make_uint4(0, 0, 0, 0);
    for (int i = tid; i < 1024; i += 256) ((uint4*)sA)[i] = z;
    __syncthreads();
    int nflt = cnt * 41;
    for (int i = tid; i < nflt; i += 256) {
      int r = i / 41, k = i - r * 41;
      float v = __builtin_nontemporal_load(&eattr[(size_t)te * 41 + i]);
      sA[r * 64 + (k ^ ((r & 7) << 3))] = f2bf(v);
    }
    if (tid < 128) spos[tid] = (te + tid < E) ? pos[te + tid] : -1;
    __syncthreads();
    v8s bfr[4][2], af[2][2];
    v4f acc[2][4];
    const v8s* wp_ = (const v8s*)gWb;
#pragma unroll
    for (int ct = 0; ct < 4; ++ct)
#pragma unroll
      for (int kh = 0; kh < 2; ++kh)
        bfr[ct][kh] = wp_[(ct * 2 + kh) * 64 + l];
#pragma unroll
    for (int rb = 0; rb < 2; ++rb)
#pragma unroll
      for (int kh = 0; kh < 2; ++kh) {
        int row_ = rbase + rb * 16 + c16;
        af[rb][kh] = *(const v8s*)&sA[row_ * 64 +
                                      ((kh * 32 + q * 8) ^ ((row_ & 7) << 3))];
      }
#pragma unroll
    for (int rb = 0; rb < 2; ++rb)
#pragma unroll
      for (int ct = 0; ct < 4; ++ct) {
        v4f a_ = {0.f, 0.f, 0.f, 0.f};
        a_ = __builtin_amdgcn_mfma_f32_16x16x32_bf16(af[rb][0], bfr[ct][0], a_, 0, 0, 0);
        a_ = __builtin_amdgcn_mfma_f32_16x16x32_bf16(af[rb][1], bfr[ct][1], a_, 0, 0, 0);
        acc[rb][ct] = a_;
      }
#pragma unroll
    for (int rb = 0; rb < 2; ++rb)
#pragma unroll
      for (int ct = 0; ct < 4; ++ct) {
        int n = ct * 16 + c16;
#pragma unroll
        for (int r = 0; r < 4; ++r) {
          float v = acc[rb][ct][r] + sb[n];
          int row = rbase + rb * 16 + q * 4 + r;
          sA[row * 64 + (n ^ ((row & 7) << 3))] = f2bf(v);
        }
      }
    __syncthreads();
    for (int i = tid; i < 1024; i += 256) {
      int r = i >> 3, cc = i & 7;
      int p = spos[r];
      if (p >= 0) {
        u32x4 d = *(const u32x4*)&sA[r * 64 + ((cc * 8) ^ ((r & 7) << 3))];
        nt_store4(&ea16[(size_t)p * 64 + cc * 8], d);
      }
    }
  }
}

// ---------------- node-side precompute body (R5 layout) ----------------
__device__ __forceinline__ void node_pre_body(
    const float* __restrict__ xr, const float* sWa, const float* sWb,
    const float* sWp, unsigned short* __restrict__ up16,
    unsigned short* __restrict__ v16, int n) {
  const float4* xr4 = (const float4*)xr;
  float u[64], p[64];
#pragma unroll
  for (int j = 0; j < 64; ++j) { u[j] = 0.f; p[j] = 0.f; }
  for (int k4 = 0; k4 < 16; ++k4) {
    float4 av = xr4[k4];
    const float* wa = sWa + k4 * 256;
    const float* wp = sWp + k4 * 256;
#pragma unroll
    for (int j = 0; j < 64; ++j) u[j] = fmaf(av.x, wa[j], u[j]);
#pragma unroll
    for (int j = 0; j < 64; ++j) p[j] = fmaf(av.x, wp[j], p[j]);
#pragma unroll
    for (int j = 0; j < 64; ++j) u[j] = fmaf(av.y, wa[64 + j], u[j]);
#pragma unroll
    for (int j = 0; j < 64; ++j) p[j] = fmaf(av.y, wp[64 + j], p[j]);
#pragma unroll
    for (int j = 0; j < 64; ++j) u[j] = fmaf(av.z, wa[128 + j], u[j]);
#pragma unroll
    for (int j = 0; j < 64; ++j) p[j] = fmaf(av.z, wp[128 + j], p[j]);
#pragma unroll
    for (int j = 0; j < 64; ++j) u[j] = fmaf(av.w, wa[192 + j], u[j]);
#pragma unroll
    for (int j = 0; j < 64; ++j) p[j] = fmaf(av.w, wp[192 + j], p[j]);
  }
  unsigned short* o = up16 + (size_t)n * 128;
#pragma unroll
  for (int q8 = 0; q8 < 8; ++q8) {
    unsigned short tmp[8];
#pragma unroll
    for (int j = 0; j < 8; ++j) {
      int i = q8 * 8 + j;
      tmp[j] = f2bf(u[((i & 3) << 4) | (i >> 2)]);
    }
    *(uint4*)&o[q8 * 8] = *(uint4*)tmp;
  }
#pragma unroll
  for (int q8 = 0; q8 < 8; ++q8) {
    unsigned short tmp[8];
#pragma unroll
    for (int j = 0; j < 8; ++j) {
      int i = q8 * 8 + j;
      tmp[j] = f2bf(p[((i & 3) << 4) | (i >> 2)]);
    }
    *(uint4*)&o[64 + q8 * 8] = *(uint4*)tmp;
  }
  float vv[64];
#pragma unroll
  for (int j = 0; j < 64; ++j) vv[j] = 0.f;
  for (int k4 = 0; k4 < 16; ++k4) {
    float4 av = xr4[k4];
    const float* wb = sWb + k4 * 256;
#pragma unroll
    for (int j = 0; j < 64; ++j) vv[j] = fmaf(av.x, wb[j], vv[j]);
#pragma unroll
    for (int j = 0; j < 64; ++j) vv[j] = fmaf(av.y, wb[64 + j], vv[j]);
#pragma unroll
    for (int j = 0; j < 64; ++j) vv[j] = fmaf(av.z, wb[128 + j], vv[j]);
#pragma unroll
    for (int j = 0; j < 64; ++j) vv[j] = fmaf(av.w, wb[192 + j], vv[j]);
  }
  unsigned short* ov = v16 + (size_t)n * 64;
#pragma unroll
  for (int q8 = 0; q8 < 8; ++q8) {
    unsigned short tmp[8];
#pragma unroll
    for (int j = 0; j < 8; ++j) {
      int i = q8 * 8 + j;
      tmp[j] = f2bf(vv[((i & 3) << 4) | (i >> 2)]);
    }
    *(uint4*)&ov[q8 * 8] = *(uint4*)tmp;
  }
}

// also zeroes xnew row n (removes a standalone memset dispatch)
__global__ __launch_bounds__(256) void k_node_pre(
    const float* __restrict__ xemb, const float* __restrict__ eW1,
    const float* __restrict__ nW1, unsigned short* __restrict__ up16,
    unsigned short* __restrict__ v16, float* __restrict__ xnew, int N) {
  __shared__ float sWa[64 * 64];
  __shared__ float sWb[64 * 64];
  __shared__ float sWp[64 * 64];
  for (int i = threadIdx.x; i < 64 * 64; i += blockDim.x) {
    sWa[i] = eW1[i];
    sWb[i] = eW1[64 * 64 + i];
    sWp[i] = nW1[i];
  }
  __syncthreads();
  int stride = gridDim.x * blockDim.x;
  float4 z = make_float4(0.f, 0.f, 0.f, 0.f);
  for (int n = blockIdx.x * blockDim.x + threadIdx.x; n < N; n += stride) {
    node_pre_body(xemb + (size_t)n * 64, sWa, sWb, sWp, up16, v16, n);
    float4* xz = (float4*)(xnew + (size_t)n * 64);
#pragma unroll
    for (int q = 0; q < 16; ++q) xz[q] = z;
  }
}

// ---------------- fused BN apply + residual + next-layer node_pre (+xnew clear) ----------------
__global__ __launch_bounds__(256) void k_bn_pre(
    float* __restrict__ xemb, float* __restrict__ xnew,
    const float* __restrict__ bnacc, const float* __restrict__ gamma,
    const float* __restrict__ beta, const float* __restrict__ eW1n,
    const float* __restrict__ nW1n, unsigned short* __restrict__ up16,
    unsigned short* __restrict__ v16, int N) {
  __shared__ float sWa[64 * 64];
  __shared__ float sWb[64 * 64];
  __shared__ float sWp[64 * 64];
  __shared__ float sscale[64], sshift[64];
  for (int i = threadIdx.x; i < 64 * 64; i += blockDim.x) {
    sWa[i] = eW1n[i];
    sWb[i] = eW1n[64 * 64 + i];
    sWp[i] = nW1n[i];
  }
  if (threadIdx.x < 64) {
    float inv = 1.0f / (float)N;
    float m = bnacc[threadIdx.x] * inv;
    float var = bnacc[64 + threadIdx.x] * inv - m * m;
    float rs = rsqrtf(var + 1e-5f);
    float g = gamma[threadIdx.x];
    sscale[threadIdx.x] = rs * g;
    sshift[threadIdx.x] = beta[threadIdx.x] - m * rs * g;
  }
  __syncthreads();
  int stride = gridDim.x * blockDim.x;
  float4 z = make_float4(0.f, 0.f, 0.f, 0.f);
  for (int n = blockIdx.x * blockDim.x + threadIdx.x; n < N; n += stride) {
    float* xr = xemb + (size_t)n * 64;
    float4* xnrow = (float4*)(xnew + (size_t)n * 64);
#pragma unroll
    for (int q = 0; q < 16; ++q) {
      float4 xn4 = xnrow[q];
      float4 xo4 = ((const float4*)xr)[q];
      xo4.x += sp_f(fmaf(xn4.x, sscale[4*q+0], sshift[4*q+0]));
      xo4.y += sp_f(fmaf(xn4.y, sscale[4*q+1], sshift[4*q+1]));
      xo4.z += sp_f(fmaf(xn4.z, sscale[4*q+2], sshift[4*q+2]));
      xo4.w += sp_f(fmaf(xn4.w, sscale[4*q+3], sshift[4*q+3]));
      ((float4*)xr)[q] = xo4;
      xnrow[q] = z;     // clear for next layer's atomics/stores
    }
    node_pre_body(xr, sWa, sWb, sWp, up16, v16, n);
  }
}

// ---------------- fused per-layer edge kernel, MFMA bf16, 4 waves x 32 rows ----------------
// LDS padded to 41 KB to cap occupancy at 3 blocks/CU (footprint < per-XCD L2)
#define READ_FRAGS(P)                                                        \
  {                                                                          \
    const v8s* wp_ = (const v8s*)gWf + (P) * 512;                            \
    _Pragma("unroll") for (int ct = 0; ct < 4; ++ct)                         \
        _Pragma("unroll") for (int kh = 0; kh < 2; ++kh)                     \
            bfr[ct][kh] = wp_[(ct * 2 + kh) * 64 + l];                       \
    _Pragma("unroll") for (int rb = 0; rb < 2; ++rb)                         \
        _Pragma("unroll") for (int kh = 0; kh < 2; ++kh) {                   \
      int row_ = rbase + rb * 16 + c16;                                      \
      af[rb][kh] = *(const v8s*)&sA[row_ * 64 +                              \
                                    ((kh * 32 + q * 8) ^ ((row_ & 7) << 3))];\
    }                                                                        \
  }

#define DO_MFMA()                                                            \
  _Pragma("unroll") for (int rb = 0; rb < 2; ++rb)                           \
      _Pragma("unroll") for (int ct = 0; ct < 4; ++ct) {                     \
    v4f a_ = {0.f, 0.f, 0.f, 0.f};                                           \
    a_ = __builtin_amdgcn_mfma_f32_16x16x32_bf16(af[rb][0], bfr[ct][0], a_,  \
                                                 0, 0, 0);                   \
    a_ = __builtin_amdgcn_mfma_f32_16x16x32_bf16(af[rb][1], bfr[ct][1], a_,  \
                                                 0, 0, 0);                   \
    acc[rb][ct] = a_;                                                        \
  }

__global__ __launch_bounds__(256, 3) void k_edge_mfma(
    const int* __restrict__ row_s, const int* __restrict__ col_s,
    unsigned short* __restrict__ ea16, const unsigned short* __restrict__ up16,
    const unsigned short* __restrict__ v16,
    const unsigned short* __restrict__ gWf, const float* __restrict__ eb1,
    const float* __restrict__ eb2, const float* __restrict__ nb1,
    const float* __restrict__ nb2, float* __restrict__ xnew,
    float* __restrict__ bnacc, int E, int store_ea) {
  __shared__ __align__(16) unsigned char smem[41984];   // padded: 3 blocks/CU
  unsigned short* sA = (unsigned short*)smem;             // 16 KB (aliased)
  float* msgb        = (float*)smem;                      // 32 KB
  float* sBb         = (float*)(smem + 32768);            // 1 KB
  int* scol          = (int*)(smem + 33792);              // 512 B

  int tid = threadIdx.x;
  int te = blockIdx.x * 128;
  int w = tid >> 6, l = tid & 63, q = l >> 4, c16 = l & 15;
  int rbase = w * 32;

  // zero bnacc for the following bn_stats (replaces a memset dispatch)
  if (blockIdx.x == 0 && tid < 128) bnacc[tid] = 0.0f;

  int rid[2][4], cid[2][4], eid[2][4];
#pragma unroll
  for (int rb = 0; rb < 2; ++rb)
#pragma unroll
    for (int r = 0; r < 4; ++r) {
      int e = te + rbase + rb * 16 + q * 4 + r;
      eid[rb][r] = e;
      int ec = e < E ? e : E - 1;
      rid[rb][r] = row_s[ec];
      cid[rb][r] = col_s[ec];
    }
  // split gathers: u + v issued early
  ushort4 uu_pf[2][4], vv_pf[2][4];
#pragma unroll
  for (int rb = 0; rb < 2; ++rb)
#pragma unroll
    for (int r = 0; r < 4; ++r) {
      uu_pf[rb][r] = *(const ushort4*)&up16[(size_t)rid[rb][r] * 128 + c16 * 4];
      vv_pf[rb][r] = *(const ushort4*)&v16[(size_t)cid[rb][r] * 64 + c16 * 4];
    }

  if (tid < 64) {
    sBb[0 * 64 + tid] = eb1[tid];
    sBb[1 * 64 + tid] = eb2[tid];
    sBb[2 * 64 + tid] = nb1[tid];
    sBb[3 * 64 + tid] = nb2[tid];
  }
  if (tid < 128) {
    int e = te + tid;
    scol[tid] = col_s[e < E ? e : E - 1];
  }
  for (int i = tid; i < 1024; i += 256) {
    int r = i >> 3, cc = i & 7;
    int e = te + r;
    if (e >= E) e = E - 1;
    u32x4 d = nt_load4(&ea16[(size_t)e * 64 + cc * 8]);
    *(u32x4*)&sA[r * 64 + ((cc * 8) ^ ((r & 7) << 3))] = d;
  }

  v8s af[2][2];
  v8s bfr[4][2];
  v4f acc[2][4];

  __syncthreads();   // staging done

  // ---- phase 0: T = sp(ea@W1c + b1 + u[row] + v[col]) ----
  READ_FRAGS(0);
  DO_MFMA();
  ushort4 pp_pf[2][4];
#pragma unroll
  for (int rb = 0; rb < 2; ++rb)
#pragma unroll
    for (int r = 0; r < 4; ++r)
      pp_pf[rb][r] =
          *(const ushort4*)&up16[(size_t)rid[rb][r] * 128 + 64 + c16 * 4];
#pragma unroll
  for (int rb = 0; rb < 2; ++rb)
#pragma unroll
    for (int r = 0; r < 4; ++r) {
      const unsigned short* up_ = (const unsigned short*)&uu_pf[rb][r];
      const unsigned short* vp_ = (const unsigned short*)&vv_pf[rb][r];
      int row = rbase + rb * 16 + q * 4 + r;
#pragma unroll
      for (int ct = 0; ct < 4; ++ct) {
        int n = ct * 16 + c16;
        float t = acc[rb][ct][r] + sBb[n] + bf2f(up_[ct]) + bf2f(vp_[ct]);
        t = sp_f(t);
        sA[row * 64 + (n ^ ((row & 7) << 3))] = f2bf(t);
      }
    }

  // ---- phase 1: ea' = T@eW2 + b2 -> sA (own band) ----
  READ_FRAGS(1);
  DO_MFMA();
#pragma unroll
  for (int rb = 0; rb < 2; ++rb)
#pragma unroll
    for (int ct = 0; ct < 4; ++ct) {
      int n = ct * 16 + c16;
#pragma unroll
      for (int r = 0; r < 4; ++r) {
        float en = acc[rb][ct][r] + sBb[64 + n];
        int row = rbase + rb * 16 + q * 4 + r;
        sA[row * 64 + (n ^ ((row & 7) << 3))] = f2bf(en);
      }
    }
  if (store_ea) {
    __syncthreads();   // writeback reads all rows
    for (int i = tid; i < 1024; i += 256) {
      int r = i >> 3, cc = i & 7;
      if (te + r < E) {
        u32x4 d = *(const u32x4*)&sA[r * 64 + ((cc * 8) ^ ((r & 7) << 3))];
        nt_store4(&ea16[(size_t)(te + r) * 64 + cc * 8], d);
      }
    }
    __syncthreads();   // phase-2 epi writes must not race writeback reads
  }

  // ---- phase 2: T2 = sp(ea'@nW1b + b3 + p[row]) ----
  READ_FRAGS(2);
  DO_MFMA();
#pragma unroll
  for (int rb = 0; rb < 2; ++rb)
#pragma unroll
    for (int r = 0; r < 4; ++r) {
      const unsigned short* pp_ = (const unsigned short*)&pp_pf[rb][r];
      int row = rbase + rb * 16 + q * 4 + r;
#pragma unroll
      for (int ct = 0; ct < 4; ++ct) {
        int n = ct * 16 + c16;
        float t2 = acc[rb][ct][r] + sBb[128 + n] + bf2f(pp_[ct]);
        t2 = sp_f(t2);
        sA[row * 64 + (n ^ ((row & 7) << 3))] = f2bf(t2);
      }
    }

  // ---- phase 3: msg = T2@nW2 + b4 -> msgb (sA dead after frag loads) ----
  READ_FRAGS(3);
  __syncthreads();   // all waves done reading sA; msgb alias safe
  DO_MFMA();
#pragma unroll
  for (int rb = 0; rb < 2; ++rb)
#pragma unroll
    for (int ct = 0; ct < 4; ++ct) {
      int n = ct * 16 + c16;
#pragma unroll
      for (int r = 0; r < 4; ++r) {
        float msg = acc[rb][ct][r] + sBb[192 + n];
        int row = rbase + rb * 16 + q * 4 + r;
        msgb[row * 64 + n] = (eid[rb][r] < E) ? msg : 0.0f;
      }
    }
  __syncthreads();

  // ---- segmented reduction; plain store for interior (exclusive) segments ----
  int nrows = E - te;
  if (nrows > 128) nrows = 128;
  for (int r0 = w; r0 < nrows; r0 += 4) {
    int c0 = scol[r0];
    if (r0 > 0 && scol[r0 - 1] == c0) continue;
    float s = 0.0f;
    int r = r0;
    do {
      s += msgb[r * 64 + l];
      ++r;
    } while (r < nrows && scol[r] == c0);
    if (r0 > 0 && r < nrows)
      xnew[(size_t)c0 * 64 + l] = s;     // run fully interior: exclusive writer
    else
      atomicAdd(&xnew[(size_t)c0 * 64 + l], s);
  }
}

// ---------------- BN stats ----------------
__global__ __launch_bounds__(256) void k_bn_stats(
    const float* __restrict__ xnew, float* __restrict__ bnacc, int N) {
  int t = threadIdx.x;
  int ch = t & 63;
  int sl = t >> 6;
  float s = 0.f, s2 = 0.f;
  for (int n = blockIdx.x * 4 + sl; n < N; n += gridDim.x * 4) {
    float v = xnew[(size_t)n * 64 + ch];
    s += v;
    s2 = fmaf(v, v, s2);
  }
  __shared__ float red[256], red2[256];
  red[t] = s;
  red2[t] = s2;
  __syncthreads();
  if (sl == 0) {
    s = red[ch] + red[64 + ch] + red[128 + ch] + red[192 + ch];
    s2 = red2[ch] + red2[64 + ch] + red2[128 + ch] + red2[192 + ch];
    atomicAdd(&bnacc[ch], s);
    atomicAdd(&bnacc[64 + ch], s2);
  }
}

// ---------------- BN apply + softplus + residual (last layer) ----------------
__global__ __launch_bounds__(256) void k_bn_apply(
    float* __restrict__ x, const float* __restrict__ xnew,
    const float* __restrict__ bnacc, const float* __restrict__ gamma,
    const float* __restrict__ beta, int N) {
  __shared__ float sscale[64], sshift[64];
  if (threadIdx.x < 64) {
    float inv = 1.0f / (float)N;
    float m = bnacc[threadIdx.x] * inv;
    float var = bnacc[64 + threadIdx.x] * inv - m * m;
    float rs = rsqrtf(var + 1e-5f);
    float g = gamma[threadIdx.x];
    sscale[threadIdx.x] = rs * g;
    sshift[threadIdx.x] = beta[threadIdx.x] - m * rs * g;
  }
  __syncthreads();
  size_t total = (size_t)N * 64;
  size_t stride = (size_t)gridDim.x * blockDim.x;
  for (size_t i = (size_t)blockIdx.x * blockDim.x + threadIdx.x; i < total; i += stride) {
    int ch = (int)(i & 63);
    float v = fmaf(xnew[i], sscale[ch], sshift[ch]);
    x[i] += sp_f(v);
  }
}

// ---------------- fused pool + predictor ----------------
__device__ __forceinline__ int lbound(const int* a, int n, int key) {
  int lo = 0, hi = n;
  while (lo < hi) {
    int mid = (lo + hi) >> 1;
    if (a[mid] < key) lo = mid + 1; else hi = mid;
  }
  return lo;
}

__global__ __launch_bounds__(256) void k_pool_pred(
    const float* __restrict__ x, const int* __restrict__ batch, int N,
    const float* __restrict__ pW1, const float* __restrict__ pb1,
    const float* __restrict__ pW2, const float* __restrict__ pb2,
    const float* __restrict__ pW3, const float* __restrict__ pb3,
    float* __restrict__ out) {
  int b = blockIdx.x;
  int lo = lbound(batch, N, b);
  int hi = lbound(batch, N, b + 1);
  int t = threadIdx.x;
  int ch = t & 63;
  int sl = t >> 6;
  float s = 0.f;
  for (int n = lo + sl; n < hi; n += 4) s += x[(size_t)n * 64 + ch];
  __shared__ float red4[4][64];
  __shared__ float sg[64];
  __shared__ float sh1[128];
  __shared__ float red[128];
  red4[sl][ch] = s;
  __syncthreads();
  if (t < 64) {
    float tot = red4[0][t] + red4[1][t] + red4[2][t] + red4[3][t];
    float cnt = (float)(hi - lo);
    sg[t] = tot / fmaxf(cnt, 1.0f);
  }
  __syncthreads();
  if (t < 128) {
    float h = pb1[t];
    for (int k = 0; k < 64; ++k) h = fmaf(sg[k], pW1[k * 128 + t], h);
    sh1[t] = sp_f(h);
  }
  __syncthreads();
  if (t < 128) {
    float h = pb2[t];
    for (int k = 0; k < 128; ++k) h = fmaf(sh1[k], pW2[k * 128 + t], h);
    red[t] = sp_f(h) * pW3[t];
  }
  __syncthreads();
  for (int off = 64; off > 0; off >>= 1) {
    if (t < off) red[t] += red[t + off];
    __syncthreads();
  }
  if (t == 0) out[b] = red[0] + pb3[0];
}

extern "C" void kernel_launch(void* const* d_in, const int* in_sizes, int n_in,
                              void* d_out, int out_size, void* d_ws, size_t ws_size,
                              hipStream_t stream) {
  const float* x         = (const float*)d_in[0];
  const float* edge_attr = (const float*)d_in[1];
  const float* charge    = (const float*)d_in[2];
  const int*   eidx      = (const int*)d_in[3];
  const int*   batch     = (const int*)d_in[4];
  const float* W_charge  = (const float*)d_in[5];
  const float* b_charge  = (const float*)d_in[6];
  const float* W_atom    = (const float*)d_in[7];
  const float* b_atom    = (const float*)d_in[8];
  const float* W_bond    = (const float*)d_in[9];
  const float* b_bond    = (const float*)d_in[10];
  const float* eW1 = (const float*)d_in[11];
  const float* eb1 = (const float*)d_in[12];
  const float* eW2 = (const float*)d_in[13];
  const float* eb2 = (const float*)d_in[14];
  const float* nW1 = (const float*)d_in[15];
  const float* nb1 = (const float*)d_in[16];
  const float* nW2 = (const float*)d_in[17];
  const float* nb2 = (const float*)d_in[18];
  const float* gam = (const float*)d_in[19];
  const float* bet = (const float*)d_in[20];
  const float* pW1 = (const float*)d_in[21];
  const float* pb1 = (const float*)d_in[22];
  const float* pW2 = (const float*)d_in[23];
  const float* pb2 = (const float*)d_in[24];
  const float* pW3 = (const float*)d_in[25];
  const float* pb3 = (const float*)d_in[26];

  int N = in_sizes[4];
  int E = in_sizes[3] / 2;
  int B = in_sizes[2];
  const int* row = eidx;
  const int* col = eidx + E;

  char* wptr = (char*)d_ws;
  unsigned short* ea16 = (unsigned short*)wptr; wptr += (((size_t)E * 64 * 2 + 255) & ~255ull);
  unsigned short* up16 = (unsigned short*)wptr; wptr += (((size_t)N * 128 * 2 + 255) & ~255ull);
  unsigned short* v16  = (unsigned short*)wptr; wptr += (((size_t)N * 64 * 2 + 255) & ~255ull);
  unsigned short* wfrag = (unsigned short*)wptr; wptr += 13 * 4096 * 2;
  float* xemb = (float*)wptr; wptr += (size_t)N * 64 * 4;
  float* xnew = (float*)wptr; wptr += (size_t)N * 64 * 4;
  float* bnacc = (float*)wptr; wptr += 256 * 4;
  int* counts = (int*)wptr;   wptr += (size_t)N * 4;
  int* scan_tmp = (int*)wptr; wptr += (size_t)N * 4;
  int* cursor = (int*)wptr;   wptr += (size_t)N * 4;
  int* bsum = (int*)wptr;     wptr += 4096;
  int* pos = (int*)wptr;      wptr += (size_t)E * 4;
  int* row_s = (int*)wptr;    wptr += (size_t)E * 4;
  int* col_s = (int*)wptr;    wptr += (size_t)E * 4;

  int NB = (N + 255) / 256;

  k_prep_wfrag<<<13, 256, 0, stream>>>(eW1, eW2, nW1, nW2, W_bond, wfrag);
  hipMemsetAsync(counts, 0, (size_t)N * 4, stream);
  k_hist<<<2048, 256, 0, stream>>>(col, counts, E);
  k_scan1<<<NB, 256, 0, stream>>>(counts, scan_tmp, bsum, N);
  k_scan2<<<1, 256, 0, stream>>>(bsum, NB);
  k_scan3<<<NB, 256, 0, stream>>>(counts, scan_tmp, bsum, cursor, N);
  k_scatter<<<2048, 256, 0, stream>>>(row, col, cursor, pos, row_s, col_s, E);

  int ntilesN = (N + 127) / 128;
  k_embed_nodes<<<ntilesN, 256, 0, stream>>>(x, batch, charge, W_charge,
                                             b_charge, W_atom, b_atom, xemb, N);
  k_embed_bonds_mfma<<<2048, 256, 0, stream>>>(edge_attr, pos,
                                               wfrag + 12 * 4096, b_bond,
                                               ea16, E);
  k_node_pre<<<NB, 256, 0, stream>>>(xemb, eW1, nW1, up16, v16, xnew, N);

  int gridE = (E + 127) / 128;
  for (int i = 0; i < 3; ++i) {
    k_edge_mfma<<<gridE, 256, 0, stream>>>(
        row_s, col_s, ea16, up16, v16, wfrag + (size_t)i * 16384,
        eb1 + (size_t)i * 64, eb2 + (size_t)i * 64, nb1 + (size_t)i * 64,
        nb2 + (size_t)i * 64, xnew, bnacc, E, (i < 2) ? 1 : 0);
    k_bn_stats<<<1024, 256, 0, stream>>>(xnew, bnacc, N);
    if (i < 2) {
      k_bn_pre<<<NB, 256, 0, stream>>>(
          xemb, xnew, bnacc, gam + (size_t)i * 64, bet + (size_t)i * 64,
          eW1 + (size_t)(i + 1) * 192 * 64, nW1 + (size_t)(i + 1) * 128 * 64,
          up16, v16, N);
    } else {
      k_bn_apply<<<4096, 256, 0, stream>>>(xemb, xnew, bnacc,
                                           gam + (size_t)i * 64,
                                           bet + (size_t)i * 64, N);
    }
  }

  k_pool_pred<<<B, 256, 0, stream>>>(xemb, batch, N, pW1, pb1, pW2, pb2,
                                     pW3, pb3, (float*)d_out);
}

// Round 13
// 1990.934 us; speedup vs baseline: 1.1153x; 1.0056x over previous
//
#include <hip/hip_runtime.h>
#include <math.h>

typedef short v8s __attribute__((ext_vector_type(8)));   // 8 bf16
typedef float v4f __attribute__((ext_vector_type(4)));
typedef unsigned int u32x4 __attribute__((ext_vector_type(4)));

__device__ __forceinline__ u32x4 nt_load4(const void* p) {
  return __builtin_nontemporal_load((const u32x4*)p);
}
__device__ __forceinline__ void nt_store4(void* p, u32x4 v) {
  __builtin_nontemporal_store(v, (u32x4*)p);
}

// fast softplus: max(x,0) + ln2*log2(1+exp(-|x|)); HW exp/log, ~3e-5 abs err
__device__ __forceinline__ float sp_f(float x) {
  return fmaxf(x, 0.0f) + 0.69314718056f * __log2f(1.0f + __expf(-fabsf(x)));
}

__device__ __forceinline__ unsigned short f2bf(float f) {
  union { float f; unsigned u; } x; x.f = f;
  unsigned r = (x.u + 0x7FFF + ((x.u >> 16) & 1)) >> 16;
  return (unsigned short)r;
}

__device__ __forceinline__ float bf2f(unsigned short h) {
  union { unsigned u; float f; } x; x.u = ((unsigned)h) << 16;
  return x.f;
}

// ---------------- one-shot weight fragment prep (3 layers x 4 mats + W_bond) ----------------
__global__ __launch_bounds__(256) void k_prep_wfrag(
    const float* __restrict__ eW1, const float* __restrict__ eW2,
    const float* __restrict__ nW1, const float* __restrict__ nW2,
    const float* __restrict__ W_bond, unsigned short* __restrict__ wfrag) {
  if (blockIdx.x == 12) {
    unsigned short* out = wfrag + 12 * 4096;
    for (int f = threadIdx.x; f < 4096; f += 256) {
      int j = f & 7, ln = (f >> 3) & 63, kh = (f >> 9) & 1, ct = f >> 10;
      int k = kh * 32 + (ln >> 4) * 8 + j;
      int n = ct * 16 + (ln & 15);
      out[f] = (k < 41) ? f2bf(W_bond[k * 64 + n]) : 0;
    }
    return;
  }
  int i = blockIdx.x >> 2;   // layer
  int m = blockIdx.x & 3;    // matrix
  const float* W;
  if (m == 0)      W = eW1 + (size_t)i * 192 * 64 + 128 * 64;  // W1c
  else if (m == 1) W = eW2 + (size_t)i * 64 * 64;
  else if (m == 2) W = nW1 + (size_t)i * 128 * 64 + 64 * 64;   // nW1b
  else             W = nW2 + (size_t)i * 64 * 64;
  unsigned short* out = wfrag + ((size_t)i * 4 + m) * 4096;
  for (int f = threadIdx.x; f < 4096; f += 256) {
    int j = f & 7, ln = (f >> 3) & 63, kh = (f >> 9) & 1, ct = f >> 10;
    int k = kh * 32 + (ln >> 4) * 8 + j;
    int n = ct * 16 + (ln & 15);
    out[f] = f2bf(W[k * 64 + n]);
  }
}

// ---------------- node embedding, LDS-staged tiles + channel split ----------------
__global__ __launch_bounds__(256) void k_embed_nodes(
    const float* __restrict__ x, const int* __restrict__ batch,
    const float* __restrict__ charge, const float* __restrict__ W_charge,
    const float* __restrict__ b_charge, const float* __restrict__ W_atom,
    const float* __restrict__ b_atom, float* __restrict__ xemb, int N) {
  __shared__ float sW[108 * 64];   // 27.6 KB
  __shared__ float sX[128 * 92];   // 46 KB
  __shared__ float sb[64];
  __shared__ float sWc[16];
  __shared__ float sbc[16];
  for (int i = threadIdx.x; i < 108 * 64; i += blockDim.x) sW[i] = W_atom[i];
  if (threadIdx.x < 64) sb[threadIdx.x] = b_atom[threadIdx.x];
  if (threadIdx.x < 16) {
    sWc[threadIdx.x] = W_charge[threadIdx.x];
    sbc[threadIdx.x] = b_charge[threadIdx.x];
  }
  int ntiles = (N + 127) >> 7;
  for (int tile = blockIdx.x; tile < ntiles; tile += gridDim.x) {
    int base = tile << 7;
    int cnt = N - base; if (cnt > 128) cnt = 128;
    __syncthreads();
    if (cnt == 128) {
      const u32x4* src = (const u32x4*)(x + (size_t)base * 92);
      for (int i = threadIdx.x; i < 2944; i += 256)
        ((u32x4*)sX)[i] = nt_load4(&src[i]);
    } else {
      for (int i = threadIdx.x; i < cnt * 92; i += 256)
        sX[i] = x[(size_t)base * 92 + i];
    }
    __syncthreads();
    int t = threadIdx.x;
    int node = t & 127, half = t >> 7;
    if (node < cnt) {
      int n = base + node;
      float acc[32];
#pragma unroll
      for (int j = 0; j < 32; ++j) acc[j] = sb[half * 32 + j];
      const float* xr = sX + node * 92;
      for (int k = 0; k < 92; ++k) {
        float a = xr[k];
        const float* wk = sW + k * 64 + half * 32;
#pragma unroll
        for (int j = 0; j < 32; ++j) acc[j] = fmaf(a, wk[j], acc[j]);
      }
      float ch = charge[batch[n]];
#pragma unroll
      for (int c = 0; c < 16; ++c) {
        float cf = fmaf(ch, sWc[c], sbc[c]);
        const float* wk = sW + (92 + c) * 64 + half * 32;
#pragma unroll
        for (int j = 0; j < 32; ++j) acc[j] = fmaf(cf, wk[j], acc[j]);
      }
      float* o = xemb + (size_t)n * 64 + half * 32;
#pragma unroll
      for (int q8 = 0; q8 < 8; ++q8)
        ((float4*)o)[q8] = make_float4(acc[4*q8], acc[4*q8+1], acc[4*q8+2], acc[4*q8+3]);
    }
  }
}

// ---------------- CSR build ----------------
__global__ __launch_bounds__(256) void k_hist(const int* __restrict__ col,
                                              int* __restrict__ counts, int E) {
  int stride = gridDim.x * blockDim.x;
  for (int e = blockIdx.x * blockDim.x + threadIdx.x; e < E; e += stride)
    atomicAdd(&counts[col[e]], 1);
}

__global__ __launch_bounds__(256) void k_scan1(const int* __restrict__ counts,
                                               int* __restrict__ scan_tmp,
                                               int* __restrict__ bsum, int N) {
  __shared__ int sd[2][256];
  int t = threadIdx.x;
  int i = blockIdx.x * 256 + t;
  int v = (i < N) ? counts[i] : 0;
  sd[0][t] = v;
  __syncthreads();
  int s = 0;
#pragma unroll
  for (int off = 1; off < 256; off <<= 1) {
    int nv = sd[s][t];
    if (t >= off) nv += sd[s][t - off];
    sd[s ^ 1][t] = nv;
    s ^= 1;
    __syncthreads();
  }
  if (i < N) scan_tmp[i] = sd[s][t];
  if (t == 255) bsum[blockIdx.x] = sd[s][255];
}

__global__ __launch_bounds__(256) void k_scan2(int* __restrict__ b, int NB) {
  __shared__ int sd[2][256];
  __shared__ int carry_s;
  int t = threadIdx.x;
  if (t == 0) carry_s = 0;
  __syncthreads();
  for (int base = 0; base < NB; base += 256) {
    int i = base + t;
    int v = (i < NB) ? b[i] : 0;
    sd[0][t] = v;
    __syncthreads();
    int s = 0;
#pragma unroll
    for (int off = 1; off < 256; off <<= 1) {
      int nv = sd[s][t];
      if (t >= off) nv += sd[s][t - off];
      sd[s ^ 1][t] = nv;
      s ^= 1;
      __syncthreads();
    }
    int c = carry_s;
    int tot = sd[s][255];
    if (i < NB) b[i] = sd[s][t] + c;
    __syncthreads();
    if (t == 0) carry_s = c + tot;
    __syncthreads();
  }
}

__global__ __launch_bounds__(256) void k_scan3(const int* __restrict__ counts,
                                               const int* __restrict__ scan_tmp,
                                               const int* __restrict__ bsum,
                                               int* __restrict__ cursor, int N) {
  int i = blockIdx.x * 256 + threadIdx.x;
  if (i < N) {
    int base = (blockIdx.x > 0) ? bsum[blockIdx.x - 1] : 0;
    cursor[i] = scan_tmp[i] - counts[i] + base;
  }
}

__global__ __launch_bounds__(256) void k_scatter(
    const int* __restrict__ row, const int* __restrict__ col,
    int* __restrict__ cursor, int* __restrict__ pos,
    int* __restrict__ row_s, int* __restrict__ col_s, int E) {
  int stride = gridDim.x * blockDim.x;
  for (int e = blockIdx.x * blockDim.x + threadIdx.x; e < E; e += stride) {
    int c = col[e];
    int p = atomicAdd(&cursor[c], 1);
    pos[e] = p;
    row_s[p] = row[e];
    col_s[p] = c;
  }
}

// ---------------- bond embedding via MFMA: [128 edges x 41] @ [41 x 64] ----------------
__global__ __launch_bounds__(256) void k_embed_bonds_mfma(
    const float* __restrict__ eattr, const int* __restrict__ pos,
    const unsigned short* __restrict__ gWb, const float* __restrict__ b_bond,
    unsigned short* __restrict__ ea16, int E) {
  __shared__ unsigned short sA[128 * 64];  // 16 KB, swizzled
  __shared__ float sb[64];
  __shared__ int spos[128];
  int tid = threadIdx.x;
  int w = tid >> 6, l = tid & 63, q = l >> 4, c16 = l & 15;
  int rbase = w * 32;
  if (tid < 64) sb[tid] = b_bond[tid];
  int ntiles = (E + 127) >> 7;
  for (int tile = blockIdx.x; tile < ntiles; tile += gridDim.x) {
    int te = tile << 7;
    int cnt = E - te; if (cnt > 128) cnt = 128;
    __syncthreads();   // protect sA reuse across loop iterations
    uint4 z = make_uint4(0, 0, 0, 0);
    for (int i = tid; i < 1024; i += 256) ((uint4*)sA)[i] = z;
    __syncthreads();
    int nflt = cnt * 41;
    for (int i = tid; i < nflt; i += 256) {
      int r = i / 41, k = i - r * 41;
      float v = __builtin_nontemporal_load(&eattr[(size_t)te * 41 + i]);
      sA[r * 64 + (k ^ ((r & 7) << 3))] = f2bf(v);
    }
    if (tid < 128) spos[tid] = (te + tid < E) ? pos[te + tid] : -1;
    __syncthreads();
    v8s bfr[4][2], af[2][2];
    v4f acc[2][4];
    const v8s* wp_ = (const v8s*)gWb;
#pragma unroll
    for (int ct = 0; ct < 4; ++ct)
#pragma unroll
      for (int kh = 0; kh < 2; ++kh)
        bfr[ct][kh] = wp_[(ct * 2 + kh) * 64 + l];
#pragma unroll
    for (int rb = 0; rb < 2; ++rb)
#pragma unroll
      for (int kh = 0; kh < 2; ++kh) {
        int row_ = rbase + rb * 16 + c16;
        af[rb][kh] = *(const v8s*)&sA[row_ * 64 +
                                      ((kh * 32 + q * 8) ^ ((row_ & 7) << 3))];
      }
#pragma unroll
    for (int rb = 0; rb < 2; ++rb)
#pragma unroll
      for (int ct = 0; ct < 4; ++ct) {
        v4f a_ = {0.f, 0.f, 0.f, 0.f};
        a_ = __builtin_amdgcn_mfma_f32_16x16x32_bf16(af[rb][0], bfr[ct][0], a_, 0, 0, 0);
        a_ = __builtin_amdgcn_mfma_f32_16x16x32_bf16(af[rb][1], bfr[ct][1], a_, 0, 0, 0);
        acc[rb][ct] = a_;
      }
#pragma unroll
    for (int rb = 0; rb < 2; ++rb)
#pragma unroll
      for (int ct = 0; ct < 4; ++ct) {
        int n = ct * 16 + c16;
#pragma unroll
        for (int r = 0; r < 4; ++r) {
          float v = acc[rb][ct][r] + sb[n];
          int row = rbase + rb * 16 + q * 4 + r;
          sA[row * 64 + (n ^ ((row & 7) << 3))] = f2bf(v);
        }
      }
    __syncthreads();
    for (int i = tid; i < 1024; i += 256) {
      int r = i >> 3, cc = i & 7;
      int p = spos[r];
      if (p >= 0) {
        u32x4 d = *(const u32x4*)&sA[r * 64 + ((cc * 8) ^ ((r & 7) << 3))];
        nt_store4(&ea16[(size_t)p * 64 + cc * 8], d);
      }
    }
  }
}

// ---------------- node-side precompute body (R5 layout) ----------------
__device__ __forceinline__ void node_pre_body(
    const float* __restrict__ xr, const float* sWa, const float* sWb,
    const float* sWp, unsigned short* __restrict__ up16,
    unsigned short* __restrict__ v16, int n) {
  const float4* xr4 = (const float4*)xr;
  float u[64], p[64];
#pragma unroll
  for (int j = 0; j < 64; ++j) { u[j] = 0.f; p[j] = 0.f; }
  for (int k4 = 0; k4 < 16; ++k4) {
    float4 av = xr4[k4];
    const float* wa = sWa + k4 * 256;
    const float* wp = sWp + k4 * 256;
#pragma unroll
    for (int j = 0; j < 64; ++j) u[j] = fmaf(av.x, wa[j], u[j]);
#pragma unroll
    for (int j = 0; j < 64; ++j) p[j] = fmaf(av.x, wp[j], p[j]);
#pragma unroll
    for (int j = 0; j < 64; ++j) u[j] = fmaf(av.y, wa[64 + j], u[j]);
#pragma unroll
    for (int j = 0; j < 64; ++j) p[j] = fmaf(av.y, wp[64 + j], p[j]);
#pragma unroll
    for (int j = 0; j < 64; ++j) u[j] = fmaf(av.z, wa[128 + j], u[j]);
#pragma unroll
    for (int j = 0; j < 64; ++j) p[j] = fmaf(av.z, wp[128 + j], p[j]);
#pragma unroll
    for (int j = 0; j < 64; ++j) u[j] = fmaf(av.w, wa[192 + j], u[j]);
#pragma unroll
    for (int j = 0; j < 64; ++j) p[j] = fmaf(av.w, wp[192 + j], p[j]);
  }
  unsigned short* o = up16 + (size_t)n * 128;
#pragma unroll
  for (int q8 = 0; q8 < 8; ++q8) {
    unsigned short tmp[8];
#pragma unroll
    for (int j = 0; j < 8; ++j) {
      int i = q8 * 8 + j;
      tmp[j] = f2bf(u[((i & 3) << 4) | (i >> 2)]);
    }
    *(uint4*)&o[q8 * 8] = *(uint4*)tmp;
  }
#pragma unroll
  for (int q8 = 0; q8 < 8; ++q8) {
    unsigned short tmp[8];
#pragma unroll
    for (int j = 0; j < 8; ++j) {
      int i = q8 * 8 + j;
      tmp[j] = f2bf(p[((i & 3) << 4) | (i >> 2)]);
    }
    *(uint4*)&o[64 + q8 * 8] = *(uint4*)tmp;
  }
  float vv[64];
#pragma unroll
  for (int j = 0; j < 64; ++j) vv[j] = 0.f;
  for (int k4 = 0; k4 < 16; ++k4) {
    float4 av = xr4[k4];
    const float* wb = sWb + k4 * 256;
#pragma unroll
    for (int j = 0; j < 64; ++j) vv[j] = fmaf(av.x, wb[j], vv[j]);
#pragma unroll
    for (int j = 0; j < 64; ++j) vv[j] = fmaf(av.y, wb[64 + j], vv[j]);
#pragma unroll
    for (int j = 0; j < 64; ++j) vv[j] = fmaf(av.z, wb[128 + j], vv[j]);
#pragma unroll
    for (int j = 0; j < 64; ++j) vv[j] = fmaf(av.w, wb[192 + j], vv[j]);
  }
  unsigned short* ov = v16 + (size_t)n * 64;
#pragma unroll
  for (int q8 = 0; q8 < 8; ++q8) {
    unsigned short tmp[8];
#pragma unroll
    for (int j = 0; j < 8; ++j) {
      int i = q8 * 8 + j;
      tmp[j] = f2bf(vv[((i & 3) << 4) | (i >> 2)]);
    }
    *(uint4*)&ov[q8 * 8] = *(uint4*)tmp;
  }
}

// also zeroes xnew row n (removes a standalone memset dispatch)
__global__ __launch_bounds__(256) void k_node_pre(
    const float* __restrict__ xemb, const float* __restrict__ eW1,
    const float* __restrict__ nW1, unsigned short* __restrict__ up16,
    unsigned short* __restrict__ v16, float* __restrict__ xnew, int N) {
  __shared__ float sWa[64 * 64];
  __shared__ float sWb[64 * 64];
  __shared__ float sWp[64 * 64];
  for (int i = threadIdx.x; i < 64 * 64; i += blockDim.x) {
    sWa[i] = eW1[i];
    sWb[i] = eW1[64 * 64 + i];
    sWp[i] = nW1[i];
  }
  __syncthreads();
  int stride = gridDim.x * blockDim.x;
  float4 z = make_float4(0.f, 0.f, 0.f, 0.f);
  for (int n = blockIdx.x * blockDim.x + threadIdx.x; n < N; n += stride) {
    node_pre_body(xemb + (size_t)n * 64, sWa, sWb, sWp, up16, v16, n);
    float4* xz = (float4*)(xnew + (size_t)n * 64);
#pragma unroll
    for (int q = 0; q < 16; ++q) xz[q] = z;
  }
}

// ---------------- fused BN apply + residual + next-layer node_pre (+xnew clear) ----------------
__global__ __launch_bounds__(256) void k_bn_pre(
    float* __restrict__ xemb, float* __restrict__ xnew,
    const float* __restrict__ bnacc, const float* __restrict__ gamma,
    const float* __restrict__ beta, const float* __restrict__ eW1n,
    const float* __restrict__ nW1n, unsigned short* __restrict__ up16,
    unsigned short* __restrict__ v16, int N) {
  __shared__ float sWa[64 * 64];
  __shared__ float sWb[64 * 64];
  __shared__ float sWp[64 * 64];
  __shared__ float sscale[64], sshift[64];
  for (int i = threadIdx.x; i < 64 * 64; i += blockDim.x) {
    sWa[i] = eW1n[i];
    sWb[i] = eW1n[64 * 64 + i];
    sWp[i] = nW1n[i];
  }
  if (threadIdx.x < 64) {
    float inv = 1.0f / (float)N;
    float m = bnacc[threadIdx.x] * inv;
    float var = bnacc[64 + threadIdx.x] * inv - m * m;
    float rs = rsqrtf(var + 1e-5f);
    float g = gamma[threadIdx.x];
    sscale[threadIdx.x] = rs * g;
    sshift[threadIdx.x] = beta[threadIdx.x] - m * rs * g;
  }
  __syncthreads();
  int stride = gridDim.x * blockDim.x;
  float4 z = make_float4(0.f, 0.f, 0.f, 0.f);
  for (int n = blockIdx.x * blockDim.x + threadIdx.x; n < N; n += stride) {
    float* xr = xemb + (size_t)n * 64;
    float4* xnrow = (float4*)(xnew + (size_t)n * 64);
#pragma unroll
    for (int q = 0; q < 16; ++q) {
      float4 xn4 = xnrow[q];
      float4 xo4 = ((const float4*)xr)[q];
      xo4.x += sp_f(fmaf(xn4.x, sscale[4*q+0], sshift[4*q+0]));
      xo4.y += sp_f(fmaf(xn4.y, sscale[4*q+1], sshift[4*q+1]));
      xo4.z += sp_f(fmaf(xn4.z, sscale[4*q+2], sshift[4*q+2]));
      xo4.w += sp_f(fmaf(xn4.w, sscale[4*q+3], sshift[4*q+3]));
      ((float4*)xr)[q] = xo4;
      xnrow[q] = z;     // clear for next layer's atomics/stores
    }
    node_pre_body(xr, sWa, sWb, sWp, up16, v16, n);
  }
}

// ---------------- fused per-layer edge kernel: 8 waves x 16 rows, 3 blocks/CU ----------------
// 128-edge tile; LDS padded to 41 KB caps occupancy at 3 blocks/CU (same tile
// footprint as R12 = low traffic) while 24 waves/CU hide gather latency.
#define READ_FRAGS(P)                                                        \
  {                                                                          \
    const v8s* wp_ = (const v8s*)gWf + (P) * 512;                            \
    _Pragma("unroll") for (int ct = 0; ct < 4; ++ct)                         \
        _Pragma("unroll") for (int kh = 0; kh < 2; ++kh)                     \
            bfr[ct][kh] = wp_[(ct * 2 + kh) * 64 + l];                       \
    {                                                                        \
      int row_ = rbase + c16;                                                \
      _Pragma("unroll") for (int kh = 0; kh < 2; ++kh)                       \
        af[kh] = *(const v8s*)&sA[row_ * 64 +                                \
                                  ((kh * 32 + q * 8) ^ ((row_ & 7) << 3))];  \
    }                                                                        \
  }

#define DO_MFMA()                                                            \
  _Pragma("unroll") for (int ct = 0; ct < 4; ++ct) {                         \
    v4f a_ = {0.f, 0.f, 0.f, 0.f};                                           \
    a_ = __builtin_amdgcn_mfma_f32_16x16x32_bf16(af[0], bfr[ct][0], a_,      \
                                                 0, 0, 0);                   \
    a_ = __builtin_amdgcn_mfma_f32_16x16x32_bf16(af[1], bfr[ct][1], a_,      \
                                                 0, 0, 0);                   \
    acc[ct] = a_;                                                            \
  }

__global__ __launch_bounds__(512, 6) void k_edge_mfma(
    const int* __restrict__ row_s, const int* __restrict__ col_s,
    unsigned short* __restrict__ ea16, const unsigned short* __restrict__ up16,
    const unsigned short* __restrict__ v16,
    const unsigned short* __restrict__ gWf, const float* __restrict__ eb1,
    const float* __restrict__ eb2, const float* __restrict__ nb1,
    const float* __restrict__ nb2, float* __restrict__ xnew,
    float* __restrict__ bnacc, int E, int store_ea) {
  __shared__ __align__(16) unsigned char smem[41984];   // padded: 3 blocks/CU
  unsigned short* sA = (unsigned short*)smem;             // 16 KB (aliased)
  float* msgb        = (float*)smem;                      // 32 KB
  float* sBb         = (float*)(smem + 32768);            // 1 KB
  int* scol          = (int*)(smem + 33792);              // 512 B

  int tid = threadIdx.x;
  int te = blockIdx.x * 128;
  int w = tid >> 6, l = tid & 63, q = l >> 4, c16 = l & 15;
  int rbase = w * 16;

  // zero bnacc for the following bn_stats (replaces a memset dispatch)
  if (blockIdx.x == 0 && tid < 128) bnacc[tid] = 0.0f;

  int rid[4], cid[4], eid[4];
#pragma unroll
  for (int r = 0; r < 4; ++r) {
    int e = te + rbase + q * 4 + r;
    eid[r] = e;
    int ec = e < E ? e : E - 1;
    rid[r] = row_s[ec];
    cid[r] = col_s[ec];
  }
  // split gathers: u + v issued early
  ushort4 uu_pf[4], vv_pf[4];
#pragma unroll
  for (int r = 0; r < 4; ++r) {
    uu_pf[r] = *(const ushort4*)&up16[(size_t)rid[r] * 128 + c16 * 4];
    vv_pf[r] = *(const ushort4*)&v16[(size_t)cid[r] * 64 + c16 * 4];
  }

  if (tid < 64) {
    sBb[0 * 64 + tid] = eb1[tid];
    sBb[1 * 64 + tid] = eb2[tid];
    sBb[2 * 64 + tid] = nb1[tid];
    sBb[3 * 64 + tid] = nb2[tid];
  }
  if (tid < 128) {
    int e = te + tid;
    scol[tid] = col_s[e < E ? e : E - 1];
  }
  for (int i = tid; i < 1024; i += 512) {
    int r = i >> 3, cc = i & 7;
    int e = te + r;
    if (e >= E) e = E - 1;
    u32x4 d = nt_load4(&ea16[(size_t)e * 64 + cc * 8]);
    *(u32x4*)&sA[r * 64 + ((cc * 8) ^ ((r & 7) << 3))] = d;
  }

  v8s af[2];
  v8s bfr[4][2];
  v4f acc[4];

  __syncthreads();   // staging done

  // ---- phase 0: T = sp(ea@W1c + b1 + u[row] + v[col]) ----
  READ_FRAGS(0);
  DO_MFMA();
  // prefetch p for phase 2
  ushort4 pp_pf[4];
#pragma unroll
  for (int r = 0; r < 4; ++r)
    pp_pf[r] = *(const ushort4*)&up16[(size_t)rid[r] * 128 + 64 + c16 * 4];
#pragma unroll
  for (int r = 0; r < 4; ++r) {
    const unsigned short* up_ = (const unsigned short*)&uu_pf[r];
    const unsigned short* vp_ = (const unsigned short*)&vv_pf[r];
    int row = rbase + q * 4 + r;
#pragma unroll
    for (int ct = 0; ct < 4; ++ct) {
      int n = ct * 16 + c16;
      float t = acc[ct][r] + sBb[n] + bf2f(up_[ct]) + bf2f(vp_[ct]);
      t = sp_f(t);
      sA[row * 64 + (n ^ ((row & 7) << 3))] = f2bf(t);
    }
  }

  // ---- phase 1: ea' = T@eW2 + b2 -> sA (own band) ----
  READ_FRAGS(1);
  DO_MFMA();
#pragma unroll
  for (int ct = 0; ct < 4; ++ct) {
    int n = ct * 16 + c16;
#pragma unroll
    for (int r = 0; r < 4; ++r) {
      float en = acc[ct][r] + sBb[64 + n];
      int row = rbase + q * 4 + r;
      sA[row * 64 + (n ^ ((row & 7) << 3))] = f2bf(en);
    }
  }
  if (store_ea) {
    __syncthreads();   // writeback reads all rows
    for (int i = tid; i < 1024; i += 512) {
      int r = i >> 3, cc = i & 7;
      if (te + r < E) {
        u32x4 d = *(const u32x4*)&sA[r * 64 + ((cc * 8) ^ ((r & 7) << 3))];
        nt_store4(&ea16[(size_t)(te + r) * 64 + cc * 8], d);
      }
    }
    __syncthreads();   // phase-2 epi writes must not race writeback reads
  }

  // ---- phase 2: T2 = sp(ea'@nW1b + b3 + p[row]) ----
  READ_FRAGS(2);
  DO_MFMA();
#pragma unroll
  for (int r = 0; r < 4; ++r) {
    const unsigned short* pp_ = (const unsigned short*)&pp_pf[r];
    int row = rbase + q * 4 + r;
#pragma unroll
    for (int ct = 0; ct < 4; ++ct) {
      int n = ct * 16 + c16;
      float t2 = acc[ct][r] + sBb[128 + n] + bf2f(pp_[ct]);
      t2 = sp_f(t2);
      sA[row * 64 + (n ^ ((row & 7) << 3))] = f2bf(t2);
    }
  }

  // ---- phase 3: msg = T2@nW2 + b4 -> msgb (sA dead after frag loads) ----
  READ_FRAGS(3);
  __syncthreads();   // all waves done reading sA; msgb alias safe
  DO_MFMA();
#pragma unroll
  for (int ct = 0; ct < 4; ++ct) {
    int n = ct * 16 + c16;
#pragma unroll
    for (int r = 0; r < 4; ++r) {
      float msg = acc[ct][r] + sBb[192 + n];
      int row = rbase + q * 4 + r;
      msgb[row * 64 + n] = (eid[r] < E) ? msg : 0.0f;
    }
  }
  __syncthreads();

  // ---- segmented reduction; plain store for interior (exclusive) segments ----
  int nrows = E - te;
  if (nrows > 128) nrows = 128;
  for (int r0 = w; r0 < nrows; r0 += 8) {
    int c0 = scol[r0];
    if (r0 > 0 && scol[r0 - 1] == c0) continue;
    float s = 0.0f;
    int r = r0;
    do {
      s += msgb[r * 64 + l];
      ++r;
    } while (r < nrows && scol[r] == c0);
    if (r0 > 0 && r < nrows)
      xnew[(size_t)c0 * 64 + l] = s;     // run fully interior: exclusive writer
    else
      atomicAdd(&xnew[(size_t)c0 * 64 + l], s);
  }
}

// ---------------- BN stats ----------------
__global__ __launch_bounds__(256) void k_bn_stats(
    const float* __restrict__ xnew, float* __restrict__ bnacc, int N) {
  int t = threadIdx.x;
  int ch = t & 63;
  int sl = t >> 6;
  float s = 0.f, s2 = 0.f;
  for (int n = blockIdx.x * 4 + sl; n < N; n += gridDim.x * 4) {
    float v = xnew[(size_t)n * 64 + ch];
    s += v;
    s2 = fmaf(v, v, s2);
  }
  __shared__ float red[256], red2[256];
  red[t] = s;
  red2[t] = s2;
  __syncthreads();
  if (sl == 0) {
    s = red[ch] + red[64 + ch] + red[128 + ch] + red[192 + ch];
    s2 = red2[ch] + red2[64 + ch] + red2[128 + ch] + red2[192 + ch];
    atomicAdd(&bnacc[ch], s);
    atomicAdd(&bnacc[64 + ch], s2);
  }
}

// ---------------- BN apply + softplus + residual (last layer) ----------------
__global__ __launch_bounds__(256) void k_bn_apply(
    float* __restrict__ x, const float* __restrict__ xnew,
    const float* __restrict__ bnacc, const float* __restrict__ gamma,
    const float* __restrict__ beta, int N) {
  __shared__ float sscale[64], sshift[64];
  if (threadIdx.x < 64) {
    float inv = 1.0f / (float)N;
    float m = bnacc[threadIdx.x] * inv;
    float var = bnacc[64 + threadIdx.x] * inv - m * m;
    float rs = rsqrtf(var + 1e-5f);
    float g = gamma[threadIdx.x];
    sscale[threadIdx.x] = rs * g;
    sshift[threadIdx.x] = beta[threadIdx.x] - m * rs * g;
  }
  __syncthreads();
  size_t total = (size_t)N * 64;
  size_t stride = (size_t)gridDim.x * blockDim.x;
  for (size_t i = (size_t)blockIdx.x * blockDim.x + threadIdx.x; i < total; i += stride) {
    int ch = (int)(i & 63);
    float v = fmaf(xnew[i], sscale[ch], sshift[ch]);
    x[i] += sp_f(v);
  }
}

// ---------------- fused pool + predictor ----------------
__device__ __forceinline__ int lbound(const int* a, int n, int key) {
  int lo = 0, hi = n;
  while (lo < hi) {
    int mid = (lo + hi) >> 1;
    if (a[mid] < key) lo = mid + 1; else hi = mid;
  }
  return lo;
}

__global__ __launch_bounds__(256) void k_pool_pred(
    const float* __restrict__ x, const int* __restrict__ batch, int N,
    const float* __restrict__ pW1, const float* __restrict__ pb1,
    const float* __restrict__ pW2, const float* __restrict__ pb2,
    const float* __restrict__ pW3, const float* __restrict__ pb3,
    float* __restrict__ out) {
  int b = blockIdx.x;
  int lo = lbound(batch, N, b);
  int hi = lbound(batch, N, b + 1);
  int t = threadIdx.x;
  int ch = t & 63;
  int sl = t >> 6;
  float s = 0.f;
  for (int n = lo + sl; n < hi; n += 4) s += x[(size_t)n * 64 + ch];
  __shared__ float red4[4][64];
  __shared__ float sg[64];
  __shared__ float sh1[128];
  __shared__ float red[128];
  red4[sl][ch] = s;
  __syncthreads();
  if (t < 64) {
    float tot = red4[0][t] + red4[1][t] + red4[2][t] + red4[3][t];
    float cnt = (float)(hi - lo);
    sg[t] = tot / fmaxf(cnt, 1.0f);
  }
  __syncthreads();
  if (t < 128) {
    float h = pb1[t];
    for (int k = 0; k < 64; ++k) h = fmaf(sg[k], pW1[k * 128 + t], h);
    sh1[t] = sp_f(h);
  }
  __syncthreads();
  if (t < 128) {
    float h = pb2[t];
    for (int k = 0; k < 128; ++k) h = fmaf(sh1[k], pW2[k * 128 + t], h);
    red[t] = sp_f(h) * pW3[t];
  }
  __syncthreads();
  for (int off = 64; off > 0; off >>= 1) {
    if (t < off) red[t] += red[t + off];
    __syncthreads();
  }
  if (t == 0) out[b] = red[0] + pb3[0];
}

extern "C" void kernel_launch(void* const* d_in, const int* in_sizes, int n_in,
                              void* d_out, int out_size, void* d_ws, size_t ws_size,
                              hipStream_t stream) {
  const float* x         = (const float*)d_in[0];
  const float* edge_attr = (const float*)d_in[1];
  const float* charge    = (const float*)d_in[2];
  const int*   eidx      = (const int*)d_in[3];
  const int*   batch     = (const int*)d_in[4];
  const float* W_charge  = (const float*)d_in[5];
  const float* b_charge  = (const float*)d_in[6];
  const float* W_atom    = (const float*)d_in[7];
  const float* b_atom    = (const float*)d_in[8];
  const float* W_bond    = (const float*)d_in[9];
  const float* b_bond    = (const float*)d_in[10];
  const float* eW1 = (const float*)d_in[11];
  const float* eb1 = (const float*)d_in[12];
  const float* eW2 = (const float*)d_in[13];
  const float* eb2 = (const float*)d_in[14];
  const float* nW1 = (const float*)d_in[15];
  const float* nb1 = (const float*)d_in[16];
  const float* nW2 = (const float*)d_in[17];
  const float* nb2 = (const float*)d_in[18];
  const float* gam = (const float*)d_in[19];
  const float* bet = (const float*)d_in[20];
  const float* pW1 = (const float*)d_in[21];
  const float* pb1 = (const float*)d_in[22];
  const float* pW2 = (const float*)d_in[23];
  const float* pb2 = (const float*)d_in[24];
  const float* pW3 = (const float*)d_in[25];
  const float* pb3 = (const float*)d_in[26];

  int N = in_sizes[4];
  int E = in_sizes[3] / 2;
  int B = in_sizes[2];
  const int* row = eidx;
  const int* col = eidx + E;

  char* wptr = (char*)d_ws;
  unsigned short* ea16 = (unsigned short*)wptr; wptr += (((size_t)E * 64 * 2 + 255) & ~255ull);
  unsigned short* up16 = (unsigned short*)wptr; wptr += (((size_t)N * 128 * 2 + 255) & ~255ull);
  unsigned short* v16  = (unsigned short*)wptr; wptr += (((size_t)N * 64 * 2 + 255) & ~255ull);
  unsigned short* wfrag = (unsigned short*)wptr; wptr += 13 * 4096 * 2;
  float* xemb = (float*)wptr; wptr += (size_t)N * 64 * 4;
  float* xnew = (float*)wptr; wptr += (size_t)N * 64 * 4;
  float* bnacc = (float*)wptr; wptr += 256 * 4;
  int* counts = (int*)wptr;   wptr += (size_t)N * 4;
  int* scan_tmp = (int*)wptr; wptr += (size_t)N * 4;
  int* cursor = (int*)wptr;   wptr += (size_t)N * 4;
  int* bsum = (int*)wptr;     wptr += 4096;
  int* pos = (int*)wptr;      wptr += (size_t)E * 4;
  int* row_s = (int*)wptr;    wptr += (size_t)E * 4;
  int* col_s = (int*)wptr;    wptr += (size_t)E * 4;

  int NB = (N + 255) / 256;

  k_prep_wfrag<<<13, 256, 0, stream>>>(eW1, eW2, nW1, nW2, W_bond, wfrag);
  hipMemsetAsync(counts, 0, (size_t)N * 4, stream);
  k_hist<<<2048, 256, 0, stream>>>(col, counts, E);
  k_scan1<<<NB, 256, 0, stream>>>(counts, scan_tmp, bsum, N);
  k_scan2<<<1, 256, 0, stream>>>(bsum, NB);
  k_scan3<<<NB, 256, 0, stream>>>(counts, scan_tmp, bsum, cursor, N);
  k_scatter<<<2048, 256, 0, stream>>>(row, col, cursor, pos, row_s, col_s, E);

  int ntilesN = (N + 127) / 128;
  k_embed_nodes<<<ntilesN, 256, 0, stream>>>(x, batch, charge, W_charge,
                                             b_charge, W_atom, b_atom, xemb, N);
  k_embed_bonds_mfma<<<2048, 256, 0, stream>>>(edge_attr, pos,
                                               wfrag + 12 * 4096, b_bond,
                                               ea16, E);
  k_node_pre<<<NB, 256, 0, stream>>>(xemb, eW1, nW1, up16, v16, xnew, N);

  int gridE = (E + 127) / 128;
  for (int i = 0; i < 3; ++i) {
    k_edge_mfma<<<gridE, 512, 0, stream>>>(
        row_s, col_s, ea16, up16, v16, wfrag + (size_t)i * 16384,
        eb1 + (size_t)i * 64, eb2 + (size_t)i * 64, nb1 + (size_t)i * 64,
        nb2 + (size_t)i * 64, xnew, bnacc, E, (i < 2) ? 1 : 0);
    k_bn_stats<<<1024, 256, 0, stream>>>(xnew, bnacc, N);
    if (i < 2) {
      k_bn_pre<<<NB, 256, 0, stream>>>(
          xemb, xnew, bnacc, gam + (size_t)i * 64, bet + (size_t)i * 64,
          eW1 + (size_t)(i + 1) * 192 * 64, nW1 + (size_t)(i + 1) * 128 * 64,
          up16, v16, N);
    } else {
      k_bn_apply<<<4096, 256, 0, stream>>>(xemb, xnew, bnacc,
                                           gam + (size_t)i * 64,
                                           bet + (size_t)i * 64, N);
    }
  }

  k_pool_pred<<<B, 256, 0, stream>>>(xemb, batch, N, pW1, pb1, pW2, pb2,
                                     pW3, pb3, (float*)d_out);
}